// Round 7
// baseline (395.698 us; speedup 1.0000x reference)
//
#include <hip/hip_runtime.h>
#include <math.h>

// Problem constants (fixed by setup_inputs): B=4, N=2048, C=128, H=6, K=8
#define NFIX 2048
#define HH 6
#define KNN 8
#define NSLOPE 0.2f
#define EPSF 1e-6f
#define LNEPSF 1e-5f
// 0.125 (softmax scale) * log2(e), folded into Wq rows so S-MFMA output is exp2-ready
#define QSCALE 0.18033688011112042f
#define NSPLIT 2

typedef unsigned short ushort_t;
typedef unsigned int uint_t;
typedef __attribute__((ext_vector_type(8))) short bf16x8;
typedef __attribute__((ext_vector_type(4))) short bf16x4;
typedef __attribute__((ext_vector_type(8))) _Float16 f16x8;
typedef __attribute__((ext_vector_type(4))) _Float16 f16x4;
typedef __attribute__((ext_vector_type(16))) float f32x16;
typedef __attribute__((ext_vector_type(4))) float f32x4;

__device__ __forceinline__ ushort_t f2bf(float f) {
  union { float f; unsigned u; } v; v.f = f;
  unsigned r = v.u + 0x7fff + ((v.u >> 16) & 1);   // RNE
  return (ushort_t)(r >> 16);
}
__device__ __forceinline__ float bf2f(ushort_t u) {
  union { uint_t u; float f; } v; v.u = ((uint_t)u) << 16; return v.f;
}
__device__ __forceinline__ uint_t pack2(float a, float b) {
  return (uint_t)f2bf(a) | ((uint_t)f2bf(b) << 16);
}
// f32 -> f16 bit pattern (register-only)
__device__ __forceinline__ ushort_t f2h_bits(float a) {
  union { _Float16 h; ushort_t s; } cv; cv.h = (_Float16)a; return cv.s;
}
// pack two fp32 -> two f16 in one dword (register-only; no local-array aliasing)
__device__ __forceinline__ uint_t packh2(float a, float b) {
  union { _Float16 h; ushort_t s; } ha, hb;
  ha.h = (_Float16)a; hb.h = (_Float16)b;
  return (uint_t)ha.s | ((uint_t)hb.s << 16);
}

__device__ __forceinline__ void vnleaky3(const float* p, const float* dv, float* out) {
  float dot = p[0]*dv[0] + p[1]*dv[1] + p[2]*dv[2];
  float dsq = dv[0]*dv[0] + dv[1]*dv[1] + dv[2]*dv[2] + EPSF;
  float f = dot / dsq;
#pragma unroll
  for (int d = 0; d < 3; ++d) {
    float neg = p[d] - f * dv[d];
    out[d] = NSLOPE * p[d] + (1.f - NSLOPE) * ((dot >= 0.f) ? p[d] : neg);
  }
}

// ---------------- weight prep ----------------
__global__ void prep_weights(const float* __restrict__ Wq, const float* __restrict__ Wk,
                             const float* __restrict__ Wv, const float* __restrict__ Wo,
                             const float* __restrict__ W1, const float* __restrict__ U1,
                             const float* __restrict__ W2, const float* __restrict__ W3,
                             const float* __restrict__ U3, const float* __restrict__ W4,
                             const float* __restrict__ U4,
                             ushort_t* __restrict__ Wall, _Float16* __restrict__ Af16,
                             _Float16* __restrict__ W3h, _Float16* __restrict__ U3h,
                             _Float16* __restrict__ W4h, _Float16* __restrict__ U4h) {
  int idx = blockIdx.x * 256 + threadIdx.x;
  if (idx < 212992) {
    int m = idx >> 7, c = idx & 127;
    float val;
    if (m < 384)       val = Wq[m*128 + c] * QSCALE;
    else if (m < 768)  val = Wk[(m-384)*128 + c];
    else if (m < 1152) val = Wv[(m-768)*128 + c];
    else {
      int j = m - 1152;
      if (j < 128)      val = W1[j*256 + c];
      else if (j < 256) val = U1[(j-128)*256 + c];
      else if (j < 384) { int o = j-256; val = W1[o*256 + 128 + c] - W1[o*256 + c]; }
      else              { int o = j-384; val = U1[o*256 + 128 + c] - U1[o*256 + c]; }
    }
    Wall[idx] = f2bf(val); return;
  }
  idx -= 212992;
  if (idx < 49152) {
    int j = idx / 128, c = idx % 128;   // M2[c][j] = (W2a@Wo)[c][j]
    float s = 0.f;
    for (int cp = 0; cp < 128; ++cp) s += W2[c*256 + cp] * Wo[cp*384 + j];
    Af16[(size_t)c*512 + j] = (_Float16)s; return;
  }
  idx -= 49152;
  if (idx < 16384) {
    int c2 = idx / 128, c = idx % 128;
    Af16[(size_t)c*512 + 384 + c2] = (_Float16)W2[c*256 + 128 + c2]; return;
  }
  idx -= 16384;
  if (idx < 32768) { W3h[idx] = (_Float16)W3[idx]; return; }
  idx -= 32768;
  if (idx < 32768) { U3h[idx] = (_Float16)U3[idx]; return; }
  idx -= 32768;
  if (idx < 32768) { W4h[idx] = (_Float16)W4[idx]; return; }
  idx -= 32768;
  if (idx < 32768) { U4h[idx] = (_Float16)U4[idx]; return; }
}

// ---------------- LN1 ----------------
__global__ __launch_bounds__(128) void ln1_kernel(const float* __restrict__ in,
                                                  ushort_t* __restrict__ xbp,
                                                  float* __restrict__ xdi,
                                                  const float* __restrict__ g,
                                                  const float* __restrict__ b) {
  int bn = blockIdx.x;
  int c = threadIdx.x;
  const float* row = in + (size_t)bn * 384;
  float x0 = row[c*3+0], x1 = row[c*3+1], x2 = row[c*3+2];
  float nv = sqrtf(x0*x0 + x1*x1 + x2*x2 + EPSF);
  float s1 = nv, s2 = nv*nv;
#pragma unroll
  for (int off = 32; off >= 1; off >>= 1) {
    s1 += __shfl_down(s1, off);
    s2 += __shfl_down(s2, off);
  }
  __shared__ float red[4];
  int lane = threadIdx.x & 63, w = threadIdx.x >> 6;
  if (lane == 0) { red[w*2] = s1; red[w*2+1] = s2; }
  __syncthreads();
  float tot1 = red[0] + red[2], tot2 = red[1] + red[3];
  float mu  = tot1 * (1.f/128.f);
  float var = tot2 * (1.f/128.f) - mu*mu;
  float rsig = rsqrtf(var + LNEPSF);
  float nnew = g[c] * ((nv - mu) * rsig) + b[c];
  float sc = nnew / nv;
  size_t rb = (size_t)bn * 384;
  xbp[rb + c]       = f2bf(x0*sc);
  xbp[rb + 128 + c] = f2bf(x1*sc);
  xbp[rb + 256 + c] = f2bf(x2*sc);
  xdi[rb + c]       = x0;
  xdi[rb + 128 + c] = x1;
  xdi[rb + 256 + c] = x2;
}

// ---------------- fused QKV + conv1 MFMA GEMM ----------------
#define XT_PITCH 132
#define WT_PITCH 132
#define TR_PITCH 36
__global__ __launch_bounds__(256, 2) void qkv_conv1_mfma(
    const ushort_t* __restrict__ xb, const ushort_t* __restrict__ Wall,
    ushort_t* __restrict__ q, ushort_t* __restrict__ k, ushort_t* __restrict__ v,
    _Float16* __restrict__ YZh, _Float16* __restrict__ NBh) {
  __shared__ ushort_t xs[128*XT_PITCH];
  __shared__ ushort_t wt[32*WT_PITCH];
  __shared__ float tr[4][32*TR_PITCH];
  int nb = blockIdx.x % 192;
  int mq = blockIdx.x / 192;
  int n0 = nb * 128;
  int t = threadIdx.x;
  int w = t >> 6, lane = t & 63, ql = lane & 31, hl = lane >> 5;
  for (int idx = t; idx < 2048; idx += 256) {
    int n = idx >> 4, c16 = idx & 15;
    bf16x8 gv = *(const bf16x8*)&xb[(size_t)(n0 + n)*128 + c16*8];
    ushort_t* dst = &xs[n*XT_PITCH + c16*8];
    *(bf16x4*)dst = __builtin_shufflevector(gv, gv, 0, 1, 2, 3);
    *(bf16x4*)(dst+4) = __builtin_shufflevector(gv, gv, 4, 5, 6, 7);
  }
  __syncthreads();
  bf16x8 xf[8];
  {
    const ushort_t* xr = &xs[(w*32 + ql)*XT_PITCH + hl*8];
#pragma unroll
    for (int cs = 0; cs < 8; ++cs) {
      bf16x4 lo = *(const bf16x4*)(xr + cs*16);
      bf16x4 hi = *(const bf16x4*)(xr + cs*16 + 4);
      xf[cs] = __builtin_shufflevector(lo, hi, 0, 1, 2, 3, 4, 5, 6, 7);
    }
  }
  int ng = n0 + w*32 + ql;
  int pt = ng / 3;
  int d  = ng - 3*pt;
  float* trw = tr[w];
  for (int mt = 0; mt < 13; ++mt) {
    int m0 = mq*416 + mt*32;
    __syncthreads();
    for (int idx = t; idx < 512; idx += 256) {
      int mm = idx >> 4, c16 = idx & 15;
      bf16x8 gv = *(const bf16x8*)&Wall[(size_t)(m0 + mm)*128 + c16*8];
      ushort_t* dst = &wt[mm*WT_PITCH + c16*8];
      *(bf16x4*)dst = __builtin_shufflevector(gv, gv, 0, 1, 2, 3);
      *(bf16x4*)(dst+4) = __builtin_shufflevector(gv, gv, 4, 5, 6, 7);
    }
    __syncthreads();
    f32x16 acc;
#pragma unroll
    for (int r = 0; r < 16; ++r) acc[r] = 0.f;
    const ushort_t* wr = &wt[ql*WT_PITCH + hl*8];
#pragma unroll
    for (int cs = 0; cs < 8; ++cs) {
      bf16x4 lo = *(const bf16x4*)(wr + cs*16);
      bf16x4 hi = *(const bf16x4*)(wr + cs*16 + 4);
      bf16x8 af = __builtin_shufflevector(lo, hi, 0, 1, 2, 3, 4, 5, 6, 7);
      acc = __builtin_amdgcn_mfma_f32_32x32x16_bf16(af, xf[cs], acc, 0, 0, 0);
    }
#pragma unroll
    for (int r = 0; r < 16; ++r) {
      int mrow = (r&3) + 8*(r>>2) + 4*hl;
      trw[ql*TR_PITCH + mrow] = acc[r];
    }
    asm volatile("s_waitcnt lgkmcnt(0)" ::: "memory");
    float4 c0 = *(float4*)&trw[ql*TR_PITCH + hl*16 + 0];
    float4 c1 = *(float4*)&trw[ql*TR_PITCH + hl*16 + 4];
    float4 c2 = *(float4*)&trw[ql*TR_PITCH + hl*16 + 8];
    float4 c3 = *(float4*)&trw[ql*TR_PITCH + hl*16 + 12];
    asm volatile("s_waitcnt lgkmcnt(0)" ::: "memory");
    int mg = m0 + hl*16;
    if (m0 < 1152) {
      uint4 s0, s1;
      s0.x = pack2(c0.x, c0.y); s0.y = pack2(c0.z, c0.w);
      s0.z = pack2(c1.x, c1.y); s0.w = pack2(c1.z, c1.w);
      s1.x = pack2(c2.x, c2.y); s1.y = pack2(c2.z, c2.w);
      s1.z = pack2(c3.x, c3.y); s1.w = pack2(c3.z, c3.w);
      ushort_t* dst;
      if (m0 < 384)       dst = q + (size_t)pt*1152 + d*384 + mg;
      else if (m0 < 768)  dst = k + (size_t)pt*1152 + d*384 + (mg - 384);
      else                dst = v + (size_t)pt*1152 + d*384 + (mg - 768);
      *(uint4*)dst = s0;
      *(uint4*)(dst + 8) = s1;
    } else {
      int mat = mg - 1152;
      int sub = mat >> 7, o = mat & 127;
      _Float16* basep = (sub < 2) ? YZh : NBh;
      _Float16* dst = basep + (size_t)pt*768 + d*256 + (sub & 1)*128 + o;
      uint4 s0, s1;
      s0.x = packh2(c0.x, c0.y); s0.y = packh2(c0.z, c0.w);
      s0.z = packh2(c1.x, c1.y); s0.w = packh2(c1.z, c1.w);
      s1.x = packh2(c2.x, c2.y); s1.y = packh2(c2.z, c2.w);
      s1.z = packh2(c3.x, c3.y); s1.w = packh2(c3.z, c3.w);
      *(uint4*)dst = s0;
      *(uint4*)(dst + 8) = s1;
    }
  }
}

// ---------------- conv1 post ----------------
__global__ __launch_bounds__(128) void conv1_post(const _Float16* __restrict__ YZh,
    const _Float16* __restrict__ NBh, const int* __restrict__ knn_index,
    _Float16* __restrict__ kmf16) {
  int bn = blockIdx.x;
  int b = bn / NFIX, n = bn % NFIX;
  int t = threadIdx.x;
  __shared__ int sidx[KNN];
  if (t < KNN) sidx[t] = knn_index[(b*KNN + t)*NFIX + n];
  __syncthreads();
  float yb[3], zb[3];
#pragma unroll
  for (int d = 0; d < 3; ++d) {
    yb[d] = (float)NBh[(size_t)bn*768 + d*256 + t];
    zb[d] = (float)NBh[(size_t)bn*768 + d*256 + 128 + t];
  }
  float om[3] = {0.f, 0.f, 0.f};
#pragma unroll
  for (int kk = 0; kk < KNN; ++kk) {
    const _Float16* r = YZh + (size_t)sidx[kk]*768;
    float p[3], dd[3];
#pragma unroll
    for (int d = 0; d < 3; ++d) {
      p[d]  = (float)r[d*256 + t] + yb[d];
      dd[d] = (float)r[d*256 + 128 + t] + zb[d];
    }
    float res[3];
    vnleaky3(p, dd, res);
    om[0] += res[0]; om[1] += res[1]; om[2] += res[2];
  }
#pragma unroll
  for (int d = 0; d < 3; ++d)
    kmf16[((size_t)bn*3 + d)*128 + t] = (_Float16)(om[d] * (1.f/KNN));
}

// ---------------- V transpose: LDS-tiled ----------------
#define VT_LP 196
__global__ __launch_bounds__(256) void vtrans_kernel(const ushort_t* __restrict__ v,
                                                     ushort_t* __restrict__ vT) {
  __shared__ ushort_t tl[64*VT_LP];   // 25088 B
  int blk = blockIdx.x;
  int bh = blk / 32, ptile = blk % 32;
  int b = bh / HH, h = bh % HH;
  int pt0 = ptile * 64;
  int t = threadIdx.x;
#pragma unroll
  for (int i = 0; i < 6; ++i) {
    int u = i*256 + t;
    int p = u / 24, seg = u % 24;
    int d = seg >> 3, c8 = seg & 7;
    bf16x8 gv = *(const bf16x8*)&v[(size_t)(b*NFIX + pt0 + p)*1152 + d*384 + h*64 + c8*8];
    ushort_t* dst = &tl[p*VT_LP + d*64 + c8*8];
    *(bf16x4*)dst = __builtin_shufflevector(gv, gv, 0, 1, 2, 3);
    *(bf16x4*)(dst+4) = __builtin_shufflevector(gv, gv, 4, 5, 6, 7);
  }
  __syncthreads();
#pragma unroll
  for (int i = 0; i < 6; ++i) {
    int u = i*256 + t;
    int ch = u >> 3, pc = u & 7;
    int ol = ch / 3, dd = ch - 3*ol;
    int cloc = dd*64 + ol;
    ushort_t hv[8];
#pragma unroll
    for (int e = 0; e < 8; ++e)
      hv[e] = tl[(pc*8 + e)*VT_LP + cloc];
    uint4 o4;
    o4.x = (uint_t)hv[0] | ((uint_t)hv[1] << 16);
    o4.y = (uint_t)hv[2] | ((uint_t)hv[3] << 16);
    o4.z = (uint_t)hv[4] | ((uint_t)hv[5] << 16);
    o4.w = (uint_t)hv[6] | ((uint_t)hv[7] << 16);
    *(uint4*)&vT[((size_t)bh*192 + ch)*2048 + pt0 + pc*8] = o4;
  }
}

// ---------------- attention v10: r2/r5-proven body ordering + NO V LDS-staging.
// V panel (384 KB) is XCD-L2-resident (XCD-grouped decode keeps the 16 qt sharers local),
// and vT layout [bh*192+ch][key] gives each PV fragment as one contiguous 16B load.
// PV reads V direct-from-global (12 loads/iter issued before softmax -> L2 latency hides
// under exp2/pack/shfl). Removes 3 gloads + 6 ds_writes from the barrier-drain path.
// No setprio / no depth-2 prefetch (r6 A/B: both regressed). ----------------
#define KT_P 196
#define TW_P 195
__global__ __launch_bounds__(256, 2) void attn_kernel(const ushort_t* __restrict__ q,
    const ushort_t* __restrict__ k, const ushort_t* __restrict__ vT,
    ushort_t* __restrict__ opart, float* __restrict__ lpart) {
  __shared__ ushort_t kt[2][32*KT_P];   // K dbuf: 25088 B
  __shared__ ushort_t ep[2][32*KT_P];   // epilogue transpose scratch (waves 2,3): 25088 B
  __shared__ float alds[4][32];
  // XCD-aware decode: blocks round-robin XCDs by blockIdx%8. 48 (bh,split) groups, 6/XCD.
  int blk = blockIdx.x;
  int xcd = blk & 7, j = blk >> 3;          // j in 0..95
  int g = xcd*6 + (j >> 4);                 // 48 groups
  int qt = j & 15;
  int bh = g % 24;
  int split = g / 24;                       // 0..1
  int b = bh / HH, h = bh % HH;
  int t = threadIdx.x;
  int w = t >> 6, lane = t & 63, ql = lane & 31, hl = lane >> 5;
  int qrow0 = qt*128 + w*32;
  const ushort_t* qpb = q + (size_t)(b*NFIX + qrow0 + ql)*1152 + h*64;
  bf16x8 qf[12];
#pragma unroll
  for (int cs = 0; cs < 12; ++cs) {
    int red0 = cs*16 + hl*8;
    int dq = red0 >> 6, ml = red0 & 63;
    qf[cs] = *(const bf16x8*)(qpb + dq*384 + ml);
  }
  const ushort_t* ksrc[3]; int kdsto[3];
#pragma unroll
  for (int j2 = 0; j2 < 3; ++j2) {
    int idx = t + j2*256;
    int kp = idx / 24, c16 = idx % 24;
    int red0 = c16*8;
    int dk = red0 >> 6, ml = red0 & 63;
    ksrc[j2] = k + (size_t)(b*NFIX + kp)*1152 + dk*384 + h*64 + ml;
    kdsto[j2] = kp*KT_P + c16*8;
  }
  int koff0 = split * 1024;                 // 1024 keys per split, 32 K-tiles
  // per-lane V base: row = bh*192 + nt*32 + ql, col = koff0 + kb*32 + s*16 + hl*8
  const ushort_t* vgb = vT + ((size_t)bh*192 + ql)*2048 + koff0 + hl*8;
  f32x16 acc[6];
#pragma unroll
  for (int nt = 0; nt < 6; ++nt)
#pragma unroll
    for (int r = 0; r < 16; ++r) acc[nt][r] = 0.f;
  float lsum = 0.f;
  bf16x8 kpre[3];
#pragma unroll
  for (int j2 = 0; j2 < 3; ++j2)
    kpre[j2] = *(const bf16x8*)(ksrc[j2] + (size_t)koff0*1152);
#pragma unroll
  for (int j2 = 0; j2 < 3; ++j2) {
    ushort_t* kd = &kt[0][kdsto[j2]];
    *(bf16x4*)kd = __builtin_shufflevector(kpre[j2], kpre[j2], 0, 1, 2, 3);
    *(bf16x4*)(kd+4) = __builtin_shufflevector(kpre[j2], kpre[j2], 4, 5, 6, 7);
  }
  __syncthreads();
  for (int kb = 0; kb < 32; ++kb) {
    int cur = kb & 1;
    if (kb < 31) {
      int koff = koff0 + (kb+1)*32;
#pragma unroll
      for (int j2 = 0; j2 < 3; ++j2)
        kpre[j2] = *(const bf16x8*)(ksrc[j2] + (size_t)koff*1152);
    }
    // S = (K q-scaled) dot Q : 12 MFMA from kt[cur]
    f32x16 sc;
#pragma unroll
    for (int r = 0; r < 16; ++r) sc[r] = 0.f;
    const ushort_t* ktc = kt[cur];
#pragma unroll
    for (int cs = 0; cs < 12; ++cs) {
      const ushort_t* kr = &ktc[ql*KT_P + cs*16 + hl*8];
      bf16x4 alo = *(const bf16x4*)kr;
      bf16x4 ahi = *(const bf16x4*)(kr + 4);
      bf16x8 af = __builtin_shufflevector(alo, ahi, 0, 1, 2, 3, 4, 5, 6, 7);
      sc = __builtin_amdgcn_mfma_f32_32x32x16_bf16(af, qf[cs], sc, 0, 0, 0);
    }
    // issue V fragment loads for THIS tile (L2-hit; latency hides under softmax)
    bf16x8 vfr[12];
#pragma unroll
    for (int nt = 0; nt < 6; ++nt) {
#pragma unroll
      for (int s = 0; s < 2; ++s)
        vfr[nt*2+s] = *(const bf16x8*)(vgb + (size_t)nt*32*2048 + kb*32 + s*16);
    }
    uint_t u[8], pex[8];
#pragma unroll
    for (int g2 = 0; g2 < 4; ++g2) {
      float p0 = __builtin_amdgcn_exp2f(sc[g2*4 + 0]);
      float p1 = __builtin_amdgcn_exp2f(sc[g2*4 + 1]);
      float p2 = __builtin_amdgcn_exp2f(sc[g2*4 + 2]);
      float p3 = __builtin_amdgcn_exp2f(sc[g2*4 + 3]);
      lsum += (p0 + p1) + (p2 + p3);
      u[2*g2]   = pack2(p0, p1);
      u[2*g2+1] = pack2(p2, p3);
    }
#pragma unroll
    for (int j2 = 0; j2 < 8; ++j2) pex[j2] = (uint_t)__shfl_xor((int)u[j2], 32);
#pragma unroll
    for (int s = 0; s < 2; ++s) {
      uint4 au;
      au.x = hl ? pex[4*s+2] : u[4*s+0];
      au.y = hl ? pex[4*s+3] : u[4*s+1];
      au.z = hl ? u[4*s+2]   : pex[4*s+0];
      au.w = hl ? u[4*s+3]   : pex[4*s+1];
      union { uint4 ui; bf16x8 bv; } cvt; cvt.ui = au;
      bf16x8 pa = cvt.bv;
#pragma unroll
      for (int nt = 0; nt < 6; ++nt)
        acc[nt] = __builtin_amdgcn_mfma_f32_32x32x16_bf16(pa, vfr[nt*2+s], acc[nt], 0, 0, 0);
    }
    if (kb < 31) {
      int nxt = cur ^ 1;
#pragma unroll
      for (int j2 = 0; j2 < 3; ++j2) {
        ushort_t* kd = &kt[nxt][kdsto[j2]];
        *(bf16x4*)kd = __builtin_shufflevector(kpre[j2], kpre[j2], 0, 1, 2, 3);
        *(bf16x4*)(kd+4) = __builtin_shufflevector(kpre[j2], kpre[j2], 4, 5, 6, 7);
      }
    }
    __syncthreads();
  }
  lsum += __shfl_xor(lsum, 32);
  if (lane < 32) {
    alds[w][ql] = 1.0f / lsum;
    lpart[(size_t)split*24*NFIX + (size_t)bh*NFIX + qrow0 + ql] = lsum;
  }
  asm volatile("s_waitcnt lgkmcnt(0)" ::: "memory");
  float lv[4][4];
#pragma unroll
  for (int g2 = 0; g2 < 4; ++g2) {
    f32x4 tv = *(const f32x4*)&alds[w][8*g2 + 4*hl];
#pragma unroll
    for (int rr = 0; rr < 4; ++rr) lv[g2][rr] = tv[rr];
  }
  // ---- epilogue: O_s stored as f16 bits (split-combine precision) ----
  ushort_t* tw = (w == 0) ? kt[0] : (w == 1) ? kt[1] : (w == 2) ? ep[0] : ep[1];
#pragma unroll
  for (int nt = 0; nt < 6; ++nt) {
    int ch = nt*32 + ql;
#pragma unroll
    for (int r = 0; r < 16; ++r) {
      int qrow = (r&3) + 8*(r>>2) + 4*hl;
      tw[qrow*TW_P + ch] = f2h_bits(acc[nt][r] * lv[r>>2][r&3]);
    }
  }
  asm volatile("s_waitcnt lgkmcnt(0)" ::: "memory");
  const size_t SS = (size_t)8192*1152;
  ushort_t* opb = opart + (size_t)split*SS;
  size_t nbase = (size_t)(b*NFIX + qrow0) * 3;
#pragma unroll
  for (int i = 0; i < 12; ++i) {
    int chunk = i*64 + lane;
    int nl = chunk >> 3, jc = chunk & 7;
    int qq = nl / 3, dd = nl - 3*qq;
    ushort_t hv[8];
#pragma unroll
    for (int e = 0; e < 8; ++e)
      hv[e] = tw[qq*TW_P + (jc*8 + e)*3 + dd];
    uint4 sv;
    sv.x = (uint_t)hv[0] | ((uint_t)hv[1] << 16);
    sv.y = (uint_t)hv[2] | ((uint_t)hv[3] << 16);
    sv.z = (uint_t)hv[4] | ((uint_t)hv[5] << 16);
    sv.w = (uint_t)hv[6] | ((uint_t)hv[7] << 16);
    *(uint4*)&opb[(nbase + nl)*384 + h*64 + jc*8] = sv;
  }
}

// ---------------- x1mid fp16 MFMA + fused LN2 -> xmid (f32) and nxh (f16) ----------------
#define AP 68
#define XLP 132
__global__ __launch_bounds__(384) void x1mid_mfma(
    const float* __restrict__ xdi, const ushort_t* __restrict__ opart,
    const float* __restrict__ lpart, const _Float16* __restrict__ kmf16,
    const _Float16* __restrict__ Af16, float* __restrict__ xmid,
    _Float16* __restrict__ nxh, const float* __restrict__ g2,
    const float* __restrict__ b2) {
  __shared__ __align__(16) char smem[50944];
  _Float16* As = (_Float16*)smem;                 // 128 x AP = 17408 B
  _Float16* Bt = (_Float16*)(smem + 17408);       //  96 x AP = 13056 B
  float* wlsL  = (float*)(smem + 30464);          //  32 x 6 x 2 = 1536 B
  float* X     = (float*)smem;                    // epilogue overlay: 96 x XLP f32 = 50688 B
  float* stats = (float*)(smem + 50688);          // 32 x 2 f32 = 256 B
  int blk = blockIdx.x;
  int n0 = blk * 96;
  int pt0 = blk * 32;
  int t = threadIdx.x;
  int w = t >> 6, lane = t & 63, ql = lane & 31, hl = lane >> 5;
  int nsub = w >> 1, mh = w & 1;
  if (t < 192) {
    int ptl = t / 6, h = t % 6;
    int ptg = pt0 + ptl;
    int b = ptg >> 11, n = ptg & 2047;
    size_t lidx = (size_t)(b*HH + h)*NFIX + n;
    float l[NSPLIT]; float tot = 0.f;
#pragma unroll
    for (int s = 0; s < NSPLIT; ++s) {
      l[s] = lpart[(size_t)s*24*NFIX + lidx];
      tot += l[s];
    }
    float rd = 1.f / tot;
    float* wp = &wlsL[(ptl*6 + h)*NSPLIT];
#pragma unroll
    for (int s = 0; s < NSPLIT; ++s) wp[s] = l[s]*rd;
  }
  f32x16 acc[2];
#pragma unroll
  for (int m2 = 0; m2 < 2; ++m2)
#pragma unroll
    for (int r = 0; r < 16; ++r) acc[m2][r] = 0.f;
  const size_t SS = (size_t)8192*1152;
  __syncthreads();
  for (int p = 0; p < 8; ++p) {
    for (int u = t; u < 1024; u += 384) {
      int m = u >> 3, kc = u & 7;
      f16x4 a0 = *(const f16x4*)&Af16[(size_t)m*512 + p*64 + kc*8];
      f16x4 a1 = *(const f16x4*)&Af16[(size_t)m*512 + p*64 + kc*8 + 4];
      _Float16* dst = &As[m*AP + kc*8];
      *(f16x4*)dst = a0;
      *(f16x4*)(dst+4) = a1;
    }
    {
      int u = t;
      if (u < 384) {
        int n_l = u >> 2, jc = u & 3;
        int n_g = n0 + n_l;
        _Float16* dst = &Bt[n_l*AP + jc*16];
        if (p < 6) {
          int pt_l = n_l / 3;
          const float* wp = &wlsL[(pt_l*6 + p)*NSPLIT];
          float facc[16];
#pragma unroll
          for (int e = 0; e < 16; ++e) facc[e] = 0.f;
#pragma unroll
          for (int s = 0; s < NSPLIT; ++s) {
            const ushort_t* src = opart + s*SS + (size_t)n_g*384 + p*64 + jc*16;
            uint4 ra = *(const uint4*)src;
            uint4 rb = *(const uint4*)(src + 8);
            const _Float16* ua = (const _Float16*)&ra;
            const _Float16* ub = (const _Float16*)&rb;
            float wsc = wp[s];
#pragma unroll
            for (int e = 0; e < 8; ++e) {
              facc[e]     += wsc * (float)ua[e];
              facc[8 + e] += wsc * (float)ub[e];
            }
          }
          _Float16 hv[16];
#pragma unroll
          for (int e = 0; e < 16; ++e) hv[e] = (_Float16)facc[e];
#pragma unroll
          for (int g = 0; g < 4; ++g)
            *(f16x4*)(dst + g*4) = *(f16x4*)&hv[g*4];
        } else {
          const _Float16* src = kmf16 + (size_t)n_g*128 + (p-6)*64 + jc*16;
          f16x4 v0 = *(const f16x4*)src;
          f16x4 v1 = *(const f16x4*)(src + 4);
          f16x4 v2 = *(const f16x4*)(src + 8);
          f16x4 v3 = *(const f16x4*)(src + 12);
          *(f16x4*)dst = v0; *(f16x4*)(dst+4) = v1;
          *(f16x4*)(dst+8) = v2; *(f16x4*)(dst+12) = v3;
        }
      }
    }
    __syncthreads();
#pragma unroll
    for (int cs = 0; cs < 4; ++cs) {
      int kloc = cs*16 + hl*8;
      f16x4 b0 = *(const f16x4*)&Bt[(nsub*32 + ql)*AP + kloc];
      f16x4 b1 = *(const f16x4*)&Bt[(nsub*32 + ql)*AP + kloc + 4];
      f16x8 bf = __builtin_shufflevector(b0, b1, 0, 1, 2, 3, 4, 5, 6, 7);
#pragma unroll
      for (int m2 = 0; m2 < 2; ++m2) {
        int mrow = (mh*2 + m2)*32 + ql;
        f16x4 a0 = *(const f16x4*)&As[mrow*AP + kloc];
        f16x4 a1 = *(const f16x4*)&As[mrow*AP + kloc + 4];
        f16x8 af = __builtin_shufflevector(a0, a1, 0, 1, 2, 3, 4, 5, 6, 7);
        acc[m2] = __builtin_amdgcn_mfma_f32_32x32x16_f16(af, bf, acc[m2], 0, 0, 0);
      }
    }
    __syncthreads();
  }
  // ---- write acc directly into X (C frag: n = nsub*32+ql, c = mtile*32 + (r&3)+8*(r>>2)+4*hl) ----
#pragma unroll
  for (int m2 = 0; m2 < 2; ++m2) {
    int cbase = (mh*2 + m2)*32 + 4*hl;
    float* xrow = &X[(nsub*32 + ql)*XLP];
#pragma unroll
    for (int r = 0; r < 16; ++r) {
      int col = cbase + (r&3) + 8*(r>>2);
      xrow[col] = acc[m2][r];
    }
  }
  __syncthreads();
  // ---- Phase A: add residual (post-residual stays in X), emit xmid global ----
#pragma unroll
  for (int i = 0; i < 4; ++i) {
    int u = i*384 + t;                  // 96 rows x 16 chunks of 8
    int row = u >> 4, c0 = (u & 15) * 8;
    float* xp = &X[row*XLP + c0];
    const float* xd = xdi + (size_t)(n0 + row)*128 + c0;
    float4 a0 = *(float4*)xp, a1 = *(float4*)(xp + 4);
    float4 d0 = *(const float4*)xd, d1 = *(const float4*)(xd + 4);
    a0.x += d0.x; a0.y += d0.y; a0.z += d0.z; a0.w += d0.w;
    a1.x += d1.x; a1.y += d1.y; a1.z += d1.z; a1.w += d1.w;
    *(float4*)xp = a0; *(float4*)(xp + 4) = a1;
    float* dst = xmid + (size_t)(n0 + row)*128 + c0;
    *(float4*)dst = a0; *(float4*)(dst + 4) = a1;
  }
  __syncthreads();
  // ---- Phase B: per-point LN stats (6 waves cover 32 points) ----
  for (int pi = w; pi < 32; pi += 6) {
    int c = lane;
    float a0 = X[(pi*3+0)*XLP + c], a1 = X[(pi*3+1)*XLP + c], a2 = X[(pi*3+2)*XLP + c];
    float e0 = X[(pi*3+0)*XLP + c + 64], e1 = X[(pi*3+1)*XLP + c + 64], e2 = X[(pi*3+2)*XLP + c + 64];
    float nva = sqrtf(a0*a0 + a1*a1 + a2*a2 + EPSF);
    float nvb = sqrtf(e0*e0 + e1*e1 + e2*e2 + EPSF);
    float s1 = nva + nvb;
    float s2 = nva*nva + nvb*nvb;
#pragma unroll
    for (int off = 32; off >= 1; off >>= 1) {
      s1 += __shfl_down(s1, off);
      s2 += __shfl_down(s2, off);
    }
    if (lane == 0) {
      float mu = s1 * (1.f/128.f);
      float var = s2 * (1.f/128.f) - mu*mu;
      stats[pi*2]   = mu;
      stats[pi*2+1] = rsqrtf(var + LNEPSF);
    }
  }
  __syncthreads();
  // ---- Phase C: emit nxh f16 (LN2-normalized) ----
#pragma unroll
  for (int i = 0; i < 4; ++i) {
    int u = i*384 + t;
    int row = u >> 4, c0 = (u & 15) * 8;
    int pt_l = row / 3;
    float mu = stats[pt_l*2], rsig = stats[pt_l*2+1];
    const float* r0 = &X[(pt_l*3 + 0)*XLP + c0];
    const float* r1 = &X[(pt_l*3 + 1)*XLP + c0];
    const float* r2 = &X[(pt_l*3 + 2)*XLP + c0];
    const float* rd = &X[row*XLP + c0];
    float xv[8];
#pragma unroll
    for (int e = 0; e < 8; ++e) {
      float x0 = r0[e], x1 = r1[e], x2 = r2[e];
      float nv = sqrtf(x0*x0 + x1*x1 + x2*x2 + EPSF);
      float nnew = g2[c0 + e] * ((nv - mu) * rsig) + b2[c0 + e];
      xv[e] = rd[e] * (nnew / nv);
    }
    uint4 sv;
    sv.x = packh2(xv[0], xv[1]); sv.y = packh2(xv[2], xv[3]);
    sv.z = packh2(xv[4], xv[5]); sv.w = packh2(xv[6], xv[7]);
    *(uint4*)&nxh[(size_t)(n0 + row)*128 + c0] = sv;
  }
}

// ---------------- conv3: f16 MFMA, 3 d-plane GEMMs/wave ----------------
#define X3P 132
#define TR3P 36
__global__ __launch_bounds__(256) void conv3_mfma(const _Float16* __restrict__ nxh,
    const _Float16* __restrict__ W3h, const _Float16* __restrict__ U3h,
    _Float16* __restrict__ h3) {
  __shared__ __align__(16) _Float16 Xs[3*32*X3P];     // 25344 B
  __shared__ __align__(16) _Float16 tr3[4][96*TR3P];  // 27648 B
  int blk = blockIdx.x;
  int pt0 = (blk >> 1) * 32;
  int oh = blk & 1;
  int t = threadIdx.x;
  int w = t >> 6, lane = t & 63, ql = lane & 31, hl = lane >> 5;
#pragma unroll
  for (int i = 0; i < 6; ++i) {
    int u = i*256 + t;
    int r = u >> 4, c8 = u & 15;
    f16x8 gv = *(const f16x8*)&nxh[(size_t)(pt0*3 + r)*128 + c8*8];
    int d = r % 3, p = r / 3;
    _Float16* dst = &Xs[(d*32 + p)*X3P + c8*8];
    *(f16x4*)dst = __builtin_shufflevector(gv, gv, 0, 1, 2, 3);
    *(f16x4*)(dst+4) = __builtin_shufflevector(gv, gv, 4, 5, 6, 7);
  }
  __syncthreads();
  int ot = oh*128 + w*32;
  const _Float16* Wp = W3h + (size_t)(ot + ql)*128 + hl*8;
  const _Float16* Up = U3h + (size_t)(ot + ql)*128 + hl*8;
  f32x16 accP[3], accD[3];
#pragma unroll
  for (int d = 0; d < 3; ++d)
#pragma unroll
    for (int r = 0; r < 16; ++r) { accP[d][r] = 0.f; accD[d][r] = 0.f; }
#pragma unroll
  for (int cs = 0; cs < 8; ++cs) {
    f16x8 wf = *(const f16x8*)(Wp + cs*16);
    f16x8 uf = *(const f16x8*)(Up + cs*16);
#pragma unroll
    for (int d = 0; d < 3; ++d) {
      const _Float16* xr = &Xs[(d*32 + ql)*X3P + cs*16 + hl*8];
      f16x4 lo = *(const f16x4*)xr;
      f16x4 hi = *(const f16x4*)(xr + 4);
      f16x8 xf = __builtin_shufflevector(lo, hi, 0, 1, 2, 3, 4, 5, 6, 7);
      accP[d] = __builtin_amdgcn_mfma_f32_32x32x16_f16(wf, xf, accP[d], 0, 0, 0);
      accD[d] = __builtin_amdgcn_mfma_f32_32x32x16_f16(uf, xf, accD[d], 0, 0, 0);
    }
  }
  _Float16* trw = tr3[w];
#pragma unroll
  for (int r = 0; r < 16; ++r) {
    int olr = (r&3) + 8*(r>>2) + 4*hl;
    float p3[3], d3[3], res[3];
#pragma unroll
    for (int d = 0; d < 3; ++d) { p3[d] = accP[d][r]; d3[d] = accD[d][r]; }
    vnleaky3(p3, d3, res);
#pragma unroll
    for (int d = 0; d < 3; ++d) trw[(ql*3 + d)*TR3P + olr] = (_Float16)res[d];
  }
  asm volatile("s_waitcnt lgkmcnt(0)" ::: "memory");
#pragma unroll
  for (int i = 0; i < 6; ++i) {
    int u = i*64 + lane;
    int row = u >> 2, c8 = u & 3;
    const _Float16* src = &trw[row*TR3P + c8*8];
    f16x4 lo = *(const f16x4*)src;
    f16x4 hi = *(const f16x4*)(src + 4);
    f16x8 ov = __builtin_shufflevector(lo, hi, 0, 1, 2, 3, 4, 5, 6, 7);
    *(f16x8*)&h3[(size_t)(pt0*3 + row)*256 + ot + c8*8] = ov;
  }
}

// ---------------- conv4: f16 MFMA (16x16x32), + xmid residual ----------------
#define X4P 260
#define TF4P 388
__global__ __launch_bounds__(256) void conv4_mfma(const _Float16* __restrict__ h3,
    const _Float16* __restrict__ W4h, const _Float16* __restrict__ U4h,
    const float* __restrict__ xmid, float* __restrict__ out) {
  __shared__ __align__(16) _Float16 Xs[3*16*X4P];   // 24960 B
  __shared__ __align__(16) float trF[16*TF4P];      // 24832 B
  int pt0 = blockIdx.x * 16;
  int t = threadIdx.x;
  int w = t >> 6, lane = t & 63;
  int nl = lane & 15, kq = lane >> 4;
#pragma unroll
  for (int i = 0; i < 6; ++i) {
    int u = i*256 + t;
    int r = u >> 5, c8 = u & 31;
    f16x8 gv = *(const f16x8*)&h3[(size_t)(pt0*3 + r)*256 + c8*8];
    int d = r % 3, p = r / 3;
    _Float16* dst = &Xs[(d*16 + p)*X4P + c8*8];
    *(f16x4*)dst = __builtin_shufflevector(gv, gv, 0, 1, 2, 3);
    *(f16x4*)(dst+4) = __builtin_shufflevector(gv, gv, 4, 5, 6, 7);
  }
  __syncthreads();
  int ot = w*32;
  f32x4 accP[2][3], accD[2][3];
#pragma unroll
  for (int mt = 0; mt < 2; ++mt)
#pragma unroll
    for (int d = 0; d < 3; ++d)
#pragma unroll
      for (int r = 0; r < 4; ++r) { accP[mt][d][r] = 0.f; accD[mt][d][r] = 0.f; }
  const _Float16* Wb = W4h + (size_t)ot*256;
  const _Float16* Ub = U4h + (size_t)ot*256;
#pragma unroll
  for (int cs = 0; cs < 8; ++cs) {
    int kof = cs*32 + kq*8;
    f16x8 xf[3];
#pragma unroll
    for (int d = 0; d < 3; ++d) {
      const _Float16* xr = &Xs[(d*16 + nl)*X4P + kof];
      f16x4 lo = *(const f16x4*)xr;
      f16x4 hi = *(const f16x4*)(xr + 4);
      xf[d] = __builtin_shufflevector(lo, hi, 0, 1, 2, 3, 4, 5, 6, 7);
    }
#pragma unroll
    for (int mt = 0; mt < 2; ++mt) {
      f16x8 wf = *(const f16x8*)(Wb + (size_t)(mt*16 + nl)*256 + kof);
      f16x8 uf = *(const f16x8*)(Ub + (size_t)(mt*16 + nl)*256 + kof);
#pragma unroll
      for (int d = 0; d < 3; ++d) {
        accP[mt][d] = __builtin_amdgcn_mfma_f32_16x16x32_f16(wf, xf[d], accP[mt][d], 0, 0, 0);
        accD[mt][d] = __builtin_amdgcn_mfma_f32_16x16x32_f16(uf, xf[d], accD[mt][d], 0, 0, 0);
      }
    }
  }
#pragma unroll
  for (int mt = 0; mt < 2; ++mt)
#pragma unroll
    for (int r = 0; r < 4; ++r) {
      int o = ot + mt*16 + kq*4 + r;
      float p3[3], d3[3], res[3];
#pragma unroll
      for (int d = 0; d < 3; ++d) { p3[d] = accP[mt][d][r]; d3[d] = accD[mt][d][r]; }
      vnleaky3(p3, d3, res);
#pragma unroll
      for (int d = 0; d < 3; ++d) trF[nl*TF4P + o*3 + d] = res[d];
    }
  __syncthreads();
#pragma unroll
  for (int i = 0; i < 6; ++i) {
    int u = i*256 + t;
    int row = u / 96, c4 = u % 96;
    float4 vv = *(float4*)&trF[row*TF4P + c4*4];
    int bn = pt0 + row;
    float rs[4];
    const float* fv = (const float*)&vv;
#pragma unroll
    for (int e = 0; e < 4; ++e) {
      int col = c4*4 + e;
      int o = col / 3, d = col - 3*o;
      rs[e] = fv[e] + xmid[(size_t)(3*bn + d)*128 + o];
    }
    float4 ov; ov.x = rs[0]; ov.y = rs[1]; ov.z = rs[2]; ov.w = rs[3];
    *(float4*)&out[(size_t)bn*384 + c4*4] = ov;
  }
}

extern "C" void kernel_launch(void* const* d_in, const int* in_sizes, int n_in,
                              void* d_out, int out_size, void* d_ws, size_t ws_size,
                              hipStream_t stream) {
  const float* x   = (const float*)d_in[0];
  const int* knn   = (const int*)d_in[1];
  const float* g1  = (const float*)d_in[2];
  const float* b1  = (const float*)d_in[3];
  const float* g2  = (const float*)d_in[4];
  const float* b2  = (const float*)d_in[5];
  const float* Wq  = (const float*)d_in[6];
  const float* Wk  = (const float*)d_in[7];
  const float* Wv  = (const float*)d_in[8];
  const float* Wo  = (const float*)d_in[9];
  const float* W1  = (const float*)d_in[10];
  const float* U1  = (const float*)d_in[11];
  const float* W2  = (const float*)d_in[12];
  const float* W3  = (const float*)d_in[13];
  const float* U3  = (const float*)d_in[14];
  const float* W4  = (const float*)d_in[15];
  const float* U4  = (const float*)d_in[16];
  float* out = (float*)d_out;
  (void)n_in; (void)out_size; (void)ws_size;

  const size_t BN = (size_t)in_sizes[0] / 384;   // 8192

  float* ws    = (float*)d_ws;
  float* xdi   = ws;                          // BN*384 f32 (raw x, de-interleaved [n][c])
  float* xmid  = xdi + BN*384;                // BN*384 f32 (x_mid, de-interleaved)
  _Float16* kmf16 = (_Float16*)(xmid + BN*384);  // BN*384 fp16 [n][128]
  ushort_t* xbp = (ushort_t*)(kmf16 + BN*384);   // BN*384 bf16 (LN1 normalized, de-interleaved)
  ushort_t* qb = xbp + BN*384;                // BN*1152 bf16
  ushort_t* kb = qb + BN*1152;
  ushort_t* vb = kb + BN*1152;
  ushort_t* vT = vb + BN*1152;
  ushort_t* Wall = vT + BN*1152;              // 212992 bf16
  _Float16* Af16 = (_Float16*)(Wall + 212992);   // 65536 fp16
  _Float16* W3h = Af16 + 65536;               // 32768 fp16
  _Float16* U3h = W3h + 32768;
  _Float16* W4h = U3h + 32768;
  _Float16* U4h = W4h + 32768;
  ushort_t* opart = (ushort_t*)(U4h + 32768); // region 4*BN*1152 (2 splits used)
  float* lpart = (float*)(opart + 4*BN*1152); // 2*24*2048 f32
  // YZh/NBh (BN*768 f16 each = 12.6 MB) alias the opart region: conv1_post runs before attn.
  _Float16* YZh = (_Float16*)opart;
  _Float16* NBh = YZh + BN*768;
  _Float16* nxh = (_Float16*)qb;   // q dead after x1mid; LN2 out f16 [ng][128]
  _Float16* h3  = (_Float16*)kb;   // k dead after attention; conv3 out f16 [ng][256]

  prep_weights<<<1600, 256, 0, stream>>>(Wq, Wk, Wv, Wo, W1, U1, W2, W3, U3, W4, U4,
                                         Wall, Af16, W3h, U3h, W4h, U4h);
  ln1_kernel<<<(int)BN, 128, 0, stream>>>(x, xbp, xdi, g1, b1);
  qkv_conv1_mfma<<<192*4, 256, 0, stream>>>(xbp, Wall, qb, kb, vb, YZh, NBh);
  conv1_post<<<(int)BN, 128, 0, stream>>>(YZh, NBh, knn, kmf16);
  vtrans_kernel<<<768, 256, 0, stream>>>(vb, vT);
  attn_kernel<<<16*24*NSPLIT, 256, 0, stream>>>(qb, kb, vT, opart, lpart);
  x1mid_mfma<<<256, 384, 0, stream>>>(xdi, opart, lpart, kmf16, Af16, xmid, nxh, g2, b2);
  conv3_mfma<<<512, 256, 0, stream>>>(nxh, W3h, U3h, h3);
  conv4_mfma<<<512, 256, 0, stream>>>(h3, W4h, U4h, xmid, out);
}

// Round 8
// 330.867 us; speedup vs baseline: 1.1959x; 1.1959x over previous
//
#include <hip/hip_runtime.h>
#include <math.h>

// Problem constants (fixed by setup_inputs): B=4, N=2048, C=128, H=6, K=8
#define NFIX 2048
#define HH 6
#define KNN 8
#define NSLOPE 0.2f
#define EPSF 1e-6f
#define LNEPSF 1e-5f
// 0.125 (softmax scale) * log2(e), folded into Wq rows so S-MFMA output is exp2-ready
#define QSCALE 0.18033688011112042f
#define NSPLIT 2

typedef unsigned short ushort_t;
typedef unsigned int uint_t;
typedef __attribute__((ext_vector_type(8))) short bf16x8;
typedef __attribute__((ext_vector_type(4))) short bf16x4;
typedef __attribute__((ext_vector_type(8))) _Float16 f16x8;
typedef __attribute__((ext_vector_type(4))) _Float16 f16x4;
typedef __attribute__((ext_vector_type(16))) float f32x16;
typedef __attribute__((ext_vector_type(4))) float f32x4;

__device__ __forceinline__ ushort_t f2bf(float f) {
  union { float f; unsigned u; } v; v.f = f;
  unsigned r = v.u + 0x7fff + ((v.u >> 16) & 1);   // RNE
  return (ushort_t)(r >> 16);
}
__device__ __forceinline__ float bf2f(ushort_t u) {
  union { uint_t u; float f; } v; v.u = ((uint_t)u) << 16; return v.f;
}
__device__ __forceinline__ uint_t pack2(float a, float b) {
  return (uint_t)f2bf(a) | ((uint_t)f2bf(b) << 16);
}
// f32 -> f16 bit pattern (register-only)
__device__ __forceinline__ ushort_t f2h_bits(float a) {
  union { _Float16 h; ushort_t s; } cv; cv.h = (_Float16)a; return cv.s;
}
// pack two fp32 -> two f16 in one dword (register-only; no local-array aliasing)
__device__ __forceinline__ uint_t packh2(float a, float b) {
  union { _Float16 h; ushort_t s; } ha, hb;
  ha.h = (_Float16)a; hb.h = (_Float16)b;
  return (uint_t)ha.s | ((uint_t)hb.s << 16);
}

__device__ __forceinline__ void vnleaky3(const float* p, const float* dv, float* out) {
  float dot = p[0]*dv[0] + p[1]*dv[1] + p[2]*dv[2];
  float dsq = dv[0]*dv[0] + dv[1]*dv[1] + dv[2]*dv[2] + EPSF;
  float f = dot / dsq;
#pragma unroll
  for (int d = 0; d < 3; ++d) {
    float neg = p[d] - f * dv[d];
    out[d] = NSLOPE * p[d] + (1.f - NSLOPE) * ((dot >= 0.f) ? p[d] : neg);
  }
}

// ---------------- weight prep ----------------
__global__ void prep_weights(const float* __restrict__ Wq, const float* __restrict__ Wk,
                             const float* __restrict__ Wv, const float* __restrict__ Wo,
                             const float* __restrict__ W1, const float* __restrict__ U1,
                             const float* __restrict__ W2, const float* __restrict__ W3,
                             const float* __restrict__ U3, const float* __restrict__ W4,
                             const float* __restrict__ U4,
                             ushort_t* __restrict__ Wall, _Float16* __restrict__ Af16,
                             _Float16* __restrict__ W3h, _Float16* __restrict__ U3h,
                             _Float16* __restrict__ W4h, _Float16* __restrict__ U4h) {
  int idx = blockIdx.x * 256 + threadIdx.x;
  if (idx < 212992) {
    int m = idx >> 7, c = idx & 127;
    float val;
    if (m < 384)       val = Wq[m*128 + c] * QSCALE;
    else if (m < 768)  val = Wk[(m-384)*128 + c];
    else if (m < 1152) val = Wv[(m-768)*128 + c];
    else {
      int j = m - 1152;
      if (j < 128)      val = W1[j*256 + c];
      else if (j < 256) val = U1[(j-128)*256 + c];
      else if (j < 384) { int o = j-256; val = W1[o*256 + 128 + c] - W1[o*256 + c]; }
      else              { int o = j-384; val = U1[o*256 + 128 + c] - U1[o*256 + c]; }
    }
    Wall[idx] = f2bf(val); return;
  }
  idx -= 212992;
  if (idx < 49152) {
    int j = idx / 128, c = idx % 128;   // M2[c][j] = (W2a@Wo)[c][j]
    float s = 0.f;
    for (int cp = 0; cp < 128; ++cp) s += W2[c*256 + cp] * Wo[cp*384 + j];
    Af16[(size_t)c*512 + j] = (_Float16)s; return;
  }
  idx -= 49152;
  if (idx < 16384) {
    int c2 = idx / 128, c = idx % 128;
    Af16[(size_t)c*512 + 384 + c2] = (_Float16)W2[c*256 + 128 + c2]; return;
  }
  idx -= 16384;
  if (idx < 32768) { W3h[idx] = (_Float16)W3[idx]; return; }
  idx -= 32768;
  if (idx < 32768) { U3h[idx] = (_Float16)U3[idx]; return; }
  idx -= 32768;
  if (idx < 32768) { W4h[idx] = (_Float16)W4[idx]; return; }
  idx -= 32768;
  if (idx < 32768) { U4h[idx] = (_Float16)U4[idx]; return; }
}

// ---------------- LN1 ----------------
__global__ __launch_bounds__(128) void ln1_kernel(const float* __restrict__ in,
                                                  ushort_t* __restrict__ xbp,
                                                  float* __restrict__ xdi,
                                                  const float* __restrict__ g,
                                                  const float* __restrict__ b) {
  int bn = blockIdx.x;
  int c = threadIdx.x;
  const float* row = in + (size_t)bn * 384;
  float x0 = row[c*3+0], x1 = row[c*3+1], x2 = row[c*3+2];
  float nv = sqrtf(x0*x0 + x1*x1 + x2*x2 + EPSF);
  float s1 = nv, s2 = nv*nv;
#pragma unroll
  for (int off = 32; off >= 1; off >>= 1) {
    s1 += __shfl_down(s1, off);
    s2 += __shfl_down(s2, off);
  }
  __shared__ float red[4];
  int lane = threadIdx.x & 63, w = threadIdx.x >> 6;
  if (lane == 0) { red[w*2] = s1; red[w*2+1] = s2; }
  __syncthreads();
  float tot1 = red[0] + red[2], tot2 = red[1] + red[3];
  float mu  = tot1 * (1.f/128.f);
  float var = tot2 * (1.f/128.f) - mu*mu;
  float rsig = rsqrtf(var + LNEPSF);
  float nnew = g[c] * ((nv - mu) * rsig) + b[c];
  float sc = nnew / nv;
  size_t rb = (size_t)bn * 384;
  xbp[rb + c]       = f2bf(x0*sc);
  xbp[rb + 128 + c] = f2bf(x1*sc);
  xbp[rb + 256 + c] = f2bf(x2*sc);
  xdi[rb + c]       = x0;
  xdi[rb + 128 + c] = x1;
  xdi[rb + 256 + c] = x2;
}

// ---------------- fused QKV + conv1 MFMA GEMM ----------------
#define XT_PITCH 132
#define WT_PITCH 132
#define TR_PITCH 36
__global__ __launch_bounds__(256, 2) void qkv_conv1_mfma(
    const ushort_t* __restrict__ xb, const ushort_t* __restrict__ Wall,
    ushort_t* __restrict__ q, ushort_t* __restrict__ k, ushort_t* __restrict__ v,
    _Float16* __restrict__ YZh, _Float16* __restrict__ NBh) {
  __shared__ ushort_t xs[128*XT_PITCH];
  __shared__ ushort_t wt[32*WT_PITCH];
  __shared__ float tr[4][32*TR_PITCH];
  int nb = blockIdx.x % 192;
  int mq = blockIdx.x / 192;
  int n0 = nb * 128;
  int t = threadIdx.x;
  int w = t >> 6, lane = t & 63, ql = lane & 31, hl = lane >> 5;
  for (int idx = t; idx < 2048; idx += 256) {
    int n = idx >> 4, c16 = idx & 15;
    bf16x8 gv = *(const bf16x8*)&xb[(size_t)(n0 + n)*128 + c16*8];
    ushort_t* dst = &xs[n*XT_PITCH + c16*8];
    *(bf16x4*)dst = __builtin_shufflevector(gv, gv, 0, 1, 2, 3);
    *(bf16x4*)(dst+4) = __builtin_shufflevector(gv, gv, 4, 5, 6, 7);
  }
  __syncthreads();
  bf16x8 xf[8];
  {
    const ushort_t* xr = &xs[(w*32 + ql)*XT_PITCH + hl*8];
#pragma unroll
    for (int cs = 0; cs < 8; ++cs) {
      bf16x4 lo = *(const bf16x4*)(xr + cs*16);
      bf16x4 hi = *(const bf16x4*)(xr + cs*16 + 4);
      xf[cs] = __builtin_shufflevector(lo, hi, 0, 1, 2, 3, 4, 5, 6, 7);
    }
  }
  int ng = n0 + w*32 + ql;
  int pt = ng / 3;
  int d  = ng - 3*pt;
  float* trw = tr[w];
  for (int mt = 0; mt < 13; ++mt) {
    int m0 = mq*416 + mt*32;
    __syncthreads();
    for (int idx = t; idx < 512; idx += 256) {
      int mm = idx >> 4, c16 = idx & 15;
      bf16x8 gv = *(const bf16x8*)&Wall[(size_t)(m0 + mm)*128 + c16*8];
      ushort_t* dst = &wt[mm*WT_PITCH + c16*8];
      *(bf16x4*)dst = __builtin_shufflevector(gv, gv, 0, 1, 2, 3);
      *(bf16x4*)(dst+4) = __builtin_shufflevector(gv, gv, 4, 5, 6, 7);
    }
    __syncthreads();
    f32x16 acc;
#pragma unroll
    for (int r = 0; r < 16; ++r) acc[r] = 0.f;
    const ushort_t* wr = &wt[ql*WT_PITCH + hl*8];
#pragma unroll
    for (int cs = 0; cs < 8; ++cs) {
      bf16x4 lo = *(const bf16x4*)(wr + cs*16);
      bf16x4 hi = *(const bf16x4*)(wr + cs*16 + 4);
      bf16x8 af = __builtin_shufflevector(lo, hi, 0, 1, 2, 3, 4, 5, 6, 7);
      acc = __builtin_amdgcn_mfma_f32_32x32x16_bf16(af, xf[cs], acc, 0, 0, 0);
    }
#pragma unroll
    for (int r = 0; r < 16; ++r) {
      int mrow = (r&3) + 8*(r>>2) + 4*hl;
      trw[ql*TR_PITCH + mrow] = acc[r];
    }
    asm volatile("s_waitcnt lgkmcnt(0)" ::: "memory");
    float4 c0 = *(float4*)&trw[ql*TR_PITCH + hl*16 + 0];
    float4 c1 = *(float4*)&trw[ql*TR_PITCH + hl*16 + 4];
    float4 c2 = *(float4*)&trw[ql*TR_PITCH + hl*16 + 8];
    float4 c3 = *(float4*)&trw[ql*TR_PITCH + hl*16 + 12];
    asm volatile("s_waitcnt lgkmcnt(0)" ::: "memory");
    int mg = m0 + hl*16;
    if (m0 < 1152) {
      uint4 s0, s1;
      s0.x = pack2(c0.x, c0.y); s0.y = pack2(c0.z, c0.w);
      s0.z = pack2(c1.x, c1.y); s0.w = pack2(c1.z, c1.w);
      s1.x = pack2(c2.x, c2.y); s1.y = pack2(c2.z, c2.w);
      s1.z = pack2(c3.x, c3.y); s1.w = pack2(c3.z, c3.w);
      ushort_t* dst;
      if (m0 < 384)       dst = q + (size_t)pt*1152 + d*384 + mg;
      else if (m0 < 768)  dst = k + (size_t)pt*1152 + d*384 + (mg - 384);
      else                dst = v + (size_t)pt*1152 + d*384 + (mg - 768);
      *(uint4*)dst = s0;
      *(uint4*)(dst + 8) = s1;
    } else {
      int mat = mg - 1152;
      int sub = mat >> 7, o = mat & 127;
      _Float16* basep = (sub < 2) ? YZh : NBh;
      _Float16* dst = basep + (size_t)pt*768 + d*256 + (sub & 1)*128 + o;
      uint4 s0, s1;
      s0.x = packh2(c0.x, c0.y); s0.y = packh2(c0.z, c0.w);
      s0.z = packh2(c1.x, c1.y); s0.w = packh2(c1.z, c1.w);
      s1.x = packh2(c2.x, c2.y); s1.y = packh2(c2.z, c2.w);
      s1.z = packh2(c3.x, c3.y); s1.w = packh2(c3.z, c3.w);
      *(uint4*)dst = s0;
      *(uint4*)(dst + 8) = s1;
    }
  }
}

// ---------------- conv1 post: 4 points per block (launch 8192 -> 2048 blocks) ----------------
__global__ __launch_bounds__(128) void conv1_post(const _Float16* __restrict__ YZh,
    const _Float16* __restrict__ NBh, const int* __restrict__ knn_index,
    _Float16* __restrict__ kmf16) {
  int bnb = blockIdx.x * 4;
  int t = threadIdx.x;
  __shared__ int sidx[4][KNN];
  if (t < 32) {
    int pi = t >> 3, kk = t & 7;
    int bn = bnb + pi;
    int b = bn / NFIX, n = bn % NFIX;
    sidx[pi][kk] = knn_index[(b*KNN + kk)*NFIX + n];
  }
  __syncthreads();
#pragma unroll
  for (int pi = 0; pi < 4; ++pi) {
    int bn = bnb + pi;
    float yb[3], zb[3];
#pragma unroll
    for (int d = 0; d < 3; ++d) {
      yb[d] = (float)NBh[(size_t)bn*768 + d*256 + t];
      zb[d] = (float)NBh[(size_t)bn*768 + d*256 + 128 + t];
    }
    float om[3] = {0.f, 0.f, 0.f};
#pragma unroll
    for (int kk = 0; kk < KNN; ++kk) {
      const _Float16* r = YZh + (size_t)sidx[pi][kk]*768;
      float p[3], dd[3];
#pragma unroll
      for (int d = 0; d < 3; ++d) {
        p[d]  = (float)r[d*256 + t] + yb[d];
        dd[d] = (float)r[d*256 + 128 + t] + zb[d];
      }
      float res[3];
      vnleaky3(p, dd, res);
      om[0] += res[0]; om[1] += res[1]; om[2] += res[2];
    }
#pragma unroll
    for (int d = 0; d < 3; ++d)
      kmf16[((size_t)bn*3 + d)*128 + t] = (_Float16)(om[d] * (1.f/KNN));
  }
}

// ---------------- V transpose: LDS-tiled ----------------
#define VT_LP 196
__global__ __launch_bounds__(256) void vtrans_kernel(const ushort_t* __restrict__ v,
                                                     ushort_t* __restrict__ vT) {
  __shared__ ushort_t tl[64*VT_LP];   // 25088 B
  int blk = blockIdx.x;
  int bh = blk / 32, ptile = blk % 32;
  int b = bh / HH, h = bh % HH;
  int pt0 = ptile * 64;
  int t = threadIdx.x;
#pragma unroll
  for (int i = 0; i < 6; ++i) {
    int u = i*256 + t;
    int p = u / 24, seg = u % 24;
    int d = seg >> 3, c8 = seg & 7;
    bf16x8 gv = *(const bf16x8*)&v[(size_t)(b*NFIX + pt0 + p)*1152 + d*384 + h*64 + c8*8];
    ushort_t* dst = &tl[p*VT_LP + d*64 + c8*8];
    *(bf16x4*)dst = __builtin_shufflevector(gv, gv, 0, 1, 2, 3);
    *(bf16x4*)(dst+4) = __builtin_shufflevector(gv, gv, 4, 5, 6, 7);
  }
  __syncthreads();
#pragma unroll
  for (int i = 0; i < 6; ++i) {
    int u = i*256 + t;
    int ch = u >> 3, pc = u & 7;
    int ol = ch / 3, dd = ch - 3*ol;
    int cloc = dd*64 + ol;
    ushort_t hv[8];
#pragma unroll
    for (int e = 0; e < 8; ++e)
      hv[e] = tl[(pc*8 + e)*VT_LP + cloc];
    uint4 o4;
    o4.x = (uint_t)hv[0] | ((uint_t)hv[1] << 16);
    o4.y = (uint_t)hv[2] | ((uint_t)hv[3] << 16);
    o4.z = (uint_t)hv[4] | ((uint_t)hv[5] << 16);
    o4.w = (uint_t)hv[6] | ((uint_t)hv[7] << 16);
    *(uint4*)&vT[((size_t)bh*192 + ch)*2048 + pt0 + pc*8] = o4;
  }
}

// ---------------- attention (round-5 proven version): split-K=2, XCD-grouped decode,
// dual S-MFMA chains, pack2 RNE softmax, V LDS-staged dbuf, f16 O_s epilogue. ----------------
#define KT_P 196
#define VT_P 36
#define TW_P 195
__global__ __launch_bounds__(256, 2) void attn_kernel(const ushort_t* __restrict__ q,
    const ushort_t* __restrict__ k, const ushort_t* __restrict__ vT,
    ushort_t* __restrict__ opart, float* __restrict__ lpart) {
  __shared__ ushort_t kt[2][32*KT_P];
  __shared__ ushort_t vt[2][192*VT_P];
  __shared__ float alds[4][32];
  // XCD-aware decode: blocks round-robin XCDs by blockIdx%8. 48 (bh,split) groups, 6/XCD;
  // the 16 qt sharers of one K/V panel land on one XCD's L2.
  int blk = blockIdx.x;
  int xcd = blk & 7, j = blk >> 3;          // j in 0..95
  int g = xcd*6 + (j >> 4);                 // 48 groups
  int qt = j & 15;
  int bh = g % 24;
  int split = g / 24;                       // 0..1
  int b = bh / HH, h = bh % HH;
  int t = threadIdx.x;
  int w = t >> 6, lane = t & 63, ql = lane & 31, hl = lane >> 5;
  int qrow0 = qt*128 + w*32;
  const ushort_t* qpb = q + (size_t)(b*NFIX + qrow0 + ql)*1152 + h*64;
  bf16x8 qf[12];
#pragma unroll
  for (int cs = 0; cs < 12; ++cs) {
    int red0 = cs*16 + hl*8;
    int dq = red0 >> 6, ml = red0 & 63;
    qf[cs] = *(const bf16x8*)(qpb + dq*384 + ml);
  }
  const ushort_t* ksrc[3]; int kdsto[3];
  const ushort_t* vsrc[3]; int vdsto[3];
#pragma unroll
  for (int j2 = 0; j2 < 3; ++j2) {
    int idx = t + j2*256;
    int kp = idx / 24, c16 = idx % 24;
    int red0 = c16*8;
    int dk = red0 >> 6, ml = red0 & 63;
    ksrc[j2] = k + (size_t)(b*NFIX + kp)*1152 + dk*384 + h*64 + ml;
    kdsto[j2] = kp*KT_P + c16*8;
    int ch = idx >> 2, c4 = idx & 3;
    vsrc[j2] = vT + ((size_t)bh*192 + ch)*2048 + c4*8;
    vdsto[j2] = ch*VT_P + c4*8;
  }
  f32x16 acc[6];
#pragma unroll
  for (int nt = 0; nt < 6; ++nt)
#pragma unroll
    for (int r = 0; r < 16; ++r) acc[nt][r] = 0.f;
  float lsum = 0.f;
  int koff0 = split * 1024;                 // 1024 keys per split, 32 K-tiles
  bf16x8 kpre[3], vpre[3];
#pragma unroll
  for (int j2 = 0; j2 < 3; ++j2) {
    kpre[j2] = *(const bf16x8*)(ksrc[j2] + (size_t)koff0*1152);
    vpre[j2] = *(const bf16x8*)(vsrc[j2] + koff0);
  }
#pragma unroll
  for (int j2 = 0; j2 < 3; ++j2) {
    ushort_t* kd = &kt[0][kdsto[j2]];
    *(bf16x4*)kd = __builtin_shufflevector(kpre[j2], kpre[j2], 0, 1, 2, 3);
    *(bf16x4*)(kd+4) = __builtin_shufflevector(kpre[j2], kpre[j2], 4, 5, 6, 7);
    ushort_t* vd = &vt[0][vdsto[j2]];
    *(bf16x4*)vd = __builtin_shufflevector(vpre[j2], vpre[j2], 0, 1, 2, 3);
    *(bf16x4*)(vd+4) = __builtin_shufflevector(vpre[j2], vpre[j2], 4, 5, 6, 7);
  }
  __syncthreads();
  for (int kb = 0; kb < 32; ++kb) {
    int cur = kb & 1;
    if (kb < 31) {
      int koff = koff0 + (kb+1)*32;
#pragma unroll
      for (int j2 = 0; j2 < 3; ++j2) {
        kpre[j2] = *(const bf16x8*)(ksrc[j2] + (size_t)koff*1152);
        vpre[j2] = *(const bf16x8*)(vsrc[j2] + koff);
      }
    }
    // dual independent S accumulation chains (6-deep each instead of 12)
    f32x16 sca, scb;
#pragma unroll
    for (int r = 0; r < 16; ++r) { sca[r] = 0.f; scb[r] = 0.f; }
    const ushort_t* ktc = kt[cur];
#pragma unroll
    for (int cs = 0; cs < 12; ++cs) {
      const ushort_t* kr = &ktc[ql*KT_P + cs*16 + hl*8];
      bf16x4 alo = *(const bf16x4*)kr;
      bf16x4 ahi = *(const bf16x4*)(kr + 4);
      bf16x8 af = __builtin_shufflevector(alo, ahi, 0, 1, 2, 3, 4, 5, 6, 7);
      if (cs & 1) scb = __builtin_amdgcn_mfma_f32_32x32x16_bf16(af, qf[cs], scb, 0, 0, 0);
      else        sca = __builtin_amdgcn_mfma_f32_32x32x16_bf16(af, qf[cs], sca, 0, 0, 0);
    }
    uint_t u[8], pex[8];
#pragma unroll
    for (int g2 = 0; g2 < 4; ++g2) {
      float p0 = __builtin_amdgcn_exp2f(sca[g2*4 + 0] + scb[g2*4 + 0]);
      float p1 = __builtin_amdgcn_exp2f(sca[g2*4 + 1] + scb[g2*4 + 1]);
      float p2 = __builtin_amdgcn_exp2f(sca[g2*4 + 2] + scb[g2*4 + 2]);
      float p3 = __builtin_amdgcn_exp2f(sca[g2*4 + 3] + scb[g2*4 + 3]);
      lsum += (p0 + p1) + (p2 + p3);
      u[2*g2]   = pack2(p0, p1);
      u[2*g2+1] = pack2(p2, p3);
    }
#pragma unroll
    for (int j2 = 0; j2 < 8; ++j2) pex[j2] = (uint_t)__shfl_xor((int)u[j2], 32);
    const ushort_t* vtc = vt[cur];
#pragma unroll
    for (int s = 0; s < 2; ++s) {
      uint4 au;
      au.x = hl ? pex[4*s+2] : u[4*s+0];
      au.y = hl ? pex[4*s+3] : u[4*s+1];
      au.z = hl ? u[4*s+2]   : pex[4*s+0];
      au.w = hl ? u[4*s+3]   : pex[4*s+1];
      union { uint4 ui; bf16x8 bv; } cvt; cvt.ui = au;
      bf16x8 pa = cvt.bv;
#pragma unroll
      for (int nt = 0; nt < 6; ++nt) {
        const ushort_t* vr = &vtc[(nt*32 + ql)*VT_P + s*16 + hl*8];
        bf16x4 vlo = *(const bf16x4*)vr;
        bf16x4 vhi = *(const bf16x4*)(vr + 4);
        bf16x8 vf = __builtin_shufflevector(vlo, vhi, 0, 1, 2, 3, 4, 5, 6, 7);
        acc[nt] = __builtin_amdgcn_mfma_f32_32x32x16_bf16(pa, vf, acc[nt], 0, 0, 0);
      }
    }
    if (kb < 31) {
      int nxt = cur ^ 1;
#pragma unroll
      for (int j2 = 0; j2 < 3; ++j2) {
        ushort_t* kd = &kt[nxt][kdsto[j2]];
        *(bf16x4*)kd = __builtin_shufflevector(kpre[j2], kpre[j2], 0, 1, 2, 3);
        *(bf16x4*)(kd+4) = __builtin_shufflevector(kpre[j2], kpre[j2], 4, 5, 6, 7);
        ushort_t* vd = &vt[nxt][vdsto[j2]];
        *(bf16x4*)vd = __builtin_shufflevector(vpre[j2], vpre[j2], 0, 1, 2, 3);
        *(bf16x4*)(vd+4) = __builtin_shufflevector(vpre[j2], vpre[j2], 4, 5, 6, 7);
      }
    }
    __syncthreads();
  }
  lsum += __shfl_xor(lsum, 32);
  if (lane < 32) {
    alds[w][ql] = 1.0f / lsum;
    lpart[(size_t)split*24*NFIX + (size_t)bh*NFIX + qrow0 + ql] = lsum;
  }
  asm volatile("s_waitcnt lgkmcnt(0)" ::: "memory");
  float lv[4][4];
#pragma unroll
  for (int g2 = 0; g2 < 4; ++g2) {
    f32x4 tv = *(const f32x4*)&alds[w][8*g2 + 4*hl];
#pragma unroll
    for (int rr = 0; rr < 4; ++rr) lv[g2][rr] = tv[rr];
  }
  // ---- epilogue: O_s stored as f16 bits (split-combine precision) ----
  ushort_t* tw = (w == 0) ? kt[0] : (w == 1) ? kt[1] : (w == 2) ? vt[0] : vt[1];
#pragma unroll
  for (int nt = 0; nt < 6; ++nt) {
    int ch = nt*32 + ql;
#pragma unroll
    for (int r = 0; r < 16; ++r) {
      int qrow = (r&3) + 8*(r>>2) + 4*hl;
      tw[qrow*TW_P + ch] = f2h_bits(acc[nt][r] * lv[r>>2][r&3]);
    }
  }
  asm volatile("s_waitcnt lgkmcnt(0)" ::: "memory");
  const size_t SS = (size_t)8192*1152;
  ushort_t* opb = opart + (size_t)split*SS;
  size_t nbase = (size_t)(b*NFIX + qrow0) * 3;
#pragma unroll
  for (int i = 0; i < 12; ++i) {
    int chunk = i*64 + lane;
    int nl = chunk >> 3, jc = chunk & 7;
    int qq = nl / 3, dd = nl - 3*qq;
    ushort_t hv[8];
#pragma unroll
    for (int e = 0; e < 8; ++e)
      hv[e] = tw[qq*TW_P + (jc*8 + e)*3 + dd];
    uint4 sv;
    sv.x = (uint_t)hv[0] | ((uint_t)hv[1] << 16);
    sv.y = (uint_t)hv[2] | ((uint_t)hv[3] << 16);
    sv.z = (uint_t)hv[4] | ((uint_t)hv[5] << 16);
    sv.w = (uint_t)hv[6] | ((uint_t)hv[7] << 16);
    *(uint4*)&opb[(nbase + nl)*384 + h*64 + jc*8] = sv;
  }
}

// ---------------- x1mid fp16 MFMA + fused LN2 -> xmid (f32) and nxh (f16) ----------------
#define AP 68
#define XLP 132
__global__ __launch_bounds__(384) void x1mid_mfma(
    const float* __restrict__ xdi, const ushort_t* __restrict__ opart,
    const float* __restrict__ lpart, const _Float16* __restrict__ kmf16,
    const _Float16* __restrict__ Af16, float* __restrict__ xmid,
    _Float16* __restrict__ nxh, const float* __restrict__ g2,
    const float* __restrict__ b2) {
  __shared__ __align__(16) char smem[50944];
  _Float16* As = (_Float16*)smem;                 // 128 x AP = 17408 B
  _Float16* Bt = (_Float16*)(smem + 17408);       //  96 x AP = 13056 B
  float* wlsL  = (float*)(smem + 30464);          //  32 x 6 x 2 = 1536 B
  float* X     = (float*)smem;                    // epilogue overlay: 96 x XLP f32 = 50688 B
  float* stats = (float*)(smem + 50688);          // 32 x 2 f32 = 256 B
  int blk = blockIdx.x;
  int n0 = blk * 96;
  int pt0 = blk * 32;
  int t = threadIdx.x;
  int w = t >> 6, lane = t & 63, ql = lane & 31, hl = lane >> 5;
  int nsub = w >> 1, mh = w & 1;
  if (t < 192) {
    int ptl = t / 6, h = t % 6;
    int ptg = pt0 + ptl;
    int b = ptg >> 11, n = ptg & 2047;
    size_t lidx = (size_t)(b*HH + h)*NFIX + n;
    float l[NSPLIT]; float tot = 0.f;
#pragma unroll
    for (int s = 0; s < NSPLIT; ++s) {
      l[s] = lpart[(size_t)s*24*NFIX + lidx];
      tot += l[s];
    }
    float rd = 1.f / tot;
    float* wp = &wlsL[(ptl*6 + h)*NSPLIT];
#pragma unroll
    for (int s = 0; s < NSPLIT; ++s) wp[s] = l[s]*rd;
  }
  f32x16 acc[2];
#pragma unroll
  for (int m2 = 0; m2 < 2; ++m2)
#pragma unroll
    for (int r = 0; r < 16; ++r) acc[m2][r] = 0.f;
  const size_t SS = (size_t)8192*1152;
  __syncthreads();
  for (int p = 0; p < 8; ++p) {
    for (int u = t; u < 1024; u += 384) {
      int m = u >> 3, kc = u & 7;
      f16x4 a0 = *(const f16x4*)&Af16[(size_t)m*512 + p*64 + kc*8];
      f16x4 a1 = *(const f16x4*)&Af16[(size_t)m*512 + p*64 + kc*8 + 4];
      _Float16* dst = &As[m*AP + kc*8];
      *(f16x4*)dst = a0;
      *(f16x4*)(dst+4) = a1;
    }
    {
      int u = t;
      if (u < 384) {
        int n_l = u >> 2, jc = u & 3;
        int n_g = n0 + n_l;
        _Float16* dst = &Bt[n_l*AP + jc*16];
        if (p < 6) {
          int pt_l = n_l / 3;
          const float* wp = &wlsL[(pt_l*6 + p)*NSPLIT];
          float facc[16];
#pragma unroll
          for (int e = 0; e < 16; ++e) facc[e] = 0.f;
#pragma unroll
          for (int s = 0; s < NSPLIT; ++s) {
            const ushort_t* src = opart + s*SS + (size_t)n_g*384 + p*64 + jc*16;
            uint4 ra = *(const uint4*)src;
            uint4 rb = *(const uint4*)(src + 8);
            const _Float16* ua = (const _Float16*)&ra;
            const _Float16* ub = (const _Float16*)&rb;
            float wsc = wp[s];
#pragma unroll
            for (int e = 0; e < 8; ++e) {
              facc[e]     += wsc * (float)ua[e];
              facc[8 + e] += wsc * (float)ub[e];
            }
          }
          _Float16 hv[16];
#pragma unroll
          for (int e = 0; e < 16; ++e) hv[e] = (_Float16)facc[e];
#pragma unroll
          for (int g = 0; g < 4; ++g)
            *(f16x4*)(dst + g*4) = *(f16x4*)&hv[g*4];
        } else {
          const _Float16* src = kmf16 + (size_t)n_g*128 + (p-6)*64 + jc*16;
          f16x4 v0 = *(const f16x4*)src;
          f16x4 v1 = *(const f16x4*)(src + 4);
          f16x4 v2 = *(const f16x4*)(src + 8);
          f16x4 v3 = *(const f16x4*)(src + 12);
          *(f16x4*)dst = v0; *(f16x4*)(dst+4) = v1;
          *(f16x4*)(dst+8) = v2; *(f16x4*)(dst+12) = v3;
        }
      }
    }
    __syncthreads();
#pragma unroll
    for (int cs = 0; cs < 4; ++cs) {
      int kloc = cs*16 + hl*8;
      f16x4 b0 = *(const f16x4*)&Bt[(nsub*32 + ql)*AP + kloc];
      f16x4 b1 = *(const f16x4*)&Bt[(nsub*32 + ql)*AP + kloc + 4];
      f16x8 bf = __builtin_shufflevector(b0, b1, 0, 1, 2, 3, 4, 5, 6, 7);
#pragma unroll
      for (int m2 = 0; m2 < 2; ++m2) {
        int mrow = (mh*2 + m2)*32 + ql;
        f16x4 a0 = *(const f16x4*)&As[mrow*AP + kloc];
        f16x4 a1 = *(const f16x4*)&As[mrow*AP + kloc + 4];
        f16x8 af = __builtin_shufflevector(a0, a1, 0, 1, 2, 3, 4, 5, 6, 7);
        acc[m2] = __builtin_amdgcn_mfma_f32_32x32x16_f16(af, bf, acc[m2], 0, 0, 0);
      }
    }
    __syncthreads();
  }
  // ---- write acc directly into X (C frag: n = nsub*32+ql, c = mtile*32 + (r&3)+8*(r>>2)+4*hl) ----
#pragma unroll
  for (int m2 = 0; m2 < 2; ++m2) {
    int cbase = (mh*2 + m2)*32 + 4*hl;
    float* xrow = &X[(nsub*32 + ql)*XLP];
#pragma unroll
    for (int r = 0; r < 16; ++r) {
      int col = cbase + (r&3) + 8*(r>>2);
      xrow[col] = acc[m2][r];
    }
  }
  __syncthreads();
  // ---- Phase A: add residual (post-residual stays in X), emit xmid global ----
#pragma unroll
  for (int i = 0; i < 4; ++i) {
    int u = i*384 + t;                  // 96 rows x 16 chunks of 8
    int row = u >> 4, c0 = (u & 15) * 8;
    float* xp = &X[row*XLP + c0];
    const float* xd = xdi + (size_t)(n0 + row)*128 + c0;
    float4 a0 = *(float4*)xp, a1 = *(float4*)(xp + 4);
    float4 d0 = *(const float4*)xd, d1 = *(const float4*)(xd + 4);
    a0.x += d0.x; a0.y += d0.y; a0.z += d0.z; a0.w += d0.w;
    a1.x += d1.x; a1.y += d1.y; a1.z += d1.z; a1.w += d1.w;
    *(float4*)xp = a0; *(float4*)(xp + 4) = a1;
    float* dst = xmid + (size_t)(n0 + row)*128 + c0;
    *(float4*)dst = a0; *(float4*)(dst + 4) = a1;
  }
  __syncthreads();
  // ---- Phase B: per-point LN stats (6 waves cover 32 points) ----
  for (int pi = w; pi < 32; pi += 6) {
    int c = lane;
    float a0 = X[(pi*3+0)*XLP + c], a1 = X[(pi*3+1)*XLP + c], a2 = X[(pi*3+2)*XLP + c];
    float e0 = X[(pi*3+0)*XLP + c + 64], e1 = X[(pi*3+1)*XLP + c + 64], e2 = X[(pi*3+2)*XLP + c + 64];
    float nva = sqrtf(a0*a0 + a1*a1 + a2*a2 + EPSF);
    float nvb = sqrtf(e0*e0 + e1*e1 + e2*e2 + EPSF);
    float s1 = nva + nvb;
    float s2 = nva*nva + nvb*nvb;
#pragma unroll
    for (int off = 32; off >= 1; off >>= 1) {
      s1 += __shfl_down(s1, off);
      s2 += __shfl_down(s2, off);
    }
    if (lane == 0) {
      float mu = s1 * (1.f/128.f);
      float var = s2 * (1.f/128.f) - mu*mu;
      stats[pi*2]   = mu;
      stats[pi*2+1] = rsqrtf(var + LNEPSF);
    }
  }
  __syncthreads();
  // ---- Phase C: emit nxh f16 (LN2-normalized) ----
#pragma unroll
  for (int i = 0; i < 4; ++i) {
    int u = i*384 + t;
    int row = u >> 4, c0 = (u & 15) * 8;
    int pt_l = row / 3;
    float mu = stats[pt_l*2], rsig = stats[pt_l*2+1];
    const float* r0 = &X[(pt_l*3 + 0)*XLP + c0];
    const float* r1 = &X[(pt_l*3 + 1)*XLP + c0];
    const float* r2 = &X[(pt_l*3 + 2)*XLP + c0];
    const float* rd = &X[row*XLP + c0];
    float xv[8];
#pragma unroll
    for (int e = 0; e < 8; ++e) {
      float x0 = r0[e], x1 = r1[e], x2 = r2[e];
      float nv = sqrtf(x0*x0 + x1*x1 + x2*x2 + EPSF);
      float nnew = g2[c0 + e] * ((nv - mu) * rsig) + b2[c0 + e];
      xv[e] = rd[e] * (nnew / nv);
    }
    uint4 sv;
    sv.x = packh2(xv[0], xv[1]); sv.y = packh2(xv[2], xv[3]);
    sv.z = packh2(xv[4], xv[5]); sv.w = packh2(xv[6], xv[7]);
    *(uint4*)&nxh[(size_t)(n0 + row)*128 + c0] = sv;
  }
}

// ---------------- conv3: f16 MFMA, 3 d-plane GEMMs/wave ----------------
#define X3P 132
#define TR3P 36
__global__ __launch_bounds__(256) void conv3_mfma(const _Float16* __restrict__ nxh,
    const _Float16* __restrict__ W3h, const _Float16* __restrict__ U3h,
    _Float16* __restrict__ h3) {
  __shared__ __align__(16) _Float16 Xs[3*32*X3P];     // 25344 B
  __shared__ __align__(16) _Float16 tr3[4][96*TR3P];  // 27648 B
  int blk = blockIdx.x;
  int pt0 = (blk >> 1) * 32;
  int oh = blk & 1;
  int t = threadIdx.x;
  int w = t >> 6, lane = t & 63, ql = lane & 31, hl = lane >> 5;
#pragma unroll
  for (int i = 0; i < 6; ++i) {
    int u = i*256 + t;
    int r = u >> 4, c8 = u & 15;
    f16x8 gv = *(const f16x8*)&nxh[(size_t)(pt0*3 + r)*128 + c8*8];
    int d = r % 3, p = r / 3;
    _Float16* dst = &Xs[(d*32 + p)*X3P + c8*8];
    *(f16x4*)dst = __builtin_shufflevector(gv, gv, 0, 1, 2, 3);
    *(f16x4*)(dst+4) = __builtin_shufflevector(gv, gv, 4, 5, 6, 7);
  }
  __syncthreads();
  int ot = oh*128 + w*32;
  const _Float16* Wp = W3h + (size_t)(ot + ql)*128 + hl*8;
  const _Float16* Up = U3h + (size_t)(ot + ql)*128 + hl*8;
  f32x16 accP[3], accD[3];
#pragma unroll
  for (int d = 0; d < 3; ++d)
#pragma unroll
    for (int r = 0; r < 16; ++r) { accP[d][r] = 0.f; accD[d][r] = 0.f; }
#pragma unroll
  for (int cs = 0; cs < 8; ++cs) {
    f16x8 wf = *(const f16x8*)(Wp + cs*16);
    f16x8 uf = *(const f16x8*)(Up + cs*16);
#pragma unroll
    for (int d = 0; d < 3; ++d) {
      const _Float16* xr = &Xs[(d*32 + ql)*X3P + cs*16 + hl*8];
      f16x4 lo = *(const f16x4*)xr;
      f16x4 hi = *(const f16x4*)(xr + 4);
      f16x8 xf = __builtin_shufflevector(lo, hi, 0, 1, 2, 3, 4, 5, 6, 7);
      accP[d] = __builtin_amdgcn_mfma_f32_32x32x16_f16(wf, xf, accP[d], 0, 0, 0);
      accD[d] = __builtin_amdgcn_mfma_f32_32x32x16_f16(uf, xf, accD[d], 0, 0, 0);
    }
  }
  _Float16* trw = tr3[w];
#pragma unroll
  for (int r = 0; r < 16; ++r) {
    int olr = (r&3) + 8*(r>>2) + 4*hl;
    float p3[3], d3[3], res[3];
#pragma unroll
    for (int d = 0; d < 3; ++d) { p3[d] = accP[d][r]; d3[d] = accD[d][r]; }
    vnleaky3(p3, d3, res);
#pragma unroll
    for (int d = 0; d < 3; ++d) trw[(ql*3 + d)*TR3P + olr] = (_Float16)res[d];
  }
  asm volatile("s_waitcnt lgkmcnt(0)" ::: "memory");
#pragma unroll
  for (int i = 0; i < 6; ++i) {
    int u = i*64 + lane;
    int row = u >> 2, c8 = u & 3;
    const _Float16* src = &trw[row*TR3P + c8*8];
    f16x4 lo = *(const f16x4*)src;
    f16x4 hi = *(const f16x4*)(src + 4);
    f16x8 ov = __builtin_shufflevector(lo, hi, 0, 1, 2, 3, 4, 5, 6, 7);
    *(f16x8*)&h3[(size_t)(pt0*3 + row)*256 + ot + c8*8] = ov;
  }
}

// ---------------- conv4: f16 MFMA (16x16x32), + xmid residual ----------------
#define X4P 260
#define TF4P 388
__global__ __launch_bounds__(256) void conv4_mfma(const _Float16* __restrict__ h3,
    const _Float16* __restrict__ W4h, const _Float16* __restrict__ U4h,
    const float* __restrict__ xmid, float* __restrict__ out) {
  __shared__ __align__(16) _Float16 Xs[3*16*X4P];   // 24960 B
  __shared__ __align__(16) float trF[16*TF4P];      // 24832 B
  int pt0 = blockIdx.x * 16;
  int t = threadIdx.x;
  int w = t >> 6, lane = t & 63;
  int nl = lane & 15, kq = lane >> 4;
#pragma unroll
  for (int i = 0; i < 6; ++i) {
    int u = i*256 + t;
    int r = u >> 5, c8 = u & 31;
    f16x8 gv = *(const f16x8*)&h3[(size_t)(pt0*3 + r)*256 + c8*8];
    int d = r % 3, p = r / 3;
    _Float16* dst = &Xs[(d*16 + p)*X4P + c8*8];
    *(f16x4*)dst = __builtin_shufflevector(gv, gv, 0, 1, 2, 3);
    *(f16x4*)(dst+4) = __builtin_shufflevector(gv, gv, 4, 5, 6, 7);
  }
  __syncthreads();
  int ot = w*32;
  f32x4 accP[2][3], accD[2][3];
#pragma unroll
  for (int mt = 0; mt < 2; ++mt)
#pragma unroll
    for (int d = 0; d < 3; ++d)
#pragma unroll
      for (int r = 0; r < 4; ++r) { accP[mt][d][r] = 0.f; accD[mt][d][r] = 0.f; }
  const _Float16* Wb = W4h + (size_t)ot*256;
  const _Float16* Ub = U4h + (size_t)ot*256;
#pragma unroll
  for (int cs = 0; cs < 8; ++cs) {
    int kof = cs*32 + kq*8;
    f16x8 xf[3];
#pragma unroll
    for (int d = 0; d < 3; ++d) {
      const _Float16* xr = &Xs[(d*16 + nl)*X4P + kof];
      f16x4 lo = *(const f16x4*)xr;
      f16x4 hi = *(const f16x4*)(xr + 4);
      xf[d] = __builtin_shufflevector(lo, hi, 0, 1, 2, 3, 4, 5, 6, 7);
    }
#pragma unroll
    for (int mt = 0; mt < 2; ++mt) {
      f16x8 wf = *(const f16x8*)(Wb + (size_t)(mt*16 + nl)*256 + kof);
      f16x8 uf = *(const f16x8*)(Ub + (size_t)(mt*16 + nl)*256 + kof);
#pragma unroll
      for (int d = 0; d < 3; ++d) {
        accP[mt][d] = __builtin_amdgcn_mfma_f32_16x16x32_f16(wf, xf[d], accP[mt][d], 0, 0, 0);
        accD[mt][d] = __builtin_amdgcn_mfma_f32_16x16x32_f16(uf, xf[d], accD[mt][d], 0, 0, 0);
      }
    }
  }
#pragma unroll
  for (int mt = 0; mt < 2; ++mt)
#pragma unroll
    for (int r = 0; r < 4; ++r) {
      int o = ot + mt*16 + kq*4 + r;
      float p3[3], d3[3], res[3];
#pragma unroll
      for (int d = 0; d < 3; ++d) { p3[d] = accP[mt][d][r]; d3[d] = accD[mt][d][r]; }
      vnleaky3(p3, d3, res);
#pragma unroll
      for (int d = 0; d < 3; ++d) trF[nl*TF4P + o*3 + d] = res[d];
    }
  __syncthreads();
#pragma unroll
  for (int i = 0; i < 6; ++i) {
    int u = i*256 + t;
    int row = u / 96, c4 = u % 96;
    float4 vv = *(float4*)&trF[row*TF4P + c4*4];
    int bn = pt0 + row;
    float rs[4];
    const float* fv = (const float*)&vv;
#pragma unroll
    for (int e = 0; e < 4; ++e) {
      int col = c4*4 + e;
      int o = col / 3, d = col - 3*o;
      rs[e] = fv[e] + xmid[(size_t)(3*bn + d)*128 + o];
    }
    float4 ov; ov.x = rs[0]; ov.y = rs[1]; ov.z = rs[2]; ov.w = rs[3];
    *(float4*)&out[(size_t)bn*384 + c4*4] = ov;
  }
}

extern "C" void kernel_launch(void* const* d_in, const int* in_sizes, int n_in,
                              void* d_out, int out_size, void* d_ws, size_t ws_size,
                              hipStream_t stream) {
  const float* x   = (const float*)d_in[0];
  const int* knn   = (const int*)d_in[1];
  const float* g1  = (const float*)d_in[2];
  const float* b1  = (const float*)d_in[3];
  const float* g2  = (const float*)d_in[4];
  const float* b2  = (const float*)d_in[5];
  const float* Wq  = (const float*)d_in[6];
  const float* Wk  = (const float*)d_in[7];
  const float* Wv  = (const float*)d_in[8];
  const float* Wo  = (const float*)d_in[9];
  const float* W1  = (const float*)d_in[10];
  const float* U1  = (const float*)d_in[11];
  const float* W2  = (const float*)d_in[12];
  const float* W3  = (const float*)d_in[13];
  const float* U3  = (const float*)d_in[14];
  const float* W4  = (const float*)d_in[15];
  const float* U4  = (const float*)d_in[16];
  float* out = (float*)d_out;
  (void)n_in; (void)out_size; (void)ws_size;

  const size_t BN = (size_t)in_sizes[0] / 384;   // 8192

  float* ws    = (float*)d_ws;
  float* xdi   = ws;                          // BN*384 f32 (raw x, de-interleaved [n][c])
  float* xmid  = xdi + BN*384;                // BN*384 f32 (x_mid, de-interleaved)
  _Float16* kmf16 = (_Float16*)(xmid + BN*384);  // BN*384 fp16 [n][128]
  ushort_t* xbp = (ushort_t*)(kmf16 + BN*384);   // BN*384 bf16 (LN1 normalized, de-interleaved)
  ushort_t* qb = xbp + BN*384;                // BN*1152 bf16
  ushort_t* kb = qb + BN*1152;
  ushort_t* vb = kb + BN*1152;
  ushort_t* vT = vb + BN*1152;
  ushort_t* Wall = vT + BN*1152;              // 212992 bf16
  _Float16* Af16 = (_Float16*)(Wall + 212992);   // 65536 fp16
  _Float16* W3h = Af16 + 65536;               // 32768 fp16
  _Float16* U3h = W3h + 32768;
  _Float16* W4h = U3h + 32768;
  _Float16* U4h = W4h + 32768;
  ushort_t* opart = (ushort_t*)(U4h + 32768); // region 4*BN*1152 (2 splits used)
  float* lpart = (float*)(opart + 4*BN*1152); // 2*24*2048 f32
  // YZh/NBh (BN*768 f16 each = 12.6 MB) alias the opart region: conv1_post runs before attn.
  _Float16* YZh = (_Float16*)opart;
  _Float16* NBh = YZh + BN*768;
  _Float16* nxh = (_Float16*)qb;   // q dead after x1mid; LN2 out f16 [ng][128]
  _Float16* h3  = (_Float16*)kb;   // k dead after attention; conv3 out f16 [ng][256]

  prep_weights<<<1600, 256, 0, stream>>>(Wq, Wk, Wv, Wo, W1, U1, W2, W3, U3, W4, U4,
                                         Wall, Af16, W3h, U3h, W4h, U4h);
  ln1_kernel<<<(int)BN, 128, 0, stream>>>(x, xbp, xdi, g1, b1);
  qkv_conv1_mfma<<<192*4, 256, 0, stream>>>(xbp, Wall, qb, kb, vb, YZh, NBh);
  conv1_post<<<(int)(BN/4), 128, 0, stream>>>(YZh, NBh, knn, kmf16);
  vtrans_kernel<<<768, 256, 0, stream>>>(vb, vT);
  attn_kernel<<<16*24*NSPLIT, 256, 0, stream>>>(qb, kb, vT, opart, lpart);
  x1mid_mfma<<<256, 384, 0, stream>>>(xdi, opart, lpart, kmf16, Af16, xmid, nxh, g2, b2);
  conv3_mfma<<<512, 256, 0, stream>>>(nxh, W3h, U3h, h3);
  conv4_mfma<<<512, 256, 0, stream>>>(h3, W4h, U4h, xmid, out);
}

// Round 9
// 319.346 us; speedup vs baseline: 1.2391x; 1.0361x over previous
//
#include <hip/hip_runtime.h>
#include <math.h>

// Problem constants (fixed by setup_inputs): B=4, N=2048, C=128, H=6, K=8
#define NFIX 2048
#define HH 6
#define KNN 8
#define NSLOPE 0.2f
#define EPSF 1e-6f
#define LNEPSF 1e-5f
// 0.125 (softmax scale) * log2(e), folded into Wq rows so S-MFMA output is exp2-ready
#define QSCALE 0.18033688011112042f
#define NSPLIT 2

typedef unsigned short ushort_t;
typedef unsigned int uint_t;
typedef __attribute__((ext_vector_type(8))) short bf16x8;
typedef __attribute__((ext_vector_type(4))) short bf16x4;
typedef __attribute__((ext_vector_type(8))) _Float16 f16x8;
typedef __attribute__((ext_vector_type(4))) _Float16 f16x4;
typedef __attribute__((ext_vector_type(16))) float f32x16;
typedef __attribute__((ext_vector_type(4))) float f32x4;

__device__ __forceinline__ ushort_t f2bf(float f) {
  union { float f; unsigned u; } v; v.f = f;
  unsigned r = v.u + 0x7fff + ((v.u >> 16) & 1);   // RNE
  return (ushort_t)(r >> 16);
}
__device__ __forceinline__ float bf2f(ushort_t u) {
  union { uint_t u; float f; } v; v.u = ((uint_t)u) << 16; return v.f;
}
__device__ __forceinline__ uint_t pack2(float a, float b) {
  return (uint_t)f2bf(a) | ((uint_t)f2bf(b) << 16);
}
// f32 -> f16 bit pattern (register-only)
__device__ __forceinline__ ushort_t f2h_bits(float a) {
  union { _Float16 h; ushort_t s; } cv; cv.h = (_Float16)a; return cv.s;
}
// pack two fp32 -> two f16 in one dword (register-only; no local-array aliasing)
__device__ __forceinline__ uint_t packh2(float a, float b) {
  union { _Float16 h; ushort_t s; } ha, hb;
  ha.h = (_Float16)a; hb.h = (_Float16)b;
  return (uint_t)ha.s | ((uint_t)hb.s << 16);
}

__device__ __forceinline__ void vnleaky3(const float* p, const float* dv, float* out) {
  float dot = p[0]*dv[0] + p[1]*dv[1] + p[2]*dv[2];
  float dsq = dv[0]*dv[0] + dv[1]*dv[1] + dv[2]*dv[2] + EPSF;
  float f = dot / dsq;
#pragma unroll
  for (int d = 0; d < 3; ++d) {
    float neg = p[d] - f * dv[d];
    out[d] = NSLOPE * p[d] + (1.f - NSLOPE) * ((dot >= 0.f) ? p[d] : neg);
  }
}

// ---------------- fused weight prep + LN1 (independent work; overlapped in one launch) ----------------
// blocks [0,1600): weight prep (M2 segment re-indexed for coalescing: c slow, j fast ->
// Wo reads coalesced, W2 reads wave-uniform scalar; identical summation order).
// blocks [1600, 1600+4096): LN1, 2 points per 256-thread block.
__global__ __launch_bounds__(256) void prep_ln1(
    const float* __restrict__ Wq, const float* __restrict__ Wk,
    const float* __restrict__ Wv, const float* __restrict__ Wo,
    const float* __restrict__ W1, const float* __restrict__ U1,
    const float* __restrict__ W2, const float* __restrict__ W3,
    const float* __restrict__ U3, const float* __restrict__ W4,
    const float* __restrict__ U4,
    ushort_t* __restrict__ Wall, _Float16* __restrict__ Af16,
    _Float16* __restrict__ W3h, _Float16* __restrict__ U3h,
    _Float16* __restrict__ W4h, _Float16* __restrict__ U4h,
    const float* __restrict__ xin, ushort_t* __restrict__ xbp,
    float* __restrict__ xdi, const float* __restrict__ g1,
    const float* __restrict__ b1) {
  __shared__ float red[8];
  int bi = blockIdx.x;
  if (bi >= 1600) {
    // ---- LN1: 2 points per block ----
    int t = threadIdx.x;
    int half = t >> 7, c = t & 127;
    int bn = (bi - 1600) * 2 + half;
    const float* row = xin + (size_t)bn * 384;
    float x0 = row[c*3+0], x1 = row[c*3+1], x2 = row[c*3+2];
    float nv = sqrtf(x0*x0 + x1*x1 + x2*x2 + EPSF);
    float s1 = nv, s2 = nv*nv;
#pragma unroll
    for (int off = 32; off >= 1; off >>= 1) {
      s1 += __shfl_down(s1, off);
      s2 += __shfl_down(s2, off);
    }
    int lane = t & 63, w = t >> 6;
    if (lane == 0) { red[w*2] = s1; red[w*2+1] = s2; }
    __syncthreads();
    int rb4 = (w >> 1) * 4;
    float tot1 = red[rb4] + red[rb4+2], tot2 = red[rb4+1] + red[rb4+3];
    float mu  = tot1 * (1.f/128.f);
    float var = tot2 * (1.f/128.f) - mu*mu;
    float rsig = rsqrtf(var + LNEPSF);
    float nnew = g1[c] * ((nv - mu) * rsig) + b1[c];
    float sc = nnew / nv;
    size_t rb = (size_t)bn * 384;
    xbp[rb + c]       = f2bf(x0*sc);
    xbp[rb + 128 + c] = f2bf(x1*sc);
    xbp[rb + 256 + c] = f2bf(x2*sc);
    xdi[rb + c]       = x0;
    xdi[rb + 128 + c] = x1;
    xdi[rb + 256 + c] = x2;
    return;
  }
  int idx = bi * 256 + threadIdx.x;
  if (idx < 212992) {
    int m = idx >> 7, c = idx & 127;
    float val;
    if (m < 384)       val = Wq[m*128 + c] * QSCALE;
    else if (m < 768)  val = Wk[(m-384)*128 + c];
    else if (m < 1152) val = Wv[(m-768)*128 + c];
    else {
      int j = m - 1152;
      if (j < 128)      val = W1[j*256 + c];
      else if (j < 256) val = U1[(j-128)*256 + c];
      else if (j < 384) { int o = j-256; val = W1[o*256 + 128 + c] - W1[o*256 + c]; }
      else              { int o = j-384; val = U1[o*256 + 128 + c] - U1[o*256 + c]; }
    }
    Wall[idx] = f2bf(val); return;
  }
  idx -= 212992;
  if (idx < 49152) {
    int c = idx / 384, j = idx % 384;   // coalesced: j fast -> Wo stride-4B, W2 wave-uniform
    float s = 0.f;
    for (int cp = 0; cp < 128; ++cp) s += W2[c*256 + cp] * Wo[cp*384 + j];
    Af16[(size_t)c*512 + j] = (_Float16)s; return;
  }
  idx -= 49152;
  if (idx < 16384) {
    int c2 = idx / 128, c = idx % 128;
    Af16[(size_t)c*512 + 384 + c2] = (_Float16)W2[c*256 + 128 + c2]; return;
  }
  idx -= 16384;
  if (idx < 32768) { W3h[idx] = (_Float16)W3[idx]; return; }
  idx -= 32768;
  if (idx < 32768) { U3h[idx] = (_Float16)U3[idx]; return; }
  idx -= 32768;
  if (idx < 32768) { W4h[idx] = (_Float16)W4[idx]; return; }
  idx -= 32768;
  if (idx < 32768) { U4h[idx] = (_Float16)U4[idx]; return; }
}

// ---------------- fused QKV + conv1 MFMA GEMM ----------------
#define XT_PITCH 132
#define WT_PITCH 132
#define TR_PITCH 36
__global__ __launch_bounds__(256, 2) void qkv_conv1_mfma(
    const ushort_t* __restrict__ xb, const ushort_t* __restrict__ Wall,
    ushort_t* __restrict__ q, ushort_t* __restrict__ k, ushort_t* __restrict__ v,
    _Float16* __restrict__ YZh, _Float16* __restrict__ NBh) {
  __shared__ ushort_t xs[128*XT_PITCH];
  __shared__ ushort_t wt[32*WT_PITCH];
  __shared__ float tr[4][32*TR_PITCH];
  int nb = blockIdx.x % 192;
  int mq = blockIdx.x / 192;
  int n0 = nb * 128;
  int t = threadIdx.x;
  int w = t >> 6, lane = t & 63, ql = lane & 31, hl = lane >> 5;
  for (int idx = t; idx < 2048; idx += 256) {
    int n = idx >> 4, c16 = idx & 15;
    bf16x8 gv = *(const bf16x8*)&xb[(size_t)(n0 + n)*128 + c16*8];
    ushort_t* dst = &xs[n*XT_PITCH + c16*8];
    *(bf16x4*)dst = __builtin_shufflevector(gv, gv, 0, 1, 2, 3);
    *(bf16x4*)(dst+4) = __builtin_shufflevector(gv, gv, 4, 5, 6, 7);
  }
  __syncthreads();
  bf16x8 xf[8];
  {
    const ushort_t* xr = &xs[(w*32 + ql)*XT_PITCH + hl*8];
#pragma unroll
    for (int cs = 0; cs < 8; ++cs) {
      bf16x4 lo = *(const bf16x4*)(xr + cs*16);
      bf16x4 hi = *(const bf16x4*)(xr + cs*16 + 4);
      xf[cs] = __builtin_shufflevector(lo, hi, 0, 1, 2, 3, 4, 5, 6, 7);
    }
  }
  int ng = n0 + w*32 + ql;
  int pt = ng / 3;
  int d  = ng - 3*pt;
  float* trw = tr[w];
  for (int mt = 0; mt < 13; ++mt) {
    int m0 = mq*416 + mt*32;
    __syncthreads();
    for (int idx = t; idx < 512; idx += 256) {
      int mm = idx >> 4, c16 = idx & 15;
      bf16x8 gv = *(const bf16x8*)&Wall[(size_t)(m0 + mm)*128 + c16*8];
      ushort_t* dst = &wt[mm*WT_PITCH + c16*8];
      *(bf16x4*)dst = __builtin_shufflevector(gv, gv, 0, 1, 2, 3);
      *(bf16x4*)(dst+4) = __builtin_shufflevector(gv, gv, 4, 5, 6, 7);
    }
    __syncthreads();
    f32x16 acc;
#pragma unroll
    for (int r = 0; r < 16; ++r) acc[r] = 0.f;
    const ushort_t* wr = &wt[ql*WT_PITCH + hl*8];
#pragma unroll
    for (int cs = 0; cs < 8; ++cs) {
      bf16x4 lo = *(const bf16x4*)(wr + cs*16);
      bf16x4 hi = *(const bf16x4*)(wr + cs*16 + 4);
      bf16x8 af = __builtin_shufflevector(lo, hi, 0, 1, 2, 3, 4, 5, 6, 7);
      acc = __builtin_amdgcn_mfma_f32_32x32x16_bf16(af, xf[cs], acc, 0, 0, 0);
    }
#pragma unroll
    for (int r = 0; r < 16; ++r) {
      int mrow = (r&3) + 8*(r>>2) + 4*hl;
      trw[ql*TR_PITCH + mrow] = acc[r];
    }
    asm volatile("s_waitcnt lgkmcnt(0)" ::: "memory");
    float4 c0 = *(float4*)&trw[ql*TR_PITCH + hl*16 + 0];
    float4 c1 = *(float4*)&trw[ql*TR_PITCH + hl*16 + 4];
    float4 c2 = *(float4*)&trw[ql*TR_PITCH + hl*16 + 8];
    float4 c3 = *(float4*)&trw[ql*TR_PITCH + hl*16 + 12];
    asm volatile("s_waitcnt lgkmcnt(0)" ::: "memory");
    int mg = m0 + hl*16;
    if (m0 < 1152) {
      uint4 s0, s1;
      s0.x = pack2(c0.x, c0.y); s0.y = pack2(c0.z, c0.w);
      s0.z = pack2(c1.x, c1.y); s0.w = pack2(c1.z, c1.w);
      s1.x = pack2(c2.x, c2.y); s1.y = pack2(c2.z, c2.w);
      s1.z = pack2(c3.x, c3.y); s1.w = pack2(c3.z, c3.w);
      ushort_t* dst;
      if (m0 < 384)       dst = q + (size_t)pt*1152 + d*384 + mg;
      else if (m0 < 768)  dst = k + (size_t)pt*1152 + d*384 + (mg - 384);
      else                dst = v + (size_t)pt*1152 + d*384 + (mg - 768);
      *(uint4*)dst = s0;
      *(uint4*)(dst + 8) = s1;
    } else {
      int mat = mg - 1152;
      int sub = mat >> 7, o = mat & 127;
      _Float16* basep = (sub < 2) ? YZh : NBh;
      _Float16* dst = basep + (size_t)pt*768 + d*256 + (sub & 1)*128 + o;
      uint4 s0, s1;
      s0.x = packh2(c0.x, c0.y); s0.y = packh2(c0.z, c0.w);
      s0.z = packh2(c1.x, c1.y); s0.w = packh2(c1.z, c1.w);
      s1.x = packh2(c2.x, c2.y); s1.y = packh2(c2.z, c2.w);
      s1.z = packh2(c3.x, c3.y); s1.w = packh2(c3.z, c3.w);
      *(uint4*)dst = s0;
      *(uint4*)(dst + 8) = s1;
    }
  }
}

// ---------------- fused V-transpose + conv1-post (independent; overlapped in one launch) ----------------
// blocks [0,768): LDS-tiled V transpose. blocks [768, 768+1024): conv1_post, 8 pts/block.
#define VT_LP 196
__global__ __launch_bounds__(256) void post_vtrans(const ushort_t* __restrict__ v,
    ushort_t* __restrict__ vT, const _Float16* __restrict__ YZh,
    const _Float16* __restrict__ NBh, const int* __restrict__ knn_index,
    _Float16* __restrict__ kmf16) {
  __shared__ ushort_t tl[64*VT_LP];   // 25088 B
  __shared__ int sidx[8][KNN];
  int blk = blockIdx.x;
  int t = threadIdx.x;
  if (blk < 768) {
    int bh = blk / 32, ptile = blk % 32;
    int b = bh / HH, h = bh % HH;
    int pt0 = ptile * 64;
#pragma unroll
    for (int i = 0; i < 6; ++i) {
      int u = i*256 + t;
      int p = u / 24, seg = u % 24;
      int d = seg >> 3, c8 = seg & 7;
      bf16x8 gv = *(const bf16x8*)&v[(size_t)(b*NFIX + pt0 + p)*1152 + d*384 + h*64 + c8*8];
      ushort_t* dst = &tl[p*VT_LP + d*64 + c8*8];
      *(bf16x4*)dst = __builtin_shufflevector(gv, gv, 0, 1, 2, 3);
      *(bf16x4*)(dst+4) = __builtin_shufflevector(gv, gv, 4, 5, 6, 7);
    }
    __syncthreads();
#pragma unroll
    for (int i = 0; i < 6; ++i) {
      int u = i*256 + t;
      int ch = u >> 3, pc = u & 7;
      int ol = ch / 3, dd = ch - 3*ol;
      int cloc = dd*64 + ol;
      ushort_t hv[8];
#pragma unroll
      for (int e = 0; e < 8; ++e)
        hv[e] = tl[(pc*8 + e)*VT_LP + cloc];
      uint4 o4;
      o4.x = (uint_t)hv[0] | ((uint_t)hv[1] << 16);
      o4.y = (uint_t)hv[2] | ((uint_t)hv[3] << 16);
      o4.z = (uint_t)hv[4] | ((uint_t)hv[5] << 16);
      o4.w = (uint_t)hv[6] | ((uint_t)hv[7] << 16);
      *(uint4*)&vT[((size_t)bh*192 + ch)*2048 + pt0 + pc*8] = o4;
    }
    return;
  }
  // conv1_post: 8 points per block; threads 0-127 -> pts 0-3, 128-255 -> pts 4-7
  int bnb = (blk - 768) * 8;
  int half = t >> 7, c = t & 127;
  if (t < 64) {
    int pi = t >> 3, kk = t & 7;
    int bn = bnb + pi;
    int b = bn / NFIX, n = bn % NFIX;
    sidx[pi][kk] = knn_index[(b*KNN + kk)*NFIX + n];
  }
  __syncthreads();
#pragma unroll
  for (int pi2 = 0; pi2 < 4; ++pi2) {
    int pi = half*4 + pi2;
    int bn = bnb + pi;
    float yb[3], zb[3];
#pragma unroll
    for (int d = 0; d < 3; ++d) {
      yb[d] = (float)NBh[(size_t)bn*768 + d*256 + c];
      zb[d] = (float)NBh[(size_t)bn*768 + d*256 + 128 + c];
    }
    float om[3] = {0.f, 0.f, 0.f};
#pragma unroll
    for (int kk = 0; kk < KNN; ++kk) {
      const _Float16* r = YZh + (size_t)sidx[pi][kk]*768;
      float p[3], dd[3];
#pragma unroll
      for (int d = 0; d < 3; ++d) {
        p[d]  = (float)r[d*256 + c] + yb[d];
        dd[d] = (float)r[d*256 + 128 + c] + zb[d];
      }
      float res[3];
      vnleaky3(p, dd, res);
      om[0] += res[0]; om[1] += res[1]; om[2] += res[2];
    }
#pragma unroll
    for (int d = 0; d < 3; ++d)
      kmf16[((size_t)bn*3 + d)*128 + c] = (_Float16)(om[d] * (1.f/KNN));
  }
}

// ---------------- attention (round-5 proven version): split-K=2, XCD-grouped decode,
// dual S-MFMA chains, pack2 RNE softmax, V LDS-staged dbuf, f16 O_s epilogue. ----------------
#define KT_P 196
#define VT_P 36
#define TW_P 195
__global__ __launch_bounds__(256, 2) void attn_kernel(const ushort_t* __restrict__ q,
    const ushort_t* __restrict__ k, const ushort_t* __restrict__ vT,
    ushort_t* __restrict__ opart, float* __restrict__ lpart) {
  __shared__ ushort_t kt[2][32*KT_P];
  __shared__ ushort_t vt[2][192*VT_P];
  __shared__ float alds[4][32];
  // XCD-aware decode: blocks round-robin XCDs by blockIdx%8. 48 (bh,split) groups, 6/XCD;
  // the 16 qt sharers of one K/V panel land on one XCD's L2.
  int blk = blockIdx.x;
  int xcd = blk & 7, j = blk >> 3;          // j in 0..95
  int g = xcd*6 + (j >> 4);                 // 48 groups
  int qt = j & 15;
  int bh = g % 24;
  int split = g / 24;                       // 0..1
  int b = bh / HH, h = bh % HH;
  int t = threadIdx.x;
  int w = t >> 6, lane = t & 63, ql = lane & 31, hl = lane >> 5;
  int qrow0 = qt*128 + w*32;
  const ushort_t* qpb = q + (size_t)(b*NFIX + qrow0 + ql)*1152 + h*64;
  bf16x8 qf[12];
#pragma unroll
  for (int cs = 0; cs < 12; ++cs) {
    int red0 = cs*16 + hl*8;
    int dq = red0 >> 6, ml = red0 & 63;
    qf[cs] = *(const bf16x8*)(qpb + dq*384 + ml);
  }
  const ushort_t* ksrc[3]; int kdsto[3];
  const ushort_t* vsrc[3]; int vdsto[3];
#pragma unroll
  for (int j2 = 0; j2 < 3; ++j2) {
    int idx = t + j2*256;
    int kp = idx / 24, c16 = idx % 24;
    int red0 = c16*8;
    int dk = red0 >> 6, ml = red0 & 63;
    ksrc[j2] = k + (size_t)(b*NFIX + kp)*1152 + dk*384 + h*64 + ml;
    kdsto[j2] = kp*KT_P + c16*8;
    int ch = idx >> 2, c4 = idx & 3;
    vsrc[j2] = vT + ((size_t)bh*192 + ch)*2048 + c4*8;
    vdsto[j2] = ch*VT_P + c4*8;
  }
  f32x16 acc[6];
#pragma unroll
  for (int nt = 0; nt < 6; ++nt)
#pragma unroll
    for (int r = 0; r < 16; ++r) acc[nt][r] = 0.f;
  float lsum = 0.f;
  int koff0 = split * 1024;                 // 1024 keys per split, 32 K-tiles
  bf16x8 kpre[3], vpre[3];
#pragma unroll
  for (int j2 = 0; j2 < 3; ++j2) {
    kpre[j2] = *(const bf16x8*)(ksrc[j2] + (size_t)koff0*1152);
    vpre[j2] = *(const bf16x8*)(vsrc[j2] + koff0);
  }
#pragma unroll
  for (int j2 = 0; j2 < 3; ++j2) {
    ushort_t* kd = &kt[0][kdsto[j2]];
    *(bf16x4*)kd = __builtin_shufflevector(kpre[j2], kpre[j2], 0, 1, 2, 3);
    *(bf16x4*)(kd+4) = __builtin_shufflevector(kpre[j2], kpre[j2], 4, 5, 6, 7);
    ushort_t* vd = &vt[0][vdsto[j2]];
    *(bf16x4*)vd = __builtin_shufflevector(vpre[j2], vpre[j2], 0, 1, 2, 3);
    *(bf16x4*)(vd+4) = __builtin_shufflevector(vpre[j2], vpre[j2], 4, 5, 6, 7);
  }
  __syncthreads();
  for (int kb = 0; kb < 32; ++kb) {
    int cur = kb & 1;
    if (kb < 31) {
      int koff = koff0 + (kb+1)*32;
#pragma unroll
      for (int j2 = 0; j2 < 3; ++j2) {
        kpre[j2] = *(const bf16x8*)(ksrc[j2] + (size_t)koff*1152);
        vpre[j2] = *(const bf16x8*)(vsrc[j2] + koff);
      }
    }
    // dual independent S accumulation chains (6-deep each instead of 12)
    f32x16 sca, scb;
#pragma unroll
    for (int r = 0; r < 16; ++r) { sca[r] = 0.f; scb[r] = 0.f; }
    const ushort_t* ktc = kt[cur];
#pragma unroll
    for (int cs = 0; cs < 12; ++cs) {
      const ushort_t* kr = &ktc[ql*KT_P + cs*16 + hl*8];
      bf16x4 alo = *(const bf16x4*)kr;
      bf16x4 ahi = *(const bf16x4*)(kr + 4);
      bf16x8 af = __builtin_shufflevector(alo, ahi, 0, 1, 2, 3, 4, 5, 6, 7);
      if (cs & 1) scb = __builtin_amdgcn_mfma_f32_32x32x16_bf16(af, qf[cs], scb, 0, 0, 0);
      else        sca = __builtin_amdgcn_mfma_f32_32x32x16_bf16(af, qf[cs], sca, 0, 0, 0);
    }
    uint_t u[8], pex[8];
#pragma unroll
    for (int g2 = 0; g2 < 4; ++g2) {
      float p0 = __builtin_amdgcn_exp2f(sca[g2*4 + 0] + scb[g2*4 + 0]);
      float p1 = __builtin_amdgcn_exp2f(sca[g2*4 + 1] + scb[g2*4 + 1]);
      float p2 = __builtin_amdgcn_exp2f(sca[g2*4 + 2] + scb[g2*4 + 2]);
      float p3 = __builtin_amdgcn_exp2f(sca[g2*4 + 3] + scb[g2*4 + 3]);
      lsum += (p0 + p1) + (p2 + p3);
      u[2*g2]   = pack2(p0, p1);
      u[2*g2+1] = pack2(p2, p3);
    }
#pragma unroll
    for (int j2 = 0; j2 < 8; ++j2) pex[j2] = (uint_t)__shfl_xor((int)u[j2], 32);
    const ushort_t* vtc = vt[cur];
#pragma unroll
    for (int s = 0; s < 2; ++s) {
      uint4 au;
      au.x = hl ? pex[4*s+2] : u[4*s+0];
      au.y = hl ? pex[4*s+3] : u[4*s+1];
      au.z = hl ? u[4*s+2]   : pex[4*s+0];
      au.w = hl ? u[4*s+3]   : pex[4*s+1];
      union { uint4 ui; bf16x8 bv; } cvt; cvt.ui = au;
      bf16x8 pa = cvt.bv;
#pragma unroll
      for (int nt = 0; nt < 6; ++nt) {
        const ushort_t* vr = &vtc[(nt*32 + ql)*VT_P + s*16 + hl*8];
        bf16x4 vlo = *(const bf16x4*)vr;
        bf16x4 vhi = *(const bf16x4*)(vr + 4);
        bf16x8 vf = __builtin_shufflevector(vlo, vhi, 0, 1, 2, 3, 4, 5, 6, 7);
        acc[nt] = __builtin_amdgcn_mfma_f32_32x32x16_bf16(pa, vf, acc[nt], 0, 0, 0);
      }
    }
    if (kb < 31) {
      int nxt = cur ^ 1;
#pragma unroll
      for (int j2 = 0; j2 < 3; ++j2) {
        ushort_t* kd = &kt[nxt][kdsto[j2]];
        *(bf16x4*)kd = __builtin_shufflevector(kpre[j2], kpre[j2], 0, 1, 2, 3);
        *(bf16x4*)(kd+4) = __builtin_shufflevector(kpre[j2], kpre[j2], 4, 5, 6, 7);
        ushort_t* vd = &vt[nxt][vdsto[j2]];
        *(bf16x4*)vd = __builtin_shufflevector(vpre[j2], vpre[j2], 0, 1, 2, 3);
        *(bf16x4*)(vd+4) = __builtin_shufflevector(vpre[j2], vpre[j2], 4, 5, 6, 7);
      }
    }
    __syncthreads();
  }
  lsum += __shfl_xor(lsum, 32);
  if (lane < 32) {
    alds[w][ql] = 1.0f / lsum;
    lpart[(size_t)split*24*NFIX + (size_t)bh*NFIX + qrow0 + ql] = lsum;
  }
  asm volatile("s_waitcnt lgkmcnt(0)" ::: "memory");
  float lv[4][4];
#pragma unroll
  for (int g2 = 0; g2 < 4; ++g2) {
    f32x4 tv = *(const f32x4*)&alds[w][8*g2 + 4*hl];
#pragma unroll
    for (int rr = 0; rr < 4; ++rr) lv[g2][rr] = tv[rr];
  }
  // ---- epilogue: O_s stored as f16 bits (split-combine precision) ----
  ushort_t* tw = (w == 0) ? kt[0] : (w == 1) ? kt[1] : (w == 2) ? vt[0] : vt[1];
#pragma unroll
  for (int nt = 0; nt < 6; ++nt) {
    int ch = nt*32 + ql;
#pragma unroll
    for (int r = 0; r < 16; ++r) {
      int qrow = (r&3) + 8*(r>>2) + 4*hl;
      tw[qrow*TW_P + ch] = f2h_bits(acc[nt][r] * lv[r>>2][r&3]);
    }
  }
  asm volatile("s_waitcnt lgkmcnt(0)" ::: "memory");
  const size_t SS = (size_t)8192*1152;
  ushort_t* opb = opart + (size_t)split*SS;
  size_t nbase = (size_t)(b*NFIX + qrow0) * 3;
#pragma unroll
  for (int i = 0; i < 12; ++i) {
    int chunk = i*64 + lane;
    int nl = chunk >> 3, jc = chunk & 7;
    int qq = nl / 3, dd = nl - 3*qq;
    ushort_t hv[8];
#pragma unroll
    for (int e = 0; e < 8; ++e)
      hv[e] = tw[qq*TW_P + (jc*8 + e)*3 + dd];
    uint4 sv;
    sv.x = (uint_t)hv[0] | ((uint_t)hv[1] << 16);
    sv.y = (uint_t)hv[2] | ((uint_t)hv[3] << 16);
    sv.z = (uint_t)hv[4] | ((uint_t)hv[5] << 16);
    sv.w = (uint_t)hv[6] | ((uint_t)hv[7] << 16);
    *(uint4*)&opb[(nbase + nl)*384 + h*64 + jc*8] = sv;
  }
}

// ---------------- x1mid fp16 MFMA + fused LN2 -> xmid (f32) and nxh (f16) ----------------
#define AP 68
#define XLP 132
__global__ __launch_bounds__(384) void x1mid_mfma(
    const float* __restrict__ xdi, const ushort_t* __restrict__ opart,
    const float* __restrict__ lpart, const _Float16* __restrict__ kmf16,
    const _Float16* __restrict__ Af16, float* __restrict__ xmid,
    _Float16* __restrict__ nxh, const float* __restrict__ g2,
    const float* __restrict__ b2) {
  __shared__ __align__(16) char smem[50944];
  _Float16* As = (_Float16*)smem;                 // 128 x AP = 17408 B
  _Float16* Bt = (_Float16*)(smem + 17408);       //  96 x AP = 13056 B
  float* wlsL  = (float*)(smem + 30464);          //  32 x 6 x 2 = 1536 B
  float* X     = (float*)smem;                    // epilogue overlay: 96 x XLP f32 = 50688 B
  float* stats = (float*)(smem + 50688);          // 32 x 2 f32 = 256 B
  int blk = blockIdx.x;
  int n0 = blk * 96;
  int pt0 = blk * 32;
  int t = threadIdx.x;
  int w = t >> 6, lane = t & 63, ql = lane & 31, hl = lane >> 5;
  int nsub = w >> 1, mh = w & 1;
  if (t < 192) {
    int ptl = t / 6, h = t % 6;
    int ptg = pt0 + ptl;
    int b = ptg >> 11, n = ptg & 2047;
    size_t lidx = (size_t)(b*HH + h)*NFIX + n;
    float l[NSPLIT]; float tot = 0.f;
#pragma unroll
    for (int s = 0; s < NSPLIT; ++s) {
      l[s] = lpart[(size_t)s*24*NFIX + lidx];
      tot += l[s];
    }
    float rd = 1.f / tot;
    float* wp = &wlsL[(ptl*6 + h)*NSPLIT];
#pragma unroll
    for (int s = 0; s < NSPLIT; ++s) wp[s] = l[s]*rd;
  }
  f32x16 acc[2];
#pragma unroll
  for (int m2 = 0; m2 < 2; ++m2)
#pragma unroll
    for (int r = 0; r < 16; ++r) acc[m2][r] = 0.f;
  const size_t SS = (size_t)8192*1152;
  __syncthreads();
  for (int p = 0; p < 8; ++p) {
    for (int u = t; u < 1024; u += 384) {
      int m = u >> 3, kc = u & 7;
      f16x4 a0 = *(const f16x4*)&Af16[(size_t)m*512 + p*64 + kc*8];
      f16x4 a1 = *(const f16x4*)&Af16[(size_t)m*512 + p*64 + kc*8 + 4];
      _Float16* dst = &As[m*AP + kc*8];
      *(f16x4*)dst = a0;
      *(f16x4*)(dst+4) = a1;
    }
    {
      int u = t;
      if (u < 384) {
        int n_l = u >> 2, jc = u & 3;
        int n_g = n0 + n_l;
        _Float16* dst = &Bt[n_l*AP + jc*16];
        if (p < 6) {
          int pt_l = n_l / 3;
          const float* wp = &wlsL[(pt_l*6 + p)*NSPLIT];
          float facc[16];
#pragma unroll
          for (int e = 0; e < 16; ++e) facc[e] = 0.f;
#pragma unroll
          for (int s = 0; s < NSPLIT; ++s) {
            const ushort_t* src = opart + s*SS + (size_t)n_g*384 + p*64 + jc*16;
            uint4 ra = *(const uint4*)src;
            uint4 rb = *(const uint4*)(src + 8);
            const _Float16* ua = (const _Float16*)&ra;
            const _Float16* ub = (const _Float16*)&rb;
            float wsc = wp[s];
#pragma unroll
            for (int e = 0; e < 8; ++e) {
              facc[e]     += wsc * (float)ua[e];
              facc[8 + e] += wsc * (float)ub[e];
            }
          }
          _Float16 hv[16];
#pragma unroll
          for (int e = 0; e < 16; ++e) hv[e] = (_Float16)facc[e];
#pragma unroll
          for (int g = 0; g < 4; ++g)
            *(f16x4*)(dst + g*4) = *(f16x4*)&hv[g*4];
        } else {
          const _Float16* src = kmf16 + (size_t)n_g*128 + (p-6)*64 + jc*16;
          f16x4 v0 = *(const f16x4*)src;
          f16x4 v1 = *(const f16x4*)(src + 4);
          f16x4 v2 = *(const f16x4*)(src + 8);
          f16x4 v3 = *(const f16x4*)(src + 12);
          *(f16x4*)dst = v0; *(f16x4*)(dst+4) = v1;
          *(f16x4*)(dst+8) = v2; *(f16x4*)(dst+12) = v3;
        }
      }
    }
    __syncthreads();
#pragma unroll
    for (int cs = 0; cs < 4; ++cs) {
      int kloc = cs*16 + hl*8;
      f16x4 b0 = *(const f16x4*)&Bt[(nsub*32 + ql)*AP + kloc];
      f16x4 b1 = *(const f16x4*)&Bt[(nsub*32 + ql)*AP + kloc + 4];
      f16x8 bf = __builtin_shufflevector(b0, b1, 0, 1, 2, 3, 4, 5, 6, 7);
#pragma unroll
      for (int m2 = 0; m2 < 2; ++m2) {
        int mrow = (mh*2 + m2)*32 + ql;
        f16x4 a0 = *(const f16x4*)&As[mrow*AP + kloc];
        f16x4 a1 = *(const f16x4*)&As[mrow*AP + kloc + 4];
        f16x8 af = __builtin_shufflevector(a0, a1, 0, 1, 2, 3, 4, 5, 6, 7);
        acc[m2] = __builtin_amdgcn_mfma_f32_32x32x16_f16(af, bf, acc[m2], 0, 0, 0);
      }
    }
    __syncthreads();
  }
  // ---- write acc directly into X (C frag: n = nsub*32+ql, c = mtile*32 + (r&3)+8*(r>>2)+4*hl) ----
#pragma unroll
  for (int m2 = 0; m2 < 2; ++m2) {
    int cbase = (mh*2 + m2)*32 + 4*hl;
    float* xrow = &X[(nsub*32 + ql)*XLP];
#pragma unroll
    for (int r = 0; r < 16; ++r) {
      int col = cbase + (r&3) + 8*(r>>2);
      xrow[col] = acc[m2][r];
    }
  }
  __syncthreads();
  // ---- Phase A: add residual (post-residual stays in X), emit xmid global ----
#pragma unroll
  for (int i = 0; i < 4; ++i) {
    int u = i*384 + t;                  // 96 rows x 16 chunks of 8
    int row = u >> 4, c0 = (u & 15) * 8;
    float* xp = &X[row*XLP + c0];
    const float* xd = xdi + (size_t)(n0 + row)*128 + c0;
    float4 a0 = *(float4*)xp, a1 = *(float4*)(xp + 4);
    float4 d0 = *(const float4*)xd, d1 = *(const float4*)(xd + 4);
    a0.x += d0.x; a0.y += d0.y; a0.z += d0.z; a0.w += d0.w;
    a1.x += d1.x; a1.y += d1.y; a1.z += d1.z; a1.w += d1.w;
    *(float4*)xp = a0; *(float4*)(xp + 4) = a1;
    float* dst = xmid + (size_t)(n0 + row)*128 + c0;
    *(float4*)dst = a0; *(float4*)(dst + 4) = a1;
  }
  __syncthreads();
  // ---- Phase B: per-point LN stats (6 waves cover 32 points) ----
  for (int pi = w; pi < 32; pi += 6) {
    int c = lane;
    float a0 = X[(pi*3+0)*XLP + c], a1 = X[(pi*3+1)*XLP + c], a2 = X[(pi*3+2)*XLP + c];
    float e0 = X[(pi*3+0)*XLP + c + 64], e1 = X[(pi*3+1)*XLP + c + 64], e2 = X[(pi*3+2)*XLP + c + 64];
    float nva = sqrtf(a0*a0 + a1*a1 + a2*a2 + EPSF);
    float nvb = sqrtf(e0*e0 + e1*e1 + e2*e2 + EPSF);
    float s1 = nva + nvb;
    float s2 = nva*nva + nvb*nvb;
#pragma unroll
    for (int off = 32; off >= 1; off >>= 1) {
      s1 += __shfl_down(s1, off);
      s2 += __shfl_down(s2, off);
    }
    if (lane == 0) {
      float mu = s1 * (1.f/128.f);
      float var = s2 * (1.f/128.f) - mu*mu;
      stats[pi*2]   = mu;
      stats[pi*2+1] = rsqrtf(var + LNEPSF);
    }
  }
  __syncthreads();
  // ---- Phase C: emit nxh f16 (LN2-normalized) ----
#pragma unroll
  for (int i = 0; i < 4; ++i) {
    int u = i*384 + t;
    int row = u >> 4, c0 = (u & 15) * 8;
    int pt_l = row / 3;
    float mu = stats[pt_l*2], rsig = stats[pt_l*2+1];
    const float* r0 = &X[(pt_l*3 + 0)*XLP + c0];
    const float* r1 = &X[(pt_l*3 + 1)*XLP + c0];
    const float* r2 = &X[(pt_l*3 + 2)*XLP + c0];
    const float* rd = &X[row*XLP + c0];
    float xv[8];
#pragma unroll
    for (int e = 0; e < 8; ++e) {
      float x0 = r0[e], x1 = r1[e], x2 = r2[e];
      float nv = sqrtf(x0*x0 + x1*x1 + x2*x2 + EPSF);
      float nnew = g2[c0 + e] * ((nv - mu) * rsig) + b2[c0 + e];
      xv[e] = rd[e] * (nnew / nv);
    }
    uint4 sv;
    sv.x = packh2(xv[0], xv[1]); sv.y = packh2(xv[2], xv[3]);
    sv.z = packh2(xv[4], xv[5]); sv.w = packh2(xv[6], xv[7]);
    *(uint4*)&nxh[(size_t)(n0 + row)*128 + c0] = sv;
  }
}

// ---------------- conv3: f16 MFMA, 3 d-plane GEMMs/wave ----------------
#define X3P 132
#define TR3P 36
__global__ __launch_bounds__(256) void conv3_mfma(const _Float16* __restrict__ nxh,
    const _Float16* __restrict__ W3h, const _Float16* __restrict__ U3h,
    _Float16* __restrict__ h3) {
  __shared__ __align__(16) _Float16 Xs[3*32*X3P];     // 25344 B
  __shared__ __align__(16) _Float16 tr3[4][96*TR3P];  // 27648 B
  int blk = blockIdx.x;
  int pt0 = (blk >> 1) * 32;
  int oh = blk & 1;
  int t = threadIdx.x;
  int w = t >> 6, lane = t & 63, ql = lane & 31, hl = lane >> 5;
#pragma unroll
  for (int i = 0; i < 6; ++i) {
    int u = i*256 + t;
    int r = u >> 4, c8 = u & 15;
    f16x8 gv = *(const f16x8*)&nxh[(size_t)(pt0*3 + r)*128 + c8*8];
    int d = r % 3, p = r / 3;
    _Float16* dst = &Xs[(d*32 + p)*X3P + c8*8];
    *(f16x4*)dst = __builtin_shufflevector(gv, gv, 0, 1, 2, 3);
    *(f16x4*)(dst+4) = __builtin_shufflevector(gv, gv, 4, 5, 6, 7);
  }
  __syncthreads();
  int ot = oh*128 + w*32;
  const _Float16* Wp = W3h + (size_t)(ot + ql)*128 + hl*8;
  const _Float16* Up = U3h + (size_t)(ot + ql)*128 + hl*8;
  f32x16 accP[3], accD[3];
#pragma unroll
  for (int d = 0; d < 3; ++d)
#pragma unroll
    for (int r = 0; r < 16; ++r) { accP[d][r] = 0.f; accD[d][r] = 0.f; }
#pragma unroll
  for (int cs = 0; cs < 8; ++cs) {
    f16x8 wf = *(const f16x8*)(Wp + cs*16);
    f16x8 uf = *(const f16x8*)(Up + cs*16);
#pragma unroll
    for (int d = 0; d < 3; ++d) {
      const _Float16* xr = &Xs[(d*32 + ql)*X3P + cs*16 + hl*8];
      f16x4 lo = *(const f16x4*)xr;
      f16x4 hi = *(const f16x4*)(xr + 4);
      f16x8 xf = __builtin_shufflevector(lo, hi, 0, 1, 2, 3, 4, 5, 6, 7);
      accP[d] = __builtin_amdgcn_mfma_f32_32x32x16_f16(wf, xf, accP[d], 0, 0, 0);
      accD[d] = __builtin_amdgcn_mfma_f32_32x32x16_f16(uf, xf, accD[d], 0, 0, 0);
    }
  }
  _Float16* trw = tr3[w];
#pragma unroll
  for (int r = 0; r < 16; ++r) {
    int olr = (r&3) + 8*(r>>2) + 4*hl;
    float p3[3], d3[3], res[3];
#pragma unroll
    for (int d = 0; d < 3; ++d) { p3[d] = accP[d][r]; d3[d] = accD[d][r]; }
    vnleaky3(p3, d3, res);
#pragma unroll
    for (int d = 0; d < 3; ++d) trw[(ql*3 + d)*TR3P + olr] = (_Float16)res[d];
  }
  asm volatile("s_waitcnt lgkmcnt(0)" ::: "memory");
#pragma unroll
  for (int i = 0; i < 6; ++i) {
    int u = i*64 + lane;
    int row = u >> 2, c8 = u & 3;
    const _Float16* src = &trw[row*TR3P + c8*8];
    f16x4 lo = *(const f16x4*)src;
    f16x4 hi = *(const f16x4*)(src + 4);
    f16x8 ov = __builtin_shufflevector(lo, hi, 0, 1, 2, 3, 4, 5, 6, 7);
    *(f16x8*)&h3[(size_t)(pt0*3 + row)*256 + ot + c8*8] = ov;
  }
}

// ---------------- conv4: f16 MFMA (16x16x32), + xmid residual ----------------
#define X4P 260
#define TF4P 388
__global__ __launch_bounds__(256) void conv4_mfma(const _Float16* __restrict__ h3,
    const _Float16* __restrict__ W4h, const _Float16* __restrict__ U4h,
    const float* __restrict__ xmid, float* __restrict__ out) {
  __shared__ __align__(16) _Float16 Xs[3*16*X4P];   // 24960 B
  __shared__ __align__(16) float trF[16*TF4P];      // 24832 B
  int pt0 = blockIdx.x * 16;
  int t = threadIdx.x;
  int w = t >> 6, lane = t & 63;
  int nl = lane & 15, kq = lane >> 4;
#pragma unroll
  for (int i = 0; i < 6; ++i) {
    int u = i*256 + t;
    int r = u >> 5, c8 = u & 31;
    f16x8 gv = *(const f16x8*)&h3[(size_t)(pt0*3 + r)*256 + c8*8];
    int d = r % 3, p = r / 3;
    _Float16* dst = &Xs[(d*16 + p)*X4P + c8*8];
    *(f16x4*)dst = __builtin_shufflevector(gv, gv, 0, 1, 2, 3);
    *(f16x4*)(dst+4) = __builtin_shufflevector(gv, gv, 4, 5, 6, 7);
  }
  __syncthreads();
  int ot = w*32;
  f32x4 accP[2][3], accD[2][3];
#pragma unroll
  for (int mt = 0; mt < 2; ++mt)
#pragma unroll
    for (int d = 0; d < 3; ++d)
#pragma unroll
      for (int r = 0; r < 4; ++r) { accP[mt][d][r] = 0.f; accD[mt][d][r] = 0.f; }
  const _Float16* Wb = W4h + (size_t)ot*256;
  const _Float16* Ub = U4h + (size_t)ot*256;
#pragma unroll
  for (int cs = 0; cs < 8; ++cs) {
    int kof = cs*32 + kq*8;
    f16x8 xf[3];
#pragma unroll
    for (int d = 0; d < 3; ++d) {
      const _Float16* xr = &Xs[(d*16 + nl)*X4P + kof];
      f16x4 lo = *(const f16x4*)xr;
      f16x4 hi = *(const f16x4*)(xr + 4);
      xf[d] = __builtin_shufflevector(lo, hi, 0, 1, 2, 3, 4, 5, 6, 7);
    }
#pragma unroll
    for (int mt = 0; mt < 2; ++mt) {
      f16x8 wf = *(const f16x8*)(Wb + (size_t)(mt*16 + nl)*256 + kof);
      f16x8 uf = *(const f16x8*)(Ub + (size_t)(mt*16 + nl)*256 + kof);
#pragma unroll
      for (int d = 0; d < 3; ++d) {
        accP[mt][d] = __builtin_amdgcn_mfma_f32_16x16x32_f16(wf, xf[d], accP[mt][d], 0, 0, 0);
        accD[mt][d] = __builtin_amdgcn_mfma_f32_16x16x32_f16(uf, xf[d], accD[mt][d], 0, 0, 0);
      }
    }
  }
#pragma unroll
  for (int mt = 0; mt < 2; ++mt)
#pragma unroll
    for (int r = 0; r < 4; ++r) {
      int o = ot + mt*16 + kq*4 + r;
      float p3[3], d3[3], res[3];
#pragma unroll
      for (int d = 0; d < 3; ++d) { p3[d] = accP[mt][d][r]; d3[d] = accD[mt][d][r]; }
      vnleaky3(p3, d3, res);
#pragma unroll
      for (int d = 0; d < 3; ++d) trF[nl*TF4P + o*3 + d] = res[d];
    }
  __syncthreads();
#pragma unroll
  for (int i = 0; i < 6; ++i) {
    int u = i*256 + t;
    int row = u / 96, c4 = u % 96;
    float4 vv = *(float4*)&trF[row*TF4P + c4*4];
    int bn = pt0 + row;
    float rs[4];
    const float* fv = (const float*)&vv;
#pragma unroll
    for (int e = 0; e < 4; ++e) {
      int col = c4*4 + e;
      int o = col / 3, d = col - 3*o;
      rs[e] = fv[e] + xmid[(size_t)(3*bn + d)*128 + o];
    }
    float4 ov; ov.x = rs[0]; ov.y = rs[1]; ov.z = rs[2]; ov.w = rs[3];
    *(float4*)&out[(size_t)bn*384 + c4*4] = ov;
  }
}

extern "C" void kernel_launch(void* const* d_in, const int* in_sizes, int n_in,
                              void* d_out, int out_size, void* d_ws, size_t ws_size,
                              hipStream_t stream) {
  const float* x   = (const float*)d_in[0];
  const int* knn   = (const int*)d_in[1];
  const float* g1  = (const float*)d_in[2];
  const float* b1  = (const float*)d_in[3];
  const float* g2  = (const float*)d_in[4];
  const float* b2  = (const float*)d_in[5];
  const float* Wq  = (const float*)d_in[6];
  const float* Wk  = (const float*)d_in[7];
  const float* Wv  = (const float*)d_in[8];
  const float* Wo  = (const float*)d_in[9];
  const float* W1  = (const float*)d_in[10];
  const float* U1  = (const float*)d_in[11];
  const float* W2  = (const float*)d_in[12];
  const float* W3  = (const float*)d_in[13];
  const float* U3  = (const float*)d_in[14];
  const float* W4  = (const float*)d_in[15];
  const float* U4  = (const float*)d_in[16];
  float* out = (float*)d_out;
  (void)n_in; (void)out_size; (void)ws_size;

  const size_t BN = (size_t)in_sizes[0] / 384;   // 8192

  float* ws    = (float*)d_ws;
  float* xdi   = ws;                          // BN*384 f32 (raw x, de-interleaved [n][c])
  float* xmid  = xdi + BN*384;                // BN*384 f32 (x_mid, de-interleaved)
  _Float16* kmf16 = (_Float16*)(xmid + BN*384);  // BN*384 fp16 [n][128]
  ushort_t* xbp = (ushort_t*)(kmf16 + BN*384);   // BN*384 bf16 (LN1 normalized, de-interleaved)
  ushort_t* qb = xbp + BN*384;                // BN*1152 bf16
  ushort_t* kb = qb + BN*1152;
  ushort_t* vb = kb + BN*1152;
  ushort_t* vT = vb + BN*1152;
  ushort_t* Wall = vT + BN*1152;              // 212992 bf16
  _Float16* Af16 = (_Float16*)(Wall + 212992);   // 65536 fp16
  _Float16* W3h = Af16 + 65536;               // 32768 fp16
  _Float16* U3h = W3h + 32768;
  _Float16* W4h = U3h + 32768;
  _Float16* U4h = W4h + 32768;
  ushort_t* opart = (ushort_t*)(U4h + 32768); // region 4*BN*1152 (2 splits used)
  float* lpart = (float*)(opart + 4*BN*1152); // 2*24*2048 f32
  // YZh/NBh (BN*768 f16 each = 12.6 MB) alias the opart region: conv1_post runs before attn.
  _Float16* YZh = (_Float16*)opart;
  _Float16* NBh = YZh + BN*768;
  _Float16* nxh = (_Float16*)qb;   // q dead after x1mid; LN2 out f16 [ng][128]
  _Float16* h3  = (_Float16*)kb;   // k dead after attention; conv3 out f16 [ng][256]

  prep_ln1<<<1600 + 4096, 256, 0, stream>>>(Wq, Wk, Wv, Wo, W1, U1, W2, W3, U3, W4, U4,
                                            Wall, Af16, W3h, U3h, W4h, U4h,
                                            x, xbp, xdi, g1, b1);
  qkv_conv1_mfma<<<192*4, 256, 0, stream>>>(xbp, Wall, qb, kb, vb, YZh, NBh);
  post_vtrans<<<768 + 1024, 256, 0, stream>>>(vb, vT, YZh, NBh, knn, kmf16);
  attn_kernel<<<16*24*NSPLIT, 256, 0, stream>>>(qb, kb, vT, opart, lpart);
  x1mid_mfma<<<256, 384, 0, stream>>>(xdi, opart, lpart, kmf16, Af16, xmid, nxh, g2, b2);
  conv3_mfma<<<512, 256, 0, stream>>>(nxh, W3h, U3h, h3);
  conv4_mfma<<<512, 256, 0, stream>>>(h3, W4h, U4h, xmid, out);
}

// Round 10
// 316.036 us; speedup vs baseline: 1.2521x; 1.0105x over previous
//
#include <hip/hip_runtime.h>
#include <math.h>

// Problem constants (fixed by setup_inputs): B=4, N=2048, C=128, H=6, K=8
#define NFIX 2048
#define HH 6
#define KNN 8
#define NSLOPE 0.2f
#define EPSF 1e-6f
#define LNEPSF 1e-5f
// 0.125 (softmax scale) * log2(e), folded into Wq rows so S-MFMA output is exp2-ready
#define QSCALE 0.18033688011112042f
#define NSPLIT 2

typedef unsigned short ushort_t;
typedef unsigned int uint_t;
typedef __attribute__((ext_vector_type(8))) short bf16x8;
typedef __attribute__((ext_vector_type(4))) short bf16x4;
typedef __attribute__((ext_vector_type(8))) _Float16 f16x8;
typedef __attribute__((ext_vector_type(4))) _Float16 f16x4;
typedef __attribute__((ext_vector_type(16))) float f32x16;
typedef __attribute__((ext_vector_type(4))) float f32x4;

__device__ __forceinline__ ushort_t f2bf(float f) {
  union { float f; unsigned u; } v; v.f = f;
  unsigned r = v.u + 0x7fff + ((v.u >> 16) & 1);   // RNE
  return (ushort_t)(r >> 16);
}
__device__ __forceinline__ float bf2f(ushort_t u) {
  union { uint_t u; float f; } v; v.u = ((uint_t)u) << 16; return v.f;
}
__device__ __forceinline__ uint_t pack2(float a, float b) {
  return (uint_t)f2bf(a) | ((uint_t)f2bf(b) << 16);
}
// f32 -> f16 bit pattern (register-only)
__device__ __forceinline__ ushort_t f2h_bits(float a) {
  union { _Float16 h; ushort_t s; } cv; cv.h = (_Float16)a; return cv.s;
}
// pack two fp32 -> two f16 in one dword (register-only; no local-array aliasing)
__device__ __forceinline__ uint_t packh2(float a, float b) {
  union { _Float16 h; ushort_t s; } ha, hb;
  ha.h = (_Float16)a; hb.h = (_Float16)b;
  return (uint_t)ha.s | ((uint_t)hb.s << 16);
}

__device__ __forceinline__ void vnleaky3(const float* p, const float* dv, float* out) {
  float dot = p[0]*dv[0] + p[1]*dv[1] + p[2]*dv[2];
  float dsq = dv[0]*dv[0] + dv[1]*dv[1] + dv[2]*dv[2] + EPSF;
  float f = dot / dsq;
#pragma unroll
  for (int d = 0; d < 3; ++d) {
    float neg = p[d] - f * dv[d];
    out[d] = NSLOPE * p[d] + (1.f - NSLOPE) * ((dot >= 0.f) ? p[d] : neg);
  }
}

// ---------------- fused weight prep + LN1 (independent work; overlapped in one launch) ----------------
// blocks [0,1600): weight prep (M2 segment re-indexed for coalescing: c slow, j fast ->
// Wo reads coalesced, W2 reads wave-uniform scalar; identical summation order).
// blocks [1600, 1600+4096): LN1, 2 points per 256-thread block.
__global__ __launch_bounds__(256) void prep_ln1(
    const float* __restrict__ Wq, const float* __restrict__ Wk,
    const float* __restrict__ Wv, const float* __restrict__ Wo,
    const float* __restrict__ W1, const float* __restrict__ U1,
    const float* __restrict__ W2, const float* __restrict__ W3,
    const float* __restrict__ U3, const float* __restrict__ W4,
    const float* __restrict__ U4,
    ushort_t* __restrict__ Wall, _Float16* __restrict__ Af16,
    _Float16* __restrict__ W3h, _Float16* __restrict__ U3h,
    _Float16* __restrict__ W4h, _Float16* __restrict__ U4h,
    const float* __restrict__ xin, ushort_t* __restrict__ xbp,
    float* __restrict__ xdi, const float* __restrict__ g1,
    const float* __restrict__ b1) {
  __shared__ float red[8];
  int bi = blockIdx.x;
  if (bi >= 1600) {
    // ---- LN1: 2 points per block ----
    int t = threadIdx.x;
    int half = t >> 7, c = t & 127;
    int bn = (bi - 1600) * 2 + half;
    const float* row = xin + (size_t)bn * 384;
    float x0 = row[c*3+0], x1 = row[c*3+1], x2 = row[c*3+2];
    float nv = sqrtf(x0*x0 + x1*x1 + x2*x2 + EPSF);
    float s1 = nv, s2 = nv*nv;
#pragma unroll
    for (int off = 32; off >= 1; off >>= 1) {
      s1 += __shfl_down(s1, off);
      s2 += __shfl_down(s2, off);
    }
    int lane = t & 63, w = t >> 6;
    if (lane == 0) { red[w*2] = s1; red[w*2+1] = s2; }
    __syncthreads();
    int rb4 = (w >> 1) * 4;
    float tot1 = red[rb4] + red[rb4+2], tot2 = red[rb4+1] + red[rb4+3];
    float mu  = tot1 * (1.f/128.f);
    float var = tot2 * (1.f/128.f) - mu*mu;
    float rsig = rsqrtf(var + LNEPSF);
    float nnew = g1[c] * ((nv - mu) * rsig) + b1[c];
    float sc = nnew / nv;
    size_t rb = (size_t)bn * 384;
    xbp[rb + c]       = f2bf(x0*sc);
    xbp[rb + 128 + c] = f2bf(x1*sc);
    xbp[rb + 256 + c] = f2bf(x2*sc);
    xdi[rb + c]       = x0;
    xdi[rb + 128 + c] = x1;
    xdi[rb + 256 + c] = x2;
    return;
  }
  int idx = bi * 256 + threadIdx.x;
  if (idx < 212992) {
    int m = idx >> 7, c = idx & 127;
    float val;
    if (m < 384)       val = Wq[m*128 + c] * QSCALE;
    else if (m < 768)  val = Wk[(m-384)*128 + c];
    else if (m < 1152) val = Wv[(m-768)*128 + c];
    else {
      int j = m - 1152;
      if (j < 128)      val = W1[j*256 + c];
      else if (j < 256) val = U1[(j-128)*256 + c];
      else if (j < 384) { int o = j-256; val = W1[o*256 + 128 + c] - W1[o*256 + c]; }
      else              { int o = j-384; val = U1[o*256 + 128 + c] - U1[o*256 + c]; }
    }
    Wall[idx] = f2bf(val); return;
  }
  idx -= 212992;
  if (idx < 49152) {
    int c = idx / 384, j = idx % 384;   // coalesced: j fast -> Wo stride-4B, W2 wave-uniform
    float s = 0.f;
    for (int cp = 0; cp < 128; ++cp) s += W2[c*256 + cp] * Wo[cp*384 + j];
    Af16[(size_t)c*512 + j] = (_Float16)s; return;
  }
  idx -= 49152;
  if (idx < 16384) {
    int c2 = idx / 128, c = idx % 128;
    Af16[(size_t)c*512 + 384 + c2] = (_Float16)W2[c*256 + 128 + c2]; return;
  }
  idx -= 16384;
  if (idx < 32768) { W3h[idx] = (_Float16)W3[idx]; return; }
  idx -= 32768;
  if (idx < 32768) { U3h[idx] = (_Float16)U3[idx]; return; }
  idx -= 32768;
  if (idx < 32768) { W4h[idx] = (_Float16)W4[idx]; return; }
  idx -= 32768;
  if (idx < 32768) { U4h[idx] = (_Float16)U4[idx]; return; }
}

// ---------------- fused QKV + conv1 MFMA GEMM ----------------
#define XT_PITCH 132
#define WT_PITCH 132
#define TR_PITCH 36
__global__ __launch_bounds__(256, 2) void qkv_conv1_mfma(
    const ushort_t* __restrict__ xb, const ushort_t* __restrict__ Wall,
    ushort_t* __restrict__ q, ushort_t* __restrict__ k, ushort_t* __restrict__ v,
    _Float16* __restrict__ YZh, _Float16* __restrict__ NBh) {
  __shared__ ushort_t xs[128*XT_PITCH];
  __shared__ ushort_t wt[32*WT_PITCH];
  __shared__ float tr[4][32*TR_PITCH];
  int nb = blockIdx.x % 192;
  int mq = blockIdx.x / 192;
  int n0 = nb * 128;
  int t = threadIdx.x;
  int w = t >> 6, lane = t & 63, ql = lane & 31, hl = lane >> 5;
  for (int idx = t; idx < 2048; idx += 256) {
    int n = idx >> 4, c16 = idx & 15;
    bf16x8 gv = *(const bf16x8*)&xb[(size_t)(n0 + n)*128 + c16*8];
    ushort_t* dst = &xs[n*XT_PITCH + c16*8];
    *(bf16x4*)dst = __builtin_shufflevector(gv, gv, 0, 1, 2, 3);
    *(bf16x4*)(dst+4) = __builtin_shufflevector(gv, gv, 4, 5, 6, 7);
  }
  __syncthreads();
  bf16x8 xf[8];
  {
    const ushort_t* xr = &xs[(w*32 + ql)*XT_PITCH + hl*8];
#pragma unroll
    for (int cs = 0; cs < 8; ++cs) {
      bf16x4 lo = *(const bf16x4*)(xr + cs*16);
      bf16x4 hi = *(const bf16x4*)(xr + cs*16 + 4);
      xf[cs] = __builtin_shufflevector(lo, hi, 0, 1, 2, 3, 4, 5, 6, 7);
    }
  }
  int ng = n0 + w*32 + ql;
  int pt = ng / 3;
  int d  = ng - 3*pt;
  float* trw = tr[w];
  for (int mt = 0; mt < 13; ++mt) {
    int m0 = mq*416 + mt*32;
    __syncthreads();
    for (int idx = t; idx < 512; idx += 256) {
      int mm = idx >> 4, c16 = idx & 15;
      bf16x8 gv = *(const bf16x8*)&Wall[(size_t)(m0 + mm)*128 + c16*8];
      ushort_t* dst = &wt[mm*WT_PITCH + c16*8];
      *(bf16x4*)dst = __builtin_shufflevector(gv, gv, 0, 1, 2, 3);
      *(bf16x4*)(dst+4) = __builtin_shufflevector(gv, gv, 4, 5, 6, 7);
    }
    __syncthreads();
    f32x16 acc;
#pragma unroll
    for (int r = 0; r < 16; ++r) acc[r] = 0.f;
    const ushort_t* wr = &wt[ql*WT_PITCH + hl*8];
#pragma unroll
    for (int cs = 0; cs < 8; ++cs) {
      bf16x4 lo = *(const bf16x4*)(wr + cs*16);
      bf16x4 hi = *(const bf16x4*)(wr + cs*16 + 4);
      bf16x8 af = __builtin_shufflevector(lo, hi, 0, 1, 2, 3, 4, 5, 6, 7);
      acc = __builtin_amdgcn_mfma_f32_32x32x16_bf16(af, xf[cs], acc, 0, 0, 0);
    }
#pragma unroll
    for (int r = 0; r < 16; ++r) {
      int mrow = (r&3) + 8*(r>>2) + 4*hl;
      trw[ql*TR_PITCH + mrow] = acc[r];
    }
    asm volatile("s_waitcnt lgkmcnt(0)" ::: "memory");
    float4 c0 = *(float4*)&trw[ql*TR_PITCH + hl*16 + 0];
    float4 c1 = *(float4*)&trw[ql*TR_PITCH + hl*16 + 4];
    float4 c2 = *(float4*)&trw[ql*TR_PITCH + hl*16 + 8];
    float4 c3 = *(float4*)&trw[ql*TR_PITCH + hl*16 + 12];
    asm volatile("s_waitcnt lgkmcnt(0)" ::: "memory");
    int mg = m0 + hl*16;
    if (m0 < 1152) {
      uint4 s0, s1;
      s0.x = pack2(c0.x, c0.y); s0.y = pack2(c0.z, c0.w);
      s0.z = pack2(c1.x, c1.y); s0.w = pack2(c1.z, c1.w);
      s1.x = pack2(c2.x, c2.y); s1.y = pack2(c2.z, c2.w);
      s1.z = pack2(c3.x, c3.y); s1.w = pack2(c3.z, c3.w);
      ushort_t* dst;
      if (m0 < 384)       dst = q + (size_t)pt*1152 + d*384 + mg;
      else if (m0 < 768)  dst = k + (size_t)pt*1152 + d*384 + (mg - 384);
      else                dst = v + (size_t)pt*1152 + d*384 + (mg - 768);
      *(uint4*)dst = s0;
      *(uint4*)(dst + 8) = s1;
    } else {
      int mat = mg - 1152;
      int sub = mat >> 7, o = mat & 127;
      _Float16* basep = (sub < 2) ? YZh : NBh;
      _Float16* dst = basep + (size_t)pt*768 + d*256 + (sub & 1)*128 + o;
      uint4 s0, s1;
      s0.x = packh2(c0.x, c0.y); s0.y = packh2(c0.z, c0.w);
      s0.z = packh2(c1.x, c1.y); s0.w = packh2(c1.z, c1.w);
      s1.x = packh2(c2.x, c2.y); s1.y = packh2(c2.z, c2.w);
      s1.z = packh2(c3.x, c3.y); s1.w = packh2(c3.z, c3.w);
      *(uint4*)dst = s0;
      *(uint4*)(dst + 8) = s1;
    }
  }
}

// ---------------- fused V-transpose + conv1-post (independent; overlapped in one launch) ----------------
// blocks [0,768): LDS-tiled V transpose. blocks [768, 768+1024): conv1_post, 8 pts/block.
#define VT_LP 196
__global__ __launch_bounds__(256) void post_vtrans(const ushort_t* __restrict__ v,
    ushort_t* __restrict__ vT, const _Float16* __restrict__ YZh,
    const _Float16* __restrict__ NBh, const int* __restrict__ knn_index,
    _Float16* __restrict__ kmf16) {
  __shared__ ushort_t tl[64*VT_LP];   // 25088 B
  __shared__ int sidx[8][KNN];
  int blk = blockIdx.x;
  int t = threadIdx.x;
  if (blk < 768) {
    int bh = blk / 32, ptile = blk % 32;
    int b = bh / HH, h = bh % HH;
    int pt0 = ptile * 64;
#pragma unroll
    for (int i = 0; i < 6; ++i) {
      int u = i*256 + t;
      int p = u / 24, seg = u % 24;
      int d = seg >> 3, c8 = seg & 7;
      bf16x8 gv = *(const bf16x8*)&v[(size_t)(b*NFIX + pt0 + p)*1152 + d*384 + h*64 + c8*8];
      ushort_t* dst = &tl[p*VT_LP + d*64 + c8*8];
      *(bf16x4*)dst = __builtin_shufflevector(gv, gv, 0, 1, 2, 3);
      *(bf16x4*)(dst+4) = __builtin_shufflevector(gv, gv, 4, 5, 6, 7);
    }
    __syncthreads();
#pragma unroll
    for (int i = 0; i < 6; ++i) {
      int u = i*256 + t;
      int ch = u >> 3, pc = u & 7;
      int ol = ch / 3, dd = ch - 3*ol;
      int cloc = dd*64 + ol;
      ushort_t hv[8];
#pragma unroll
      for (int e = 0; e < 8; ++e)
        hv[e] = tl[(pc*8 + e)*VT_LP + cloc];
      uint4 o4;
      o4.x = (uint_t)hv[0] | ((uint_t)hv[1] << 16);
      o4.y = (uint_t)hv[2] | ((uint_t)hv[3] << 16);
      o4.z = (uint_t)hv[4] | ((uint_t)hv[5] << 16);
      o4.w = (uint_t)hv[6] | ((uint_t)hv[7] << 16);
      *(uint4*)&vT[((size_t)bh*192 + ch)*2048 + pt0 + pc*8] = o4;
    }
    return;
  }
  // conv1_post: 8 points per block; threads 0-127 -> pts 0-3, 128-255 -> pts 4-7
  int bnb = (blk - 768) * 8;
  int half = t >> 7, c = t & 127;
  if (t < 64) {
    int pi = t >> 3, kk = t & 7;
    int bn = bnb + pi;
    int b = bn / NFIX, n = bn % NFIX;
    sidx[pi][kk] = knn_index[(b*KNN + kk)*NFIX + n];
  }
  __syncthreads();
#pragma unroll
  for (int pi2 = 0; pi2 < 4; ++pi2) {
    int pi = half*4 + pi2;
    int bn = bnb + pi;
    float yb[3], zb[3];
#pragma unroll
    for (int d = 0; d < 3; ++d) {
      yb[d] = (float)NBh[(size_t)bn*768 + d*256 + c];
      zb[d] = (float)NBh[(size_t)bn*768 + d*256 + 128 + c];
    }
    float om[3] = {0.f, 0.f, 0.f};
#pragma unroll
    for (int kk = 0; kk < KNN; ++kk) {
      const _Float16* r = YZh + (size_t)sidx[pi][kk]*768;
      float p[3], dd[3];
#pragma unroll
      for (int d = 0; d < 3; ++d) {
        p[d]  = (float)r[d*256 + c] + yb[d];
        dd[d] = (float)r[d*256 + 128 + c] + zb[d];
      }
      float res[3];
      vnleaky3(p, dd, res);
      om[0] += res[0]; om[1] += res[1]; om[2] += res[2];
    }
#pragma unroll
    for (int d = 0; d < 3; ++d)
      kmf16[((size_t)bn*3 + d)*128 + c] = (_Float16)(om[d] * (1.f/KNN));
  }
}

// ---------------- attention (round-5 proven version): split-K=2, XCD-grouped decode,
// dual S-MFMA chains, pack2 RNE softmax, V LDS-staged dbuf, f16 O_s epilogue. ----------------
#define KT_P 196
#define VT_P 36
#define TW_P 195
__global__ __launch_bounds__(256, 2) void attn_kernel(const ushort_t* __restrict__ q,
    const ushort_t* __restrict__ k, const ushort_t* __restrict__ vT,
    ushort_t* __restrict__ opart, float* __restrict__ lpart) {
  __shared__ ushort_t kt[2][32*KT_P];
  __shared__ ushort_t vt[2][192*VT_P];
  __shared__ float alds[4][32];
  // XCD-aware decode: blocks round-robin XCDs by blockIdx%8. 48 (bh,split) groups, 6/XCD;
  // the 16 qt sharers of one K/V panel land on one XCD's L2.
  int blk = blockIdx.x;
  int xcd = blk & 7, j = blk >> 3;          // j in 0..95
  int g = xcd*6 + (j >> 4);                 // 48 groups
  int qt = j & 15;
  int bh = g % 24;
  int split = g / 24;                       // 0..1
  int b = bh / HH, h = bh % HH;
  int t = threadIdx.x;
  int w = t >> 6, lane = t & 63, ql = lane & 31, hl = lane >> 5;
  int qrow0 = qt*128 + w*32;
  const ushort_t* qpb = q + (size_t)(b*NFIX + qrow0 + ql)*1152 + h*64;
  bf16x8 qf[12];
#pragma unroll
  for (int cs = 0; cs < 12; ++cs) {
    int red0 = cs*16 + hl*8;
    int dq = red0 >> 6, ml = red0 & 63;
    qf[cs] = *(const bf16x8*)(qpb + dq*384 + ml);
  }
  const ushort_t* ksrc[3]; int kdsto[3];
  const ushort_t* vsrc[3]; int vdsto[3];
#pragma unroll
  for (int j2 = 0; j2 < 3; ++j2) {
    int idx = t + j2*256;
    int kp = idx / 24, c16 = idx % 24;
    int red0 = c16*8;
    int dk = red0 >> 6, ml = red0 & 63;
    ksrc[j2] = k + (size_t)(b*NFIX + kp)*1152 + dk*384 + h*64 + ml;
    kdsto[j2] = kp*KT_P + c16*8;
    int ch = idx >> 2, c4 = idx & 3;
    vsrc[j2] = vT + ((size_t)bh*192 + ch)*2048 + c4*8;
    vdsto[j2] = ch*VT_P + c4*8;
  }
  f32x16 acc[6];
#pragma unroll
  for (int nt = 0; nt < 6; ++nt)
#pragma unroll
    for (int r = 0; r < 16; ++r) acc[nt][r] = 0.f;
  float lsum = 0.f;
  int koff0 = split * 1024;                 // 1024 keys per split, 32 K-tiles
  bf16x8 kpre[3], vpre[3];
#pragma unroll
  for (int j2 = 0; j2 < 3; ++j2) {
    kpre[j2] = *(const bf16x8*)(ksrc[j2] + (size_t)koff0*1152);
    vpre[j2] = *(const bf16x8*)(vsrc[j2] + koff0);
  }
#pragma unroll
  for (int j2 = 0; j2 < 3; ++j2) {
    ushort_t* kd = &kt[0][kdsto[j2]];
    *(bf16x4*)kd = __builtin_shufflevector(kpre[j2], kpre[j2], 0, 1, 2, 3);
    *(bf16x4*)(kd+4) = __builtin_shufflevector(kpre[j2], kpre[j2], 4, 5, 6, 7);
    ushort_t* vd = &vt[0][vdsto[j2]];
    *(bf16x4*)vd = __builtin_shufflevector(vpre[j2], vpre[j2], 0, 1, 2, 3);
    *(bf16x4*)(vd+4) = __builtin_shufflevector(vpre[j2], vpre[j2], 4, 5, 6, 7);
  }
  __syncthreads();
  for (int kb = 0; kb < 32; ++kb) {
    int cur = kb & 1;
    if (kb < 31) {
      int koff = koff0 + (kb+1)*32;
#pragma unroll
      for (int j2 = 0; j2 < 3; ++j2) {
        kpre[j2] = *(const bf16x8*)(ksrc[j2] + (size_t)koff*1152);
        vpre[j2] = *(const bf16x8*)(vsrc[j2] + koff);
      }
    }
    // dual independent S accumulation chains (6-deep each instead of 12)
    f32x16 sca, scb;
#pragma unroll
    for (int r = 0; r < 16; ++r) { sca[r] = 0.f; scb[r] = 0.f; }
    const ushort_t* ktc = kt[cur];
#pragma unroll
    for (int cs = 0; cs < 12; ++cs) {
      const ushort_t* kr = &ktc[ql*KT_P + cs*16 + hl*8];
      bf16x4 alo = *(const bf16x4*)kr;
      bf16x4 ahi = *(const bf16x4*)(kr + 4);
      bf16x8 af = __builtin_shufflevector(alo, ahi, 0, 1, 2, 3, 4, 5, 6, 7);
      if (cs & 1) scb = __builtin_amdgcn_mfma_f32_32x32x16_bf16(af, qf[cs], scb, 0, 0, 0);
      else        sca = __builtin_amdgcn_mfma_f32_32x32x16_bf16(af, qf[cs], sca, 0, 0, 0);
    }
    uint_t u[8], pex[8];
#pragma unroll
    for (int g2 = 0; g2 < 4; ++g2) {
      float p0 = __builtin_amdgcn_exp2f(sca[g2*4 + 0] + scb[g2*4 + 0]);
      float p1 = __builtin_amdgcn_exp2f(sca[g2*4 + 1] + scb[g2*4 + 1]);
      float p2 = __builtin_amdgcn_exp2f(sca[g2*4 + 2] + scb[g2*4 + 2]);
      float p3 = __builtin_amdgcn_exp2f(sca[g2*4 + 3] + scb[g2*4 + 3]);
      lsum += (p0 + p1) + (p2 + p3);
      u[2*g2]   = pack2(p0, p1);
      u[2*g2+1] = pack2(p2, p3);
    }
#pragma unroll
    for (int j2 = 0; j2 < 8; ++j2) pex[j2] = (uint_t)__shfl_xor((int)u[j2], 32);
    const ushort_t* vtc = vt[cur];
#pragma unroll
    for (int s = 0; s < 2; ++s) {
      uint4 au;
      au.x = hl ? pex[4*s+2] : u[4*s+0];
      au.y = hl ? pex[4*s+3] : u[4*s+1];
      au.z = hl ? u[4*s+2]   : pex[4*s+0];
      au.w = hl ? u[4*s+3]   : pex[4*s+1];
      union { uint4 ui; bf16x8 bv; } cvt; cvt.ui = au;
      bf16x8 pa = cvt.bv;
#pragma unroll
      for (int nt = 0; nt < 6; ++nt) {
        const ushort_t* vr = &vtc[(nt*32 + ql)*VT_P + s*16 + hl*8];
        bf16x4 vlo = *(const bf16x4*)vr;
        bf16x4 vhi = *(const bf16x4*)(vr + 4);
        bf16x8 vf = __builtin_shufflevector(vlo, vhi, 0, 1, 2, 3, 4, 5, 6, 7);
        acc[nt] = __builtin_amdgcn_mfma_f32_32x32x16_bf16(pa, vf, acc[nt], 0, 0, 0);
      }
    }
    if (kb < 31) {
      int nxt = cur ^ 1;
#pragma unroll
      for (int j2 = 0; j2 < 3; ++j2) {
        ushort_t* kd = &kt[nxt][kdsto[j2]];
        *(bf16x4*)kd = __builtin_shufflevector(kpre[j2], kpre[j2], 0, 1, 2, 3);
        *(bf16x4*)(kd+4) = __builtin_shufflevector(kpre[j2], kpre[j2], 4, 5, 6, 7);
        ushort_t* vd = &vt[nxt][vdsto[j2]];
        *(bf16x4*)vd = __builtin_shufflevector(vpre[j2], vpre[j2], 0, 1, 2, 3);
        *(bf16x4*)(vd+4) = __builtin_shufflevector(vpre[j2], vpre[j2], 4, 5, 6, 7);
      }
    }
    __syncthreads();
  }
  lsum += __shfl_xor(lsum, 32);
  if (lane < 32) {
    alds[w][ql] = 1.0f / lsum;
    lpart[(size_t)split*24*NFIX + (size_t)bh*NFIX + qrow0 + ql] = lsum;
  }
  asm volatile("s_waitcnt lgkmcnt(0)" ::: "memory");
  float lv[4][4];
#pragma unroll
  for (int g2 = 0; g2 < 4; ++g2) {
    f32x4 tv = *(const f32x4*)&alds[w][8*g2 + 4*hl];
#pragma unroll
    for (int rr = 0; rr < 4; ++rr) lv[g2][rr] = tv[rr];
  }
  // ---- epilogue: O_s stored as f16 bits (split-combine precision) ----
  ushort_t* tw = (w == 0) ? kt[0] : (w == 1) ? kt[1] : (w == 2) ? vt[0] : vt[1];
#pragma unroll
  for (int nt = 0; nt < 6; ++nt) {
    int ch = nt*32 + ql;
#pragma unroll
    for (int r = 0; r < 16; ++r) {
      int qrow = (r&3) + 8*(r>>2) + 4*hl;
      tw[qrow*TW_P + ch] = f2h_bits(acc[nt][r] * lv[r>>2][r&3]);
    }
  }
  asm volatile("s_waitcnt lgkmcnt(0)" ::: "memory");
  const size_t SS = (size_t)8192*1152;
  ushort_t* opb = opart + (size_t)split*SS;
  size_t nbase = (size_t)(b*NFIX + qrow0) * 3;
#pragma unroll
  for (int i = 0; i < 12; ++i) {
    int chunk = i*64 + lane;
    int nl = chunk >> 3, jc = chunk & 7;
    int qq = nl / 3, dd = nl - 3*qq;
    ushort_t hv[8];
#pragma unroll
    for (int e = 0; e < 8; ++e)
      hv[e] = tw[qq*TW_P + (jc*8 + e)*3 + dd];
    uint4 sv;
    sv.x = (uint_t)hv[0] | ((uint_t)hv[1] << 16);
    sv.y = (uint_t)hv[2] | ((uint_t)hv[3] << 16);
    sv.z = (uint_t)hv[4] | ((uint_t)hv[5] << 16);
    sv.w = (uint_t)hv[6] | ((uint_t)hv[7] << 16);
    *(uint4*)&opb[(nbase + nl)*384 + h*64 + jc*8] = sv;
  }
}

// ---------------- x1mid fp16 MFMA + fused LN2, widened to 768 threads (12 waves) ----------------
// grid 256 = 1 block/CU; 12 waves/CU (was 6) for latency hiding. Each wave owns one
// (nsub, m-tile) pair (3 x 4 = 12), acc = single f32x16. Bt staging refined to
// 8 f16/thread (96 rows x 8 col-chunks = 768). Math/summation order identical.
#define AP 68
#define XLP 132
__global__ __launch_bounds__(768) void x1mid_mfma(
    const float* __restrict__ xdi, const ushort_t* __restrict__ opart,
    const float* __restrict__ lpart, const _Float16* __restrict__ kmf16,
    const _Float16* __restrict__ Af16, float* __restrict__ xmid,
    _Float16* __restrict__ nxh, const float* __restrict__ g2,
    const float* __restrict__ b2) {
  __shared__ __align__(16) char smem[50944];
  _Float16* As = (_Float16*)smem;                 // 128 x AP = 17408 B
  _Float16* Bt = (_Float16*)(smem + 17408);       //  96 x AP = 13056 B
  float* wlsL  = (float*)(smem + 30464);          //  32 x 6 x 2 = 1536 B
  float* X     = (float*)smem;                    // epilogue overlay: 96 x XLP f32 = 50688 B
  float* stats = (float*)(smem + 50688);          // 32 x 2 f32 = 256 B
  int blk = blockIdx.x;
  int n0 = blk * 96;
  int pt0 = blk * 32;
  int t = threadIdx.x;
  int w = t >> 6, lane = t & 63, ql = lane & 31, hl = lane >> 5;
  int nsub = w >> 2, mt2 = w & 3;                 // 12 waves: 3 n-subtiles x 4 m-tiles
  if (t < 192) {
    int ptl = t / 6, h = t % 6;
    int ptg = pt0 + ptl;
    int b = ptg >> 11, n = ptg & 2047;
    size_t lidx = (size_t)(b*HH + h)*NFIX + n;
    float l[NSPLIT]; float tot = 0.f;
#pragma unroll
    for (int s = 0; s < NSPLIT; ++s) {
      l[s] = lpart[(size_t)s*24*NFIX + lidx];
      tot += l[s];
    }
    float rd = 1.f / tot;
    float* wp = &wlsL[(ptl*6 + h)*NSPLIT];
#pragma unroll
    for (int s = 0; s < NSPLIT; ++s) wp[s] = l[s]*rd;
  }
  f32x16 acc;
#pragma unroll
  for (int r = 0; r < 16; ++r) acc[r] = 0.f;
  const size_t SS = (size_t)8192*1152;
  __syncthreads();
  for (int p = 0; p < 8; ++p) {
    for (int u = t; u < 1024; u += 768) {
      int m = u >> 3, kc = u & 7;
      f16x4 a0 = *(const f16x4*)&Af16[(size_t)m*512 + p*64 + kc*8];
      f16x4 a1 = *(const f16x4*)&Af16[(size_t)m*512 + p*64 + kc*8 + 4];
      _Float16* dst = &As[m*AP + kc*8];
      *(f16x4*)dst = a0;
      *(f16x4*)(dst+4) = a1;
    }
    {
      // Bt staging: 768 threads = 96 rows x 8 col-chunks of 8 f16
      int n_l = t >> 3, jc = t & 7;
      int n_g = n0 + n_l;
      _Float16* dst = &Bt[n_l*AP + jc*8];
      if (p < 6) {
        int pt_l = n_l / 3;
        const float* wp = &wlsL[(pt_l*6 + p)*NSPLIT];
        float facc[8];
#pragma unroll
        for (int e = 0; e < 8; ++e) facc[e] = 0.f;
#pragma unroll
        for (int s = 0; s < NSPLIT; ++s) {
          const ushort_t* src = opart + s*SS + (size_t)n_g*384 + p*64 + jc*8;
          uint4 ra = *(const uint4*)src;
          const _Float16* ua = (const _Float16*)&ra;
          float wsc = wp[s];
#pragma unroll
          for (int e = 0; e < 8; ++e)
            facc[e] += wsc * (float)ua[e];
        }
        _Float16 hv[8];
#pragma unroll
        for (int e = 0; e < 8; ++e) hv[e] = (_Float16)facc[e];
        *(f16x4*)dst = *(f16x4*)&hv[0];
        *(f16x4*)(dst+4) = *(f16x4*)&hv[4];
      } else {
        const _Float16* src = kmf16 + (size_t)n_g*128 + (p-6)*64 + jc*8;
        f16x4 v0 = *(const f16x4*)src;
        f16x4 v1 = *(const f16x4*)(src + 4);
        *(f16x4*)dst = v0; *(f16x4*)(dst+4) = v1;
      }
    }
    __syncthreads();
#pragma unroll
    for (int cs = 0; cs < 4; ++cs) {
      int kloc = cs*16 + hl*8;
      f16x4 b0 = *(const f16x4*)&Bt[(nsub*32 + ql)*AP + kloc];
      f16x4 b1 = *(const f16x4*)&Bt[(nsub*32 + ql)*AP + kloc + 4];
      f16x8 bf = __builtin_shufflevector(b0, b1, 0, 1, 2, 3, 4, 5, 6, 7);
      int mrow = mt2*32 + ql;
      f16x4 a0 = *(const f16x4*)&As[mrow*AP + kloc];
      f16x4 a1 = *(const f16x4*)&As[mrow*AP + kloc + 4];
      f16x8 af = __builtin_shufflevector(a0, a1, 0, 1, 2, 3, 4, 5, 6, 7);
      acc = __builtin_amdgcn_mfma_f32_32x32x16_f16(af, bf, acc, 0, 0, 0);
    }
    __syncthreads();
  }
  // ---- write acc directly into X (C frag: n = nsub*32+ql, c = mt2*32 + (r&3)+8*(r>>2)+4*hl) ----
  {
    int cbase = mt2*32 + 4*hl;
    float* xrow = &X[(nsub*32 + ql)*XLP];
#pragma unroll
    for (int r = 0; r < 16; ++r) {
      int col = cbase + (r&3) + 8*(r>>2);
      xrow[col] = acc[r];
    }
  }
  __syncthreads();
  // ---- Phase A: add residual (post-residual stays in X), emit xmid global ----
#pragma unroll
  for (int i = 0; i < 2; ++i) {
    int u = i*768 + t;                  // 96 rows x 16 chunks of 8 = 1536
    int row = u >> 4, c0 = (u & 15) * 8;
    float* xp = &X[row*XLP + c0];
    const float* xd = xdi + (size_t)(n0 + row)*128 + c0;
    float4 a0 = *(float4*)xp, a1 = *(float4*)(xp + 4);
    float4 d0 = *(const float4*)xd, d1 = *(const float4*)(xd + 4);
    a0.x += d0.x; a0.y += d0.y; a0.z += d0.z; a0.w += d0.w;
    a1.x += d1.x; a1.y += d1.y; a1.z += d1.z; a1.w += d1.w;
    *(float4*)xp = a0; *(float4*)(xp + 4) = a1;
    float* dst = xmid + (size_t)(n0 + row)*128 + c0;
    *(float4*)dst = a0; *(float4*)(dst + 4) = a1;
  }
  __syncthreads();
  // ---- Phase B: per-point LN stats (12 waves cover 32 points) ----
  for (int pi = w; pi < 32; pi += 12) {
    int c = lane;
    float a0 = X[(pi*3+0)*XLP + c], a1 = X[(pi*3+1)*XLP + c], a2 = X[(pi*3+2)*XLP + c];
    float e0 = X[(pi*3+0)*XLP + c + 64], e1 = X[(pi*3+1)*XLP + c + 64], e2 = X[(pi*3+2)*XLP + c + 64];
    float nva = sqrtf(a0*a0 + a1*a1 + a2*a2 + EPSF);
    float nvb = sqrtf(e0*e0 + e1*e1 + e2*e2 + EPSF);
    float s1 = nva + nvb;
    float s2 = nva*nva + nvb*nvb;
#pragma unroll
    for (int off = 32; off >= 1; off >>= 1) {
      s1 += __shfl_down(s1, off);
      s2 += __shfl_down(s2, off);
    }
    if (lane == 0) {
      float mu = s1 * (1.f/128.f);
      float var = s2 * (1.f/128.f) - mu*mu;
      stats[pi*2]   = mu;
      stats[pi*2+1] = rsqrtf(var + LNEPSF);
    }
  }
  __syncthreads();
  // ---- Phase C: emit nxh f16 (LN2-normalized) ----
#pragma unroll
  for (int i = 0; i < 2; ++i) {
    int u = i*768 + t;
    int row = u >> 4, c0 = (u & 15) * 8;
    int pt_l = row / 3;
    float mu = stats[pt_l*2], rsig = stats[pt_l*2+1];
    const float* r0 = &X[(pt_l*3 + 0)*XLP + c0];
    const float* r1 = &X[(pt_l*3 + 1)*XLP + c0];
    const float* r2 = &X[(pt_l*3 + 2)*XLP + c0];
    const float* rd = &X[row*XLP + c0];
    float xv[8];
#pragma unroll
    for (int e = 0; e < 8; ++e) {
      float x0 = r0[e], x1 = r1[e], x2 = r2[e];
      float nv = sqrtf(x0*x0 + x1*x1 + x2*x2 + EPSF);
      float nnew = g2[c0 + e] * ((nv - mu) * rsig) + b2[c0 + e];
      xv[e] = rd[e] * (nnew / nv);
    }
    uint4 sv;
    sv.x = packh2(xv[0], xv[1]); sv.y = packh2(xv[2], xv[3]);
    sv.z = packh2(xv[4], xv[5]); sv.w = packh2(xv[6], xv[7]);
    *(uint4*)&nxh[(size_t)(n0 + row)*128 + c0] = sv;
  }
}

// ---------------- conv3: f16 MFMA, 3 d-plane GEMMs/wave ----------------
#define X3P 132
#define TR3P 36
__global__ __launch_bounds__(256) void conv3_mfma(const _Float16* __restrict__ nxh,
    const _Float16* __restrict__ W3h, const _Float16* __restrict__ U3h,
    _Float16* __restrict__ h3) {
  __shared__ __align__(16) _Float16 Xs[3*32*X3P];     // 25344 B
  __shared__ __align__(16) _Float16 tr3[4][96*TR3P];  // 27648 B
  int blk = blockIdx.x;
  int pt0 = (blk >> 1) * 32;
  int oh = blk & 1;
  int t = threadIdx.x;
  int w = t >> 6, lane = t & 63, ql = lane & 31, hl = lane >> 5;
#pragma unroll
  for (int i = 0; i < 6; ++i) {
    int u = i*256 + t;
    int r = u >> 4, c8 = u & 15;
    f16x8 gv = *(const f16x8*)&nxh[(size_t)(pt0*3 + r)*128 + c8*8];
    int d = r % 3, p = r / 3;
    _Float16* dst = &Xs[(d*32 + p)*X3P + c8*8];
    *(f16x4*)dst = __builtin_shufflevector(gv, gv, 0, 1, 2, 3);
    *(f16x4*)(dst+4) = __builtin_shufflevector(gv, gv, 4, 5, 6, 7);
  }
  __syncthreads();
  int ot = oh*128 + w*32;
  const _Float16* Wp = W3h + (size_t)(ot + ql)*128 + hl*8;
  const _Float16* Up = U3h + (size_t)(ot + ql)*128 + hl*8;
  f32x16 accP[3], accD[3];
#pragma unroll
  for (int d = 0; d < 3; ++d)
#pragma unroll
    for (int r = 0; r < 16; ++r) { accP[d][r] = 0.f; accD[d][r] = 0.f; }
#pragma unroll
  for (int cs = 0; cs < 8; ++cs) {
    f16x8 wf = *(const f16x8*)(Wp + cs*16);
    f16x8 uf = *(const f16x8*)(Up + cs*16);
#pragma unroll
    for (int d = 0; d < 3; ++d) {
      const _Float16* xr = &Xs[(d*32 + ql)*X3P + cs*16 + hl*8];
      f16x4 lo = *(const f16x4*)xr;
      f16x4 hi = *(const f16x4*)(xr + 4);
      f16x8 xf = __builtin_shufflevector(lo, hi, 0, 1, 2, 3, 4, 5, 6, 7);
      accP[d] = __builtin_amdgcn_mfma_f32_32x32x16_f16(wf, xf, accP[d], 0, 0, 0);
      accD[d] = __builtin_amdgcn_mfma_f32_32x32x16_f16(uf, xf, accD[d], 0, 0, 0);
    }
  }
  _Float16* trw = tr3[w];
#pragma unroll
  for (int r = 0; r < 16; ++r) {
    int olr = (r&3) + 8*(r>>2) + 4*hl;
    float p3[3], d3[3], res[3];
#pragma unroll
    for (int d = 0; d < 3; ++d) { p3[d] = accP[d][r]; d3[d] = accD[d][r]; }
    vnleaky3(p3, d3, res);
#pragma unroll
    for (int d = 0; d < 3; ++d) trw[(ql*3 + d)*TR3P + olr] = (_Float16)res[d];
  }
  asm volatile("s_waitcnt lgkmcnt(0)" ::: "memory");
#pragma unroll
  for (int i = 0; i < 6; ++i) {
    int u = i*64 + lane;
    int row = u >> 2, c8 = u & 3;
    const _Float16* src = &trw[row*TR3P + c8*8];
    f16x4 lo = *(const f16x4*)src;
    f16x4 hi = *(const f16x4*)(src + 4);
    f16x8 ov = __builtin_shufflevector(lo, hi, 0, 1, 2, 3, 4, 5, 6, 7);
    *(f16x8*)&h3[(size_t)(pt0*3 + row)*256 + ot + c8*8] = ov;
  }
}

// ---------------- conv4: f16 MFMA (16x16x32), + xmid residual ----------------
#define X4P 260
#define TF4P 388
__global__ __launch_bounds__(256) void conv4_mfma(const _Float16* __restrict__ h3,
    const _Float16* __restrict__ W4h, const _Float16* __restrict__ U4h,
    const float* __restrict__ xmid, float* __restrict__ out) {
  __shared__ __align__(16) _Float16 Xs[3*16*X4P];   // 24960 B
  __shared__ __align__(16) float trF[16*TF4P];      // 24832 B
  int pt0 = blockIdx.x * 16;
  int t = threadIdx.x;
  int w = t >> 6, lane = t & 63;
  int nl = lane & 15, kq = lane >> 4;
#pragma unroll
  for (int i = 0; i < 6; ++i) {
    int u = i*256 + t;
    int r = u >> 5, c8 = u & 31;
    f16x8 gv = *(const f16x8*)&h3[(size_t)(pt0*3 + r)*256 + c8*8];
    int d = r % 3, p = r / 3;
    _Float16* dst = &Xs[(d*16 + p)*X4P + c8*8];
    *(f16x4*)dst = __builtin_shufflevector(gv, gv, 0, 1, 2, 3);
    *(f16x4*)(dst+4) = __builtin_shufflevector(gv, gv, 4, 5, 6, 7);
  }
  __syncthreads();
  int ot = w*32;
  f32x4 accP[2][3], accD[2][3];
#pragma unroll
  for (int mt = 0; mt < 2; ++mt)
#pragma unroll
    for (int d = 0; d < 3; ++d)
#pragma unroll
      for (int r = 0; r < 4; ++r) { accP[mt][d][r] = 0.f; accD[mt][d][r] = 0.f; }
  const _Float16* Wb = W4h + (size_t)ot*256;
  const _Float16* Ub = U4h + (size_t)ot*256;
#pragma unroll
  for (int cs = 0; cs < 8; ++cs) {
    int kof = cs*32 + kq*8;
    f16x8 xf[3];
#pragma unroll
    for (int d = 0; d < 3; ++d) {
      const _Float16* xr = &Xs[(d*16 + nl)*X4P + kof];
      f16x4 lo = *(const f16x4*)xr;
      f16x4 hi = *(const f16x4*)(xr + 4);
      xf[d] = __builtin_shufflevector(lo, hi, 0, 1, 2, 3, 4, 5, 6, 7);
    }
#pragma unroll
    for (int mt = 0; mt < 2; ++mt) {
      f16x8 wf = *(const f16x8*)(Wb + (size_t)(mt*16 + nl)*256 + kof);
      f16x8 uf = *(const f16x8*)(Ub + (size_t)(mt*16 + nl)*256 + kof);
#pragma unroll
      for (int d = 0; d < 3; ++d) {
        accP[mt][d] = __builtin_amdgcn_mfma_f32_16x16x32_f16(wf, xf[d], accP[mt][d], 0, 0, 0);
        accD[mt][d] = __builtin_amdgcn_mfma_f32_16x16x32_f16(uf, xf[d], accD[mt][d], 0, 0, 0);
      }
    }
  }
#pragma unroll
  for (int mt = 0; mt < 2; ++mt)
#pragma unroll
    for (int r = 0; r < 4; ++r) {
      int o = ot + mt*16 + kq*4 + r;
      float p3[3], d3[3], res[3];
#pragma unroll
      for (int d = 0; d < 3; ++d) { p3[d] = accP[mt][d][r]; d3[d] = accD[mt][d][r]; }
      vnleaky3(p3, d3, res);
#pragma unroll
      for (int d = 0; d < 3; ++d) trF[nl*TF4P + o*3 + d] = res[d];
    }
  __syncthreads();
#pragma unroll
  for (int i = 0; i < 6; ++i) {
    int u = i*256 + t;
    int row = u / 96, c4 = u % 96;
    float4 vv = *(float4*)&trF[row*TF4P + c4*4];
    int bn = pt0 + row;
    float rs[4];
    const float* fv = (const float*)&vv;
#pragma unroll
    for (int e = 0; e < 4; ++e) {
      int col = c4*4 + e;
      int o = col / 3, d = col - 3*o;
      rs[e] = fv[e] + xmid[(size_t)(3*bn + d)*128 + o];
    }
    float4 ov; ov.x = rs[0]; ov.y = rs[1]; ov.z = rs[2]; ov.w = rs[3];
    *(float4*)&out[(size_t)bn*384 + c4*4] = ov;
  }
}

extern "C" void kernel_launch(void* const* d_in, const int* in_sizes, int n_in,
                              void* d_out, int out_size, void* d_ws, size_t ws_size,
                              hipStream_t stream) {
  const float* x   = (const float*)d_in[0];
  const int* knn   = (const int*)d_in[1];
  const float* g1  = (const float*)d_in[2];
  const float* b1  = (const float*)d_in[3];
  const float* g2  = (const float*)d_in[4];
  const float* b2  = (const float*)d_in[5];
  const float* Wq  = (const float*)d_in[6];
  const float* Wk  = (const float*)d_in[7];
  const float* Wv  = (const float*)d_in[8];
  const float* Wo  = (const float*)d_in[9];
  const float* W1  = (const float*)d_in[10];
  const float* U1  = (const float*)d_in[11];
  const float* W2  = (const float*)d_in[12];
  const float* W3  = (const float*)d_in[13];
  const float* U3  = (const float*)d_in[14];
  const float* W4  = (const float*)d_in[15];
  const float* U4  = (const float*)d_in[16];
  float* out = (float*)d_out;
  (void)n_in; (void)out_size; (void)ws_size;

  const size_t BN = (size_t)in_sizes[0] / 384;   // 8192

  float* ws    = (float*)d_ws;
  float* xdi   = ws;                          // BN*384 f32 (raw x, de-interleaved [n][c])
  float* xmid  = xdi + BN*384;                // BN*384 f32 (x_mid, de-interleaved)
  _Float16* kmf16 = (_Float16*)(xmid + BN*384);  // BN*384 fp16 [n][128]
  ushort_t* xbp = (ushort_t*)(kmf16 + BN*384);   // BN*384 bf16 (LN1 normalized, de-interleaved)
  ushort_t* qb = xbp + BN*384;                // BN*1152 bf16
  ushort_t* kb = qb + BN*1152;
  ushort_t* vb = kb + BN*1152;
  ushort_t* vT = vb + BN*1152;
  ushort_t* Wall = vT + BN*1152;              // 212992 bf16
  _Float16* Af16 = (_Float16*)(Wall + 212992);   // 65536 fp16
  _Float16* W3h = Af16 + 65536;               // 32768 fp16
  _Float16* U3h = W3h + 32768;
  _Float16* W4h = U3h + 32768;
  _Float16* U4h = W4h + 32768;
  ushort_t* opart = (ushort_t*)(U4h + 32768); // region 4*BN*1152 (2 splits used)
  float* lpart = (float*)(opart + 4*BN*1152); // 2*24*2048 f32
  // YZh/NBh (BN*768 f16 each = 12.6 MB) alias the opart region: conv1_post runs before attn.
  _Float16* YZh = (_Float16*)opart;
  _Float16* NBh = YZh + BN*768;
  _Float16* nxh = (_Float16*)qb;   // q dead after x1mid; LN2 out f16 [ng][128]
  _Float16* h3  = (_Float16*)kb;   // k dead after attention; conv3 out f16 [ng][256]

  prep_ln1<<<1600 + 4096, 256, 0, stream>>>(Wq, Wk, Wv, Wo, W1, U1, W2, W3, U3, W4, U4,
                                            Wall, Af16, W3h, U3h, W4h, U4h,
                                            x, xbp, xdi, g1, b1);
  qkv_conv1_mfma<<<192*4, 256, 0, stream>>>(xbp, Wall, qb, kb, vb, YZh, NBh);
  post_vtrans<<<768 + 1024, 256, 0, stream>>>(vb, vT, YZh, NBh, knn, kmf16);
  attn_kernel<<<16*24*NSPLIT, 256, 0, stream>>>(qb, kb, vT, opart, lpart);
  x1mid_mfma<<<256, 768, 0, stream>>>(xdi, opart, lpart, kmf16, Af16, xmid, nxh, g2, b2);
  conv3_mfma<<<512, 256, 0, stream>>>(nxh, W3h, U3h, h3);
  conv4_mfma<<<512, 256, 0, stream>>>(h3, W4h, U4h, xmid, out);
}

// Round 11
// 312.342 us; speedup vs baseline: 1.2669x; 1.0118x over previous
//
#include <hip/hip_runtime.h>
#include <math.h>

// Problem constants (fixed by setup_inputs): B=4, N=2048, C=128, H=6, K=8
#define NFIX 2048
#define HH 6
#define KNN 8
#define NSLOPE 0.2f
#define EPSF 1e-6f
#define LNEPSF 1e-5f
// 0.125 (softmax scale) * log2(e), folded into Wq rows so S-MFMA output is exp2-ready
#define QSCALE 0.18033688011112042f
#define NSPLIT 2

typedef unsigned short ushort_t;
typedef unsigned int uint_t;
typedef __attribute__((ext_vector_type(8))) short bf16x8;
typedef __attribute__((ext_vector_type(4))) short bf16x4;
typedef __attribute__((ext_vector_type(8))) _Float16 f16x8;
typedef __attribute__((ext_vector_type(4))) _Float16 f16x4;
typedef __attribute__((ext_vector_type(16))) float f32x16;
typedef __attribute__((ext_vector_type(4))) float f32x4;

__device__ __forceinline__ ushort_t f2bf(float f) {
  union { float f; unsigned u; } v; v.f = f;
  unsigned r = v.u + 0x7fff + ((v.u >> 16) & 1);   // RNE
  return (ushort_t)(r >> 16);
}
__device__ __forceinline__ float bf2f(ushort_t u) {
  union { uint_t u; float f; } v; v.u = ((uint_t)u) << 16; return v.f;
}
__device__ __forceinline__ uint_t pack2(float a, float b) {
  return (uint_t)f2bf(a) | ((uint_t)f2bf(b) << 16);
}
// f32 -> f16 bit pattern (register-only)
__device__ __forceinline__ ushort_t f2h_bits(float a) {
  union { _Float16 h; ushort_t s; } cv; cv.h = (_Float16)a; return cv.s;
}
// pack two fp32 -> two f16 in one dword (register-only; no local-array aliasing)
__device__ __forceinline__ uint_t packh2(float a, float b) {
  union { _Float16 h; ushort_t s; } ha, hb;
  ha.h = (_Float16)a; hb.h = (_Float16)b;
  return (uint_t)ha.s | ((uint_t)hb.s << 16);
}

__device__ __forceinline__ void vnleaky3(const float* p, const float* dv, float* out) {
  float dot = p[0]*dv[0] + p[1]*dv[1] + p[2]*dv[2];
  float dsq = dv[0]*dv[0] + dv[1]*dv[1] + dv[2]*dv[2] + EPSF;
  float f = dot / dsq;
#pragma unroll
  for (int d = 0; d < 3; ++d) {
    float neg = p[d] - f * dv[d];
    out[d] = NSLOPE * p[d] + (1.f - NSLOPE) * ((dot >= 0.f) ? p[d] : neg);
  }
}

// ---------------- fused weight prep + LN1 (independent work; overlapped in one launch) ----------------
__global__ __launch_bounds__(256) void prep_ln1(
    const float* __restrict__ Wq, const float* __restrict__ Wk,
    const float* __restrict__ Wv, const float* __restrict__ Wo,
    const float* __restrict__ W1, const float* __restrict__ U1,
    const float* __restrict__ W2, const float* __restrict__ W3,
    const float* __restrict__ U3, const float* __restrict__ W4,
    const float* __restrict__ U4,
    ushort_t* __restrict__ Wall, _Float16* __restrict__ Af16,
    _Float16* __restrict__ W3h, _Float16* __restrict__ U3h,
    _Float16* __restrict__ W4h, _Float16* __restrict__ U4h,
    const float* __restrict__ xin, ushort_t* __restrict__ xbp,
    float* __restrict__ xdi, const float* __restrict__ g1,
    const float* __restrict__ b1) {
  __shared__ float red[8];
  int bi = blockIdx.x;
  if (bi >= 1600) {
    // ---- LN1: 2 points per block ----
    int t = threadIdx.x;
    int half = t >> 7, c = t & 127;
    int bn = (bi - 1600) * 2 + half;
    const float* row = xin + (size_t)bn * 384;
    float x0 = row[c*3+0], x1 = row[c*3+1], x2 = row[c*3+2];
    float nv = sqrtf(x0*x0 + x1*x1 + x2*x2 + EPSF);
    float s1 = nv, s2 = nv*nv;
#pragma unroll
    for (int off = 32; off >= 1; off >>= 1) {
      s1 += __shfl_down(s1, off);
      s2 += __shfl_down(s2, off);
    }
    int lane = t & 63, w = t >> 6;
    if (lane == 0) { red[w*2] = s1; red[w*2+1] = s2; }
    __syncthreads();
    int rb4 = (w >> 1) * 4;
    float tot1 = red[rb4] + red[rb4+2], tot2 = red[rb4+1] + red[rb4+3];
    float mu  = tot1 * (1.f/128.f);
    float var = tot2 * (1.f/128.f) - mu*mu;
    float rsig = rsqrtf(var + LNEPSF);
    float nnew = g1[c] * ((nv - mu) * rsig) + b1[c];
    float sc = nnew / nv;
    size_t rb = (size_t)bn * 384;
    xbp[rb + c]       = f2bf(x0*sc);
    xbp[rb + 128 + c] = f2bf(x1*sc);
    xbp[rb + 256 + c] = f2bf(x2*sc);
    xdi[rb + c]       = x0;
    xdi[rb + 128 + c] = x1;
    xdi[rb + 256 + c] = x2;
    return;
  }
  int idx = bi * 256 + threadIdx.x;
  if (idx < 212992) {
    int m = idx >> 7, c = idx & 127;
    float val;
    if (m < 384)       val = Wq[m*128 + c] * QSCALE;
    else if (m < 768)  val = Wk[(m-384)*128 + c];
    else if (m < 1152) val = Wv[(m-768)*128 + c];
    else {
      int j = m - 1152;
      if (j < 128)      val = W1[j*256 + c];
      else if (j < 256) val = U1[(j-128)*256 + c];
      else if (j < 384) { int o = j-256; val = W1[o*256 + 128 + c] - W1[o*256 + c]; }
      else              { int o = j-384; val = U1[o*256 + 128 + c] - U1[o*256 + c]; }
    }
    Wall[idx] = f2bf(val); return;
  }
  idx -= 212992;
  if (idx < 49152) {
    int c = idx / 384, j = idx % 384;   // coalesced: j fast -> Wo stride-4B, W2 wave-uniform
    float s = 0.f;
    for (int cp = 0; cp < 128; ++cp) s += W2[c*256 + cp] * Wo[cp*384 + j];
    Af16[(size_t)c*512 + j] = (_Float16)s; return;
  }
  idx -= 49152;
  if (idx < 16384) {
    int c2 = idx / 128, c = idx % 128;
    Af16[(size_t)c*512 + 384 + c2] = (_Float16)W2[c*256 + 128 + c2]; return;
  }
  idx -= 16384;
  if (idx < 32768) { W3h[idx] = (_Float16)W3[idx]; return; }
  idx -= 32768;
  if (idx < 32768) { U3h[idx] = (_Float16)U3[idx]; return; }
  idx -= 32768;
  if (idx < 32768) { W4h[idx] = (_Float16)W4[idx]; return; }
  idx -= 32768;
  if (idx < 32768) { U4h[idx] = (_Float16)U4[idx]; return; }
}

// ---------------- fused QKV + conv1 MFMA GEMM ----------------
#define XT_PITCH 132
#define WT_PITCH 132
#define TR_PITCH 36
__global__ __launch_bounds__(256, 2) void qkv_conv1_mfma(
    const ushort_t* __restrict__ xb, const ushort_t* __restrict__ Wall,
    ushort_t* __restrict__ q, ushort_t* __restrict__ k, ushort_t* __restrict__ v,
    _Float16* __restrict__ YZh, _Float16* __restrict__ NBh) {
  __shared__ ushort_t xs[128*XT_PITCH];
  __shared__ ushort_t wt[32*WT_PITCH];
  __shared__ float tr[4][32*TR_PITCH];
  int nb = blockIdx.x % 192;
  int mq = blockIdx.x / 192;
  int n0 = nb * 128;
  int t = threadIdx.x;
  int w = t >> 6, lane = t & 63, ql = lane & 31, hl = lane >> 5;
  for (int idx = t; idx < 2048; idx += 256) {
    int n = idx >> 4, c16 = idx & 15;
    bf16x8 gv = *(const bf16x8*)&xb[(size_t)(n0 + n)*128 + c16*8];
    ushort_t* dst = &xs[n*XT_PITCH + c16*8];
    *(bf16x4*)dst = __builtin_shufflevector(gv, gv, 0, 1, 2, 3);
    *(bf16x4*)(dst+4) = __builtin_shufflevector(gv, gv, 4, 5, 6, 7);
  }
  __syncthreads();
  bf16x8 xf[8];
  {
    const ushort_t* xr = &xs[(w*32 + ql)*XT_PITCH + hl*8];
#pragma unroll
    for (int cs = 0; cs < 8; ++cs) {
      bf16x4 lo = *(const bf16x4*)(xr + cs*16);
      bf16x4 hi = *(const bf16x4*)(xr + cs*16 + 4);
      xf[cs] = __builtin_shufflevector(lo, hi, 0, 1, 2, 3, 4, 5, 6, 7);
    }
  }
  int ng = n0 + w*32 + ql;
  int pt = ng / 3;
  int d  = ng - 3*pt;
  float* trw = tr[w];
  for (int mt = 0; mt < 13; ++mt) {
    int m0 = mq*416 + mt*32;
    __syncthreads();
    for (int idx = t; idx < 512; idx += 256) {
      int mm = idx >> 4, c16 = idx & 15;
      bf16x8 gv = *(const bf16x8*)&Wall[(size_t)(m0 + mm)*128 + c16*8];
      ushort_t* dst = &wt[mm*WT_PITCH + c16*8];
      *(bf16x4*)dst = __builtin_shufflevector(gv, gv, 0, 1, 2, 3);
      *(bf16x4*)(dst+4) = __builtin_shufflevector(gv, gv, 4, 5, 6, 7);
    }
    __syncthreads();
    f32x16 acc;
#pragma unroll
    for (int r = 0; r < 16; ++r) acc[r] = 0.f;
    const ushort_t* wr = &wt[ql*WT_PITCH + hl*8];
#pragma unroll
    for (int cs = 0; cs < 8; ++cs) {
      bf16x4 lo = *(const bf16x4*)(wr + cs*16);
      bf16x4 hi = *(const bf16x4*)(wr + cs*16 + 4);
      bf16x8 af = __builtin_shufflevector(lo, hi, 0, 1, 2, 3, 4, 5, 6, 7);
      acc = __builtin_amdgcn_mfma_f32_32x32x16_bf16(af, xf[cs], acc, 0, 0, 0);
    }
#pragma unroll
    for (int r = 0; r < 16; ++r) {
      int mrow = (r&3) + 8*(r>>2) + 4*hl;
      trw[ql*TR_PITCH + mrow] = acc[r];
    }
    asm volatile("s_waitcnt lgkmcnt(0)" ::: "memory");
    float4 c0 = *(float4*)&trw[ql*TR_PITCH + hl*16 + 0];
    float4 c1 = *(float4*)&trw[ql*TR_PITCH + hl*16 + 4];
    float4 c2 = *(float4*)&trw[ql*TR_PITCH + hl*16 + 8];
    float4 c3 = *(float4*)&trw[ql*TR_PITCH + hl*16 + 12];
    asm volatile("s_waitcnt lgkmcnt(0)" ::: "memory");
    int mg = m0 + hl*16;
    if (m0 < 1152) {
      uint4 s0, s1;
      s0.x = pack2(c0.x, c0.y); s0.y = pack2(c0.z, c0.w);
      s0.z = pack2(c1.x, c1.y); s0.w = pack2(c1.z, c1.w);
      s1.x = pack2(c2.x, c2.y); s1.y = pack2(c2.z, c2.w);
      s1.z = pack2(c3.x, c3.y); s1.w = pack2(c3.z, c3.w);
      ushort_t* dst;
      if (m0 < 384)       dst = q + (size_t)pt*1152 + d*384 + mg;
      else if (m0 < 768)  dst = k + (size_t)pt*1152 + d*384 + (mg - 384);
      else                dst = v + (size_t)pt*1152 + d*384 + (mg - 768);
      *(uint4*)dst = s0;
      *(uint4*)(dst + 8) = s1;
    } else {
      int mat = mg - 1152;
      int sub = mat >> 7, o = mat & 127;
      _Float16* basep = (sub < 2) ? YZh : NBh;
      _Float16* dst = basep + (size_t)pt*768 + d*256 + (sub & 1)*128 + o;
      uint4 s0, s1;
      s0.x = packh2(c0.x, c0.y); s0.y = packh2(c0.z, c0.w);
      s0.z = packh2(c1.x, c1.y); s0.w = packh2(c1.z, c1.w);
      s1.x = packh2(c2.x, c2.y); s1.y = packh2(c2.z, c2.w);
      s1.z = packh2(c3.x, c3.y); s1.w = packh2(c3.z, c3.w);
      *(uint4*)dst = s0;
      *(uint4*)(dst + 8) = s1;
    }
  }
}

// ---------------- fused V-transpose + conv1-post (independent; overlapped in one launch) ----------------
#define VT_LP 196
__global__ __launch_bounds__(256) void post_vtrans(const ushort_t* __restrict__ v,
    ushort_t* __restrict__ vT, const _Float16* __restrict__ YZh,
    const _Float16* __restrict__ NBh, const int* __restrict__ knn_index,
    _Float16* __restrict__ kmf16) {
  __shared__ ushort_t tl[64*VT_LP];   // 25088 B
  __shared__ int sidx[8][KNN];
  int blk = blockIdx.x;
  int t = threadIdx.x;
  if (blk < 768) {
    int bh = blk / 32, ptile = blk % 32;
    int b = bh / HH, h = bh % HH;
    int pt0 = ptile * 64;
#pragma unroll
    for (int i = 0; i < 6; ++i) {
      int u = i*256 + t;
      int p = u / 24, seg = u % 24;
      int d = seg >> 3, c8 = seg & 7;
      bf16x8 gv = *(const bf16x8*)&v[(size_t)(b*NFIX + pt0 + p)*1152 + d*384 + h*64 + c8*8];
      ushort_t* dst = &tl[p*VT_LP + d*64 + c8*8];
      *(bf16x4*)dst = __builtin_shufflevector(gv, gv, 0, 1, 2, 3);
      *(bf16x4*)(dst+4) = __builtin_shufflevector(gv, gv, 4, 5, 6, 7);
    }
    __syncthreads();
#pragma unroll
    for (int i = 0; i < 6; ++i) {
      int u = i*256 + t;
      int ch = u >> 3, pc = u & 7;
      int ol = ch / 3, dd = ch - 3*ol;
      int cloc = dd*64 + ol;
      ushort_t hv[8];
#pragma unroll
      for (int e = 0; e < 8; ++e)
        hv[e] = tl[(pc*8 + e)*VT_LP + cloc];
      uint4 o4;
      o4.x = (uint_t)hv[0] | ((uint_t)hv[1] << 16);
      o4.y = (uint_t)hv[2] | ((uint_t)hv[3] << 16);
      o4.z = (uint_t)hv[4] | ((uint_t)hv[5] << 16);
      o4.w = (uint_t)hv[6] | ((uint_t)hv[7] << 16);
      *(uint4*)&vT[((size_t)bh*192 + ch)*2048 + pt0 + pc*8] = o4;
    }
    return;
  }
  // conv1_post: 8 points per block; threads 0-127 -> pts 0-3, 128-255 -> pts 4-7
  int bnb = (blk - 768) * 8;
  int half = t >> 7, c = t & 127;
  if (t < 64) {
    int pi = t >> 3, kk = t & 7;
    int bn = bnb + pi;
    int b = bn / NFIX, n = bn % NFIX;
    sidx[pi][kk] = knn_index[(b*KNN + kk)*NFIX + n];
  }
  __syncthreads();
#pragma unroll
  for (int pi2 = 0; pi2 < 4; ++pi2) {
    int pi = half*4 + pi2;
    int bn = bnb + pi;
    float yb[3], zb[3];
#pragma unroll
    for (int d = 0; d < 3; ++d) {
      yb[d] = (float)NBh[(size_t)bn*768 + d*256 + c];
      zb[d] = (float)NBh[(size_t)bn*768 + d*256 + 128 + c];
    }
    float om[3] = {0.f, 0.f, 0.f};
#pragma unroll
    for (int kk = 0; kk < KNN; ++kk) {
      const _Float16* r = YZh + (size_t)sidx[pi][kk]*768;
      float p[3], dd[3];
#pragma unroll
      for (int d = 0; d < 3; ++d) {
        p[d]  = (float)r[d*256 + c] + yb[d];
        dd[d] = (float)r[d*256 + 128 + c] + zb[d];
      }
      float res[3];
      vnleaky3(p, dd, res);
      om[0] += res[0]; om[1] += res[1]; om[2] += res[2];
    }
#pragma unroll
    for (int d = 0; d < 3; ++d)
      kmf16[((size_t)bn*3 + d)*128 + c] = (_Float16)(om[d] * (1.f/KNN));
  }
}

// ---------------- attention (round-5 proven version): split-K=2, XCD-grouped decode,
// dual S-MFMA chains, pack2 RNE softmax, V LDS-staged dbuf, f16 O_s epilogue. ----------------
#define KT_P 196
#define VT_P 36
#define TW_P 195
__global__ __launch_bounds__(256, 2) void attn_kernel(const ushort_t* __restrict__ q,
    const ushort_t* __restrict__ k, const ushort_t* __restrict__ vT,
    ushort_t* __restrict__ opart, float* __restrict__ lpart) {
  __shared__ ushort_t kt[2][32*KT_P];
  __shared__ ushort_t vt[2][192*VT_P];
  __shared__ float alds[4][32];
  int blk = blockIdx.x;
  int xcd = blk & 7, j = blk >> 3;          // j in 0..95
  int g = xcd*6 + (j >> 4);                 // 48 groups
  int qt = j & 15;
  int bh = g % 24;
  int split = g / 24;                       // 0..1
  int b = bh / HH, h = bh % HH;
  int t = threadIdx.x;
  int w = t >> 6, lane = t & 63, ql = lane & 31, hl = lane >> 5;
  int qrow0 = qt*128 + w*32;
  const ushort_t* qpb = q + (size_t)(b*NFIX + qrow0 + ql)*1152 + h*64;
  bf16x8 qf[12];
#pragma unroll
  for (int cs = 0; cs < 12; ++cs) {
    int red0 = cs*16 + hl*8;
    int dq = red0 >> 6, ml = red0 & 63;
    qf[cs] = *(const bf16x8*)(qpb + dq*384 + ml);
  }
  const ushort_t* ksrc[3]; int kdsto[3];
  const ushort_t* vsrc[3]; int vdsto[3];
#pragma unroll
  for (int j2 = 0; j2 < 3; ++j2) {
    int idx = t + j2*256;
    int kp = idx / 24, c16 = idx % 24;
    int red0 = c16*8;
    int dk = red0 >> 6, ml = red0 & 63;
    ksrc[j2] = k + (size_t)(b*NFIX + kp)*1152 + dk*384 + h*64 + ml;
    kdsto[j2] = kp*KT_P + c16*8;
    int ch = idx >> 2, c4 = idx & 3;
    vsrc[j2] = vT + ((size_t)bh*192 + ch)*2048 + c4*8;
    vdsto[j2] = ch*VT_P + c4*8;
  }
  f32x16 acc[6];
#pragma unroll
  for (int nt = 0; nt < 6; ++nt)
#pragma unroll
    for (int r = 0; r < 16; ++r) acc[nt][r] = 0.f;
  float lsum = 0.f;
  int koff0 = split * 1024;                 // 1024 keys per split, 32 K-tiles
  bf16x8 kpre[3], vpre[3];
#pragma unroll
  for (int j2 = 0; j2 < 3; ++j2) {
    kpre[j2] = *(const bf16x8*)(ksrc[j2] + (size_t)koff0*1152);
    vpre[j2] = *(const bf16x8*)(vsrc[j2] + koff0);
  }
#pragma unroll
  for (int j2 = 0; j2 < 3; ++j2) {
    ushort_t* kd = &kt[0][kdsto[j2]];
    *(bf16x4*)kd = __builtin_shufflevector(kpre[j2], kpre[j2], 0, 1, 2, 3);
    *(bf16x4*)(kd+4) = __builtin_shufflevector(kpre[j2], kpre[j2], 4, 5, 6, 7);
    ushort_t* vd = &vt[0][vdsto[j2]];
    *(bf16x4*)vd = __builtin_shufflevector(vpre[j2], vpre[j2], 0, 1, 2, 3);
    *(bf16x4*)(vd+4) = __builtin_shufflevector(vpre[j2], vpre[j2], 4, 5, 6, 7);
  }
  __syncthreads();
  for (int kb = 0; kb < 32; ++kb) {
    int cur = kb & 1;
    if (kb < 31) {
      int koff = koff0 + (kb+1)*32;
#pragma unroll
      for (int j2 = 0; j2 < 3; ++j2) {
        kpre[j2] = *(const bf16x8*)(ksrc[j2] + (size_t)koff*1152);
        vpre[j2] = *(const bf16x8*)(vsrc[j2] + koff);
      }
    }
    // dual independent S accumulation chains (6-deep each instead of 12)
    f32x16 sca, scb;
#pragma unroll
    for (int r = 0; r < 16; ++r) { sca[r] = 0.f; scb[r] = 0.f; }
    const ushort_t* ktc = kt[cur];
#pragma unroll
    for (int cs = 0; cs < 12; ++cs) {
      const ushort_t* kr = &ktc[ql*KT_P + cs*16 + hl*8];
      bf16x4 alo = *(const bf16x4*)kr;
      bf16x4 ahi = *(const bf16x4*)(kr + 4);
      bf16x8 af = __builtin_shufflevector(alo, ahi, 0, 1, 2, 3, 4, 5, 6, 7);
      if (cs & 1) scb = __builtin_amdgcn_mfma_f32_32x32x16_bf16(af, qf[cs], scb, 0, 0, 0);
      else        sca = __builtin_amdgcn_mfma_f32_32x32x16_bf16(af, qf[cs], sca, 0, 0, 0);
    }
    uint_t u[8], pex[8];
#pragma unroll
    for (int g2 = 0; g2 < 4; ++g2) {
      float p0 = __builtin_amdgcn_exp2f(sca[g2*4 + 0] + scb[g2*4 + 0]);
      float p1 = __builtin_amdgcn_exp2f(sca[g2*4 + 1] + scb[g2*4 + 1]);
      float p2 = __builtin_amdgcn_exp2f(sca[g2*4 + 2] + scb[g2*4 + 2]);
      float p3 = __builtin_amdgcn_exp2f(sca[g2*4 + 3] + scb[g2*4 + 3]);
      lsum += (p0 + p1) + (p2 + p3);
      u[2*g2]   = pack2(p0, p1);
      u[2*g2+1] = pack2(p2, p3);
    }
#pragma unroll
    for (int j2 = 0; j2 < 8; ++j2) pex[j2] = (uint_t)__shfl_xor((int)u[j2], 32);
    const ushort_t* vtc = vt[cur];
#pragma unroll
    for (int s = 0; s < 2; ++s) {
      uint4 au;
      au.x = hl ? pex[4*s+2] : u[4*s+0];
      au.y = hl ? pex[4*s+3] : u[4*s+1];
      au.z = hl ? u[4*s+2]   : pex[4*s+0];
      au.w = hl ? u[4*s+3]   : pex[4*s+1];
      union { uint4 ui; bf16x8 bv; } cvt; cvt.ui = au;
      bf16x8 pa = cvt.bv;
#pragma unroll
      for (int nt = 0; nt < 6; ++nt) {
        const ushort_t* vr = &vtc[(nt*32 + ql)*VT_P + s*16 + hl*8];
        bf16x4 vlo = *(const bf16x4*)vr;
        bf16x4 vhi = *(const bf16x4*)(vr + 4);
        bf16x8 vf = __builtin_shufflevector(vlo, vhi, 0, 1, 2, 3, 4, 5, 6, 7);
        acc[nt] = __builtin_amdgcn_mfma_f32_32x32x16_bf16(pa, vf, acc[nt], 0, 0, 0);
      }
    }
    if (kb < 31) {
      int nxt = cur ^ 1;
#pragma unroll
      for (int j2 = 0; j2 < 3; ++j2) {
        ushort_t* kd = &kt[nxt][kdsto[j2]];
        *(bf16x4*)kd = __builtin_shufflevector(kpre[j2], kpre[j2], 0, 1, 2, 3);
        *(bf16x4*)(kd+4) = __builtin_shufflevector(kpre[j2], kpre[j2], 4, 5, 6, 7);
        ushort_t* vd = &vt[nxt][vdsto[j2]];
        *(bf16x4*)vd = __builtin_shufflevector(vpre[j2], vpre[j2], 0, 1, 2, 3);
        *(bf16x4*)(vd+4) = __builtin_shufflevector(vpre[j2], vpre[j2], 4, 5, 6, 7);
      }
    }
    __syncthreads();
  }
  lsum += __shfl_xor(lsum, 32);
  if (lane < 32) {
    alds[w][ql] = 1.0f / lsum;
    lpart[(size_t)split*24*NFIX + (size_t)bh*NFIX + qrow0 + ql] = lsum;
  }
  asm volatile("s_waitcnt lgkmcnt(0)" ::: "memory");
  float lv[4][4];
#pragma unroll
  for (int g2 = 0; g2 < 4; ++g2) {
    f32x4 tv = *(const f32x4*)&alds[w][8*g2 + 4*hl];
#pragma unroll
    for (int rr = 0; rr < 4; ++rr) lv[g2][rr] = tv[rr];
  }
  // ---- epilogue: O_s stored as f16 bits (split-combine precision) ----
  ushort_t* tw = (w == 0) ? kt[0] : (w == 1) ? kt[1] : (w == 2) ? vt[0] : vt[1];
#pragma unroll
  for (int nt = 0; nt < 6; ++nt) {
    int ch = nt*32 + ql;
#pragma unroll
    for (int r = 0; r < 16; ++r) {
      int qrow = (r&3) + 8*(r>>2) + 4*hl;
      tw[qrow*TW_P + ch] = f2h_bits(acc[nt][r] * lv[r>>2][r&3]);
    }
  }
  asm volatile("s_waitcnt lgkmcnt(0)" ::: "memory");
  const size_t SS = (size_t)8192*1152;
  ushort_t* opb = opart + (size_t)split*SS;
  size_t nbase = (size_t)(b*NFIX + qrow0) * 3;
#pragma unroll
  for (int i = 0; i < 12; ++i) {
    int chunk = i*64 + lane;
    int nl = chunk >> 3, jc = chunk & 7;
    int qq = nl / 3, dd = nl - 3*qq;
    ushort_t hv[8];
#pragma unroll
    for (int e = 0; e < 8; ++e)
      hv[e] = tw[qq*TW_P + (jc*8 + e)*3 + dd];
    uint4 sv;
    sv.x = (uint_t)hv[0] | ((uint_t)hv[1] << 16);
    sv.y = (uint_t)hv[2] | ((uint_t)hv[3] << 16);
    sv.z = (uint_t)hv[4] | ((uint_t)hv[5] << 16);
    sv.w = (uint_t)hv[6] | ((uint_t)hv[7] << 16);
    *(uint4*)&opb[(nbase + nl)*384 + h*64 + jc*8] = sv;
  }
}

// ---------------- x1mid fp16 MFMA + fused LN2, 768 threads (12 waves) ----------------
#define AP 68
#define XLP 132
__global__ __launch_bounds__(768) void x1mid_mfma(
    const float* __restrict__ xdi, const ushort_t* __restrict__ opart,
    const float* __restrict__ lpart, const _Float16* __restrict__ kmf16,
    const _Float16* __restrict__ Af16, float* __restrict__ xmid,
    _Float16* __restrict__ nxh, const float* __restrict__ g2,
    const float* __restrict__ b2) {
  __shared__ __align__(16) char smem[50944];
  _Float16* As = (_Float16*)smem;                 // 128 x AP = 17408 B
  _Float16* Bt = (_Float16*)(smem + 17408);       //  96 x AP = 13056 B
  float* wlsL  = (float*)(smem + 30464);          //  32 x 6 x 2 = 1536 B
  float* X     = (float*)smem;                    // epilogue overlay: 96 x XLP f32 = 50688 B
  float* stats = (float*)(smem + 50688);          // 32 x 2 f32 = 256 B
  int blk = blockIdx.x;
  int n0 = blk * 96;
  int pt0 = blk * 32;
  int t = threadIdx.x;
  int w = t >> 6, lane = t & 63, ql = lane & 31, hl = lane >> 5;
  int nsub = w >> 2, mt2 = w & 3;                 // 12 waves: 3 n-subtiles x 4 m-tiles
  if (t < 192) {
    int ptl = t / 6, h = t % 6;
    int ptg = pt0 + ptl;
    int b = ptg >> 11, n = ptg & 2047;
    size_t lidx = (size_t)(b*HH + h)*NFIX + n;
    float l[NSPLIT]; float tot = 0.f;
#pragma unroll
    for (int s = 0; s < NSPLIT; ++s) {
      l[s] = lpart[(size_t)s*24*NFIX + lidx];
      tot += l[s];
    }
    float rd = 1.f / tot;
    float* wp = &wlsL[(ptl*6 + h)*NSPLIT];
#pragma unroll
    for (int s = 0; s < NSPLIT; ++s) wp[s] = l[s]*rd;
  }
  f32x16 acc;
#pragma unroll
  for (int r = 0; r < 16; ++r) acc[r] = 0.f;
  const size_t SS = (size_t)8192*1152;
  __syncthreads();
  for (int p = 0; p < 8; ++p) {
    for (int u = t; u < 1024; u += 768) {
      int m = u >> 3, kc = u & 7;
      f16x4 a0 = *(const f16x4*)&Af16[(size_t)m*512 + p*64 + kc*8];
      f16x4 a1 = *(const f16x4*)&Af16[(size_t)m*512 + p*64 + kc*8 + 4];
      _Float16* dst = &As[m*AP + kc*8];
      *(f16x4*)dst = a0;
      *(f16x4*)(dst+4) = a1;
    }
    {
      // Bt staging: 768 threads = 96 rows x 8 col-chunks of 8 f16
      int n_l = t >> 3, jc = t & 7;
      int n_g = n0 + n_l;
      _Float16* dst = &Bt[n_l*AP + jc*8];
      if (p < 6) {
        int pt_l = n_l / 3;
        const float* wp = &wlsL[(pt_l*6 + p)*NSPLIT];
        float facc[8];
#pragma unroll
        for (int e = 0; e < 8; ++e) facc[e] = 0.f;
#pragma unroll
        for (int s = 0; s < NSPLIT; ++s) {
          const ushort_t* src = opart + s*SS + (size_t)n_g*384 + p*64 + jc*8;
          uint4 ra = *(const uint4*)src;
          const _Float16* ua = (const _Float16*)&ra;
          float wsc = wp[s];
#pragma unroll
          for (int e = 0; e < 8; ++e)
            facc[e] += wsc * (float)ua[e];
        }
        _Float16 hv[8];
#pragma unroll
        for (int e = 0; e < 8; ++e) hv[e] = (_Float16)facc[e];
        *(f16x4*)dst = *(f16x4*)&hv[0];
        *(f16x4*)(dst+4) = *(f16x4*)&hv[4];
      } else {
        const _Float16* src = kmf16 + (size_t)n_g*128 + (p-6)*64 + jc*8;
        f16x4 v0 = *(const f16x4*)src;
        f16x4 v1 = *(const f16x4*)(src + 4);
        *(f16x4*)dst = v0; *(f16x4*)(dst+4) = v1;
      }
    }
    __syncthreads();
#pragma unroll
    for (int cs = 0; cs < 4; ++cs) {
      int kloc = cs*16 + hl*8;
      f16x4 b0 = *(const f16x4*)&Bt[(nsub*32 + ql)*AP + kloc];
      f16x4 b1 = *(const f16x4*)&Bt[(nsub*32 + ql)*AP + kloc + 4];
      f16x8 bf = __builtin_shufflevector(b0, b1, 0, 1, 2, 3, 4, 5, 6, 7);
      int mrow = mt2*32 + ql;
      f16x4 a0 = *(const f16x4*)&As[mrow*AP + kloc];
      f16x4 a1 = *(const f16x4*)&As[mrow*AP + kloc + 4];
      f16x8 af = __builtin_shufflevector(a0, a1, 0, 1, 2, 3, 4, 5, 6, 7);
      acc = __builtin_amdgcn_mfma_f32_32x32x16_f16(af, bf, acc, 0, 0, 0);
    }
    __syncthreads();
  }
  {
    int cbase = mt2*32 + 4*hl;
    float* xrow = &X[(nsub*32 + ql)*XLP];
#pragma unroll
    for (int r = 0; r < 16; ++r) {
      int col = cbase + (r&3) + 8*(r>>2);
      xrow[col] = acc[r];
    }
  }
  __syncthreads();
  // ---- Phase A: add residual (post-residual stays in X), emit xmid global ----
#pragma unroll
  for (int i = 0; i < 2; ++i) {
    int u = i*768 + t;                  // 96 rows x 16 chunks of 8 = 1536
    int row = u >> 4, c0 = (u & 15) * 8;
    float* xp = &X[row*XLP + c0];
    const float* xd = xdi + (size_t)(n0 + row)*128 + c0;
    float4 a0 = *(float4*)xp, a1 = *(float4*)(xp + 4);
    float4 d0 = *(const float4*)xd, d1 = *(const float4*)(xd + 4);
    a0.x += d0.x; a0.y += d0.y; a0.z += d0.z; a0.w += d0.w;
    a1.x += d1.x; a1.y += d1.y; a1.z += d1.z; a1.w += d1.w;
    *(float4*)xp = a0; *(float4*)(xp + 4) = a1;
    float* dst = xmid + (size_t)(n0 + row)*128 + c0;
    *(float4*)dst = a0; *(float4*)(dst + 4) = a1;
  }
  __syncthreads();
  // ---- Phase B: per-point LN stats (12 waves cover 32 points) ----
  for (int pi = w; pi < 32; pi += 12) {
    int c = lane;
    float a0 = X[(pi*3+0)*XLP + c], a1 = X[(pi*3+1)*XLP + c], a2 = X[(pi*3+2)*XLP + c];
    float e0 = X[(pi*3+0)*XLP + c + 64], e1 = X[(pi*3+1)*XLP + c + 64], e2 = X[(pi*3+2)*XLP + c + 64];
    float nva = sqrtf(a0*a0 + a1*a1 + a2*a2 + EPSF);
    float nvb = sqrtf(e0*e0 + e1*e1 + e2*e2 + EPSF);
    float s1 = nva + nvb;
    float s2 = nva*nva + nvb*nvb;
#pragma unroll
    for (int off = 32; off >= 1; off >>= 1) {
      s1 += __shfl_down(s1, off);
      s2 += __shfl_down(s2, off);
    }
    if (lane == 0) {
      float mu = s1 * (1.f/128.f);
      float var = s2 * (1.f/128.f) - mu*mu;
      stats[pi*2]   = mu;
      stats[pi*2+1] = rsqrtf(var + LNEPSF);
    }
  }
  __syncthreads();
  // ---- Phase C: emit nxh f16 (LN2-normalized) ----
#pragma unroll
  for (int i = 0; i < 2; ++i) {
    int u = i*768 + t;
    int row = u >> 4, c0 = (u & 15) * 8;
    int pt_l = row / 3;
    float mu = stats[pt_l*2], rsig = stats[pt_l*2+1];
    const float* r0 = &X[(pt_l*3 + 0)*XLP + c0];
    const float* r1 = &X[(pt_l*3 + 1)*XLP + c0];
    const float* r2 = &X[(pt_l*3 + 2)*XLP + c0];
    const float* rd = &X[row*XLP + c0];
    float xv[8];
#pragma unroll
    for (int e = 0; e < 8; ++e) {
      float x0 = r0[e], x1 = r1[e], x2 = r2[e];
      float nv = sqrtf(x0*x0 + x1*x1 + x2*x2 + EPSF);
      float nnew = g2[c0 + e] * ((nv - mu) * rsig) + b2[c0 + e];
      xv[e] = rd[e] * (nnew / nv);
    }
    uint4 sv;
    sv.x = packh2(xv[0], xv[1]); sv.y = packh2(xv[2], xv[3]);
    sv.z = packh2(xv[4], xv[5]); sv.w = packh2(xv[6], xv[7]);
    *(uint4*)&nxh[(size_t)(n0 + row)*128 + c0] = sv;
  }
}

// ---------------- conv3+conv4 FUSED: 32-pt tile, 512 thr / 8 waves, h3 lives in LDS ----------------
// Phase 1: stage nxh (25 KB), conv3 MFMAs (wave w -> o-range w*32, all 3 d in-register).
// Phase 2: vnleaky -> H[d*32+p][260] f16 in LDS (overlays Xs3); conv4 MFMAs read H
//          (wave: ph=w>>2 point-half, o4=(w&3)*32; exact conv4 16x16x32 frag code).
// Phase 3: vnleaky -> trF f32 (overlays H) -> coalesced out + xmid residual.
// h3 global round-trip (25 MB) and one launch eliminated; all rounding identical (f16 via LDS).
#define X3P 132
#define HP4 260
#define TF4P 388
__global__ __launch_bounds__(512) void conv34_fused(const _Float16* __restrict__ nxh,
    const _Float16* __restrict__ W3h, const _Float16* __restrict__ U3h,
    const _Float16* __restrict__ W4h, const _Float16* __restrict__ U4h,
    const float* __restrict__ xmid, float* __restrict__ out) {
  __shared__ __align__(16) char smem[49920];
  _Float16* Xs3 = (_Float16*)smem;   // 3*32*X3P f16 = 25344 B (phase 1)
  _Float16* H   = (_Float16*)smem;   // 96 * HP4 f16 = 49920 B (phase 2, overlays Xs3)
  float* trF    = (float*)smem;      // 32 * TF4P f32 = 49664 B (phase 3, overlays H)
  int pt0 = blockIdx.x * 32;
  int t = threadIdx.x;
  int w = t >> 6, lane = t & 63, ql = lane & 31, hl = lane >> 5;
  // ---- Phase 1: stage X (96 rows x 128 cols, d-plane de-interleave) ----
#pragma unroll
  for (int i = 0; i < 3; ++i) {
    int u = i*512 + t;
    int r = u >> 4, c8 = u & 15;
    f16x8 gv = *(const f16x8*)&nxh[(size_t)(pt0*3 + r)*128 + c8*8];
    int d = r % 3, p = r / 3;
    _Float16* dst = &Xs3[(d*32 + p)*X3P + c8*8];
    *(f16x4*)dst = __builtin_shufflevector(gv, gv, 0, 1, 2, 3);
    *(f16x4*)(dst+4) = __builtin_shufflevector(gv, gv, 4, 5, 6, 7);
  }
  __syncthreads();
  int ot3 = w*32;
  const _Float16* Wp = W3h + (size_t)(ot3 + ql)*128 + hl*8;
  const _Float16* Up = U3h + (size_t)(ot3 + ql)*128 + hl*8;
  f32x16 accP[3], accD[3];
#pragma unroll
  for (int d = 0; d < 3; ++d)
#pragma unroll
    for (int r = 0; r < 16; ++r) { accP[d][r] = 0.f; accD[d][r] = 0.f; }
#pragma unroll
  for (int cs = 0; cs < 8; ++cs) {
    f16x8 wf = *(const f16x8*)(Wp + cs*16);
    f16x8 uf = *(const f16x8*)(Up + cs*16);
#pragma unroll
    for (int d = 0; d < 3; ++d) {
      const _Float16* xr = &Xs3[(d*32 + ql)*X3P + cs*16 + hl*8];
      f16x4 lo = *(const f16x4*)xr;
      f16x4 hi = *(const f16x4*)(xr + 4);
      f16x8 xf = __builtin_shufflevector(lo, hi, 0, 1, 2, 3, 4, 5, 6, 7);
      accP[d] = __builtin_amdgcn_mfma_f32_32x32x16_f16(wf, xf, accP[d], 0, 0, 0);
      accD[d] = __builtin_amdgcn_mfma_f32_32x32x16_f16(uf, xf, accD[d], 0, 0, 0);
    }
  }
  __syncthreads();   // all Xs3 reads done; safe to overlay with H
  // ---- Phase 2a: vnleaky -> H (rows d*32+p, cols o; disjoint col ranges per wave) ----
#pragma unroll
  for (int r = 0; r < 16; ++r) {
    int olr = (r&3) + 8*(r>>2) + 4*hl;
    float p3[3], d3[3], res[3];
#pragma unroll
    for (int d = 0; d < 3; ++d) { p3[d] = accP[d][r]; d3[d] = accD[d][r]; }
    vnleaky3(p3, d3, res);
#pragma unroll
    for (int d = 0; d < 3; ++d)
      H[(d*32 + ql)*HP4 + ot3 + olr] = (_Float16)res[d];
  }
  __syncthreads();
  // ---- Phase 2b: conv4 MFMAs from H ----
  int ph = w >> 2;           // point-half: 0 -> pts 0-15, 1 -> pts 16-31
  int ot4 = (w & 3) * 32;
  int nl = lane & 15, kq = lane >> 4;
  f32x4 acc4P[2][3], acc4D[2][3];
#pragma unroll
  for (int mt = 0; mt < 2; ++mt)
#pragma unroll
    for (int d = 0; d < 3; ++d)
#pragma unroll
      for (int r = 0; r < 4; ++r) { acc4P[mt][d][r] = 0.f; acc4D[mt][d][r] = 0.f; }
  const _Float16* Wb = W4h + (size_t)ot4*256;
  const _Float16* Ub = U4h + (size_t)ot4*256;
#pragma unroll
  for (int cs = 0; cs < 8; ++cs) {
    int kof = cs*32 + kq*8;
    f16x8 xf[3];
#pragma unroll
    for (int d = 0; d < 3; ++d) {
      const _Float16* xr = &H[(d*32 + ph*16 + nl)*HP4 + kof];
      f16x4 lo = *(const f16x4*)xr;
      f16x4 hi = *(const f16x4*)(xr + 4);
      xf[d] = __builtin_shufflevector(lo, hi, 0, 1, 2, 3, 4, 5, 6, 7);
    }
#pragma unroll
    for (int mt = 0; mt < 2; ++mt) {
      f16x8 wf = *(const f16x8*)(Wb + (size_t)(mt*16 + nl)*256 + kof);
      f16x8 uf = *(const f16x8*)(Ub + (size_t)(mt*16 + nl)*256 + kof);
#pragma unroll
      for (int d = 0; d < 3; ++d) {
        acc4P[mt][d] = __builtin_amdgcn_mfma_f32_16x16x32_f16(wf, xf[d], acc4P[mt][d], 0, 0, 0);
        acc4D[mt][d] = __builtin_amdgcn_mfma_f32_16x16x32_f16(uf, xf[d], acc4D[mt][d], 0, 0, 0);
      }
    }
  }
  __syncthreads();   // all H reads done; safe to overlay with trF
  // ---- Phase 3: vnleaky -> trF[p][o*3+d] (interleaved layout) ----
#pragma unroll
  for (int mt = 0; mt < 2; ++mt)
#pragma unroll
    for (int r = 0; r < 4; ++r) {
      int o = ot4 + mt*16 + kq*4 + r;
      int p_l = ph*16 + nl;
      float p3[3], d3[3], res[3];
#pragma unroll
      for (int d = 0; d < 3; ++d) { p3[d] = acc4P[mt][d][r]; d3[d] = acc4D[mt][d][r]; }
      vnleaky3(p3, d3, res);
#pragma unroll
      for (int d = 0; d < 3; ++d) trF[p_l*TF4P + o*3 + d] = res[d];
    }
  __syncthreads();
  // ---- write out: 32 rows x 384 f32, + xmid residual (de-interleaved [3bn+d][o]) ----
#pragma unroll
  for (int i = 0; i < 6; ++i) {
    int u = i*512 + t;
    int row = u / 96, c4 = u % 96;
    float4 vv = *(float4*)&trF[row*TF4P + c4*4];
    int bn = pt0 + row;
    float rs[4];
    const float* fv = (const float*)&vv;
#pragma unroll
    for (int e = 0; e < 4; ++e) {
      int col = c4*4 + e;
      int o = col / 3, d = col - 3*o;
      rs[e] = fv[e] + xmid[(size_t)(3*bn + d)*128 + o];
    }
    float4 ov; ov.x = rs[0]; ov.y = rs[1]; ov.z = rs[2]; ov.w = rs[3];
    *(float4*)&out[(size_t)bn*384 + c4*4] = ov;
  }
}

extern "C" void kernel_launch(void* const* d_in, const int* in_sizes, int n_in,
                              void* d_out, int out_size, void* d_ws, size_t ws_size,
                              hipStream_t stream) {
  const float* x   = (const float*)d_in[0];
  const int* knn   = (const int*)d_in[1];
  const float* g1  = (const float*)d_in[2];
  const float* b1  = (const float*)d_in[3];
  const float* g2  = (const float*)d_in[4];
  const float* b2  = (const float*)d_in[5];
  const float* Wq  = (const float*)d_in[6];
  const float* Wk  = (const float*)d_in[7];
  const float* Wv  = (const float*)d_in[8];
  const float* Wo  = (const float*)d_in[9];
  const float* W1  = (const float*)d_in[10];
  const float* U1  = (const float*)d_in[11];
  const float* W2  = (const float*)d_in[12];
  const float* W3  = (const float*)d_in[13];
  const float* U3  = (const float*)d_in[14];
  const float* W4  = (const float*)d_in[15];
  const float* U4  = (const float*)d_in[16];
  float* out = (float*)d_out;
  (void)n_in; (void)out_size; (void)ws_size;

  const size_t BN = (size_t)in_sizes[0] / 384;   // 8192

  float* ws    = (float*)d_ws;
  float* xdi   = ws;                          // BN*384 f32 (raw x, de-interleaved [n][c])
  float* xmid  = xdi + BN*384;                // BN*384 f32 (x_mid, de-interleaved)
  _Float16* kmf16 = (_Float16*)(xmid + BN*384);  // BN*384 fp16 [n][128]
  ushort_t* xbp = (ushort_t*)(kmf16 + BN*384);   // BN*384 bf16 (LN1 normalized, de-interleaved)
  ushort_t* qb = xbp + BN*384;                // BN*1152 bf16
  ushort_t* kb = qb + BN*1152;
  ushort_t* vb = kb + BN*1152;
  ushort_t* vT = vb + BN*1152;
  ushort_t* Wall = vT + BN*1152;              // 212992 bf16
  _Float16* Af16 = (_Float16*)(Wall + 212992);   // 65536 fp16
  _Float16* W3h = Af16 + 65536;               // 32768 fp16
  _Float16* U3h = W3h + 32768;
  _Float16* W4h = U3h + 32768;
  _Float16* U4h = W4h + 32768;
  ushort_t* opart = (ushort_t*)(U4h + 32768); // region 4*BN*1152 (2 splits used)
  float* lpart = (float*)(opart + 4*BN*1152); // 2*24*2048 f32
  // YZh/NBh (BN*768 f16 each = 12.6 MB) alias the opart region: conv1_post runs before attn.
  _Float16* YZh = (_Float16*)opart;
  _Float16* NBh = YZh + BN*768;
  _Float16* nxh = (_Float16*)qb;   // q dead after x1mid; LN2 out f16 [ng][128]

  prep_ln1<<<1600 + 4096, 256, 0, stream>>>(Wq, Wk, Wv, Wo, W1, U1, W2, W3, U3, W4, U4,
                                            Wall, Af16, W3h, U3h, W4h, U4h,
                                            x, xbp, xdi, g1, b1);
  qkv_conv1_mfma<<<192*4, 256, 0, stream>>>(xbp, Wall, qb, kb, vb, YZh, NBh);
  post_vtrans<<<768 + 1024, 256, 0, stream>>>(vb, vT, YZh, NBh, knn, kmf16);
  attn_kernel<<<16*24*NSPLIT, 256, 0, stream>>>(qb, kb, vT, opart, lpart);
  x1mid_mfma<<<256, 768, 0, stream>>>(xdi, opart, lpart, kmf16, Af16, xmid, nxh, g2, b2);
  conv34_fused<<<256, 512, 0, stream>>>(nxh, W3h, U3h, W4h, U4h, xmid, out);
}

// Round 12
// 298.510 us; speedup vs baseline: 1.3256x; 1.0463x over previous
//
#include <hip/hip_runtime.h>
#include <math.h>

// Problem constants (fixed by setup_inputs): B=4, N=2048, C=128, H=6, K=8
#define NFIX 2048
#define HH 6
#define KNN 8
#define NSLOPE 0.2f
#define EPSF 1e-6f
#define LNEPSF 1e-5f
// 0.125 (softmax scale) * log2(e), folded into Wq rows so S-MFMA output is exp2-ready
#define QSCALE 0.18033688011112042f
#define NSPLIT 2

typedef unsigned short ushort_t;
typedef unsigned int uint_t;
typedef __attribute__((ext_vector_type(8))) short bf16x8;
typedef __attribute__((ext_vector_type(4))) short bf16x4;
typedef __attribute__((ext_vector_type(8))) _Float16 f16x8;
typedef __attribute__((ext_vector_type(4))) _Float16 f16x4;
typedef __attribute__((ext_vector_type(16))) float f32x16;
typedef __attribute__((ext_vector_type(4))) float f32x4;

__device__ __forceinline__ ushort_t f2bf(float f) {
  union { float f; unsigned u; } v; v.f = f;
  unsigned r = v.u + 0x7fff + ((v.u >> 16) & 1);   // RNE
  return (ushort_t)(r >> 16);
}
__device__ __forceinline__ float bf2f(ushort_t u) {
  union { uint_t u; float f; } v; v.u = ((uint_t)u) << 16; return v.f;
}
__device__ __forceinline__ uint_t pack2(float a, float b) {
  return (uint_t)f2bf(a) | ((uint_t)f2bf(b) << 16);
}
// f32 -> f16 bit pattern (register-only)
__device__ __forceinline__ ushort_t f2h_bits(float a) {
  union { _Float16 h; ushort_t s; } cv; cv.h = (_Float16)a; return cv.s;
}
// pack two fp32 -> two f16 in one dword (register-only; no local-array aliasing)
__device__ __forceinline__ uint_t packh2(float a, float b) {
  union { _Float16 h; ushort_t s; } ha, hb;
  ha.h = (_Float16)a; hb.h = (_Float16)b;
  return (uint_t)ha.s | ((uint_t)hb.s << 16);
}

__device__ __forceinline__ void vnleaky3(const float* p, const float* dv, float* out) {
  float dot = p[0]*dv[0] + p[1]*dv[1] + p[2]*dv[2];
  float dsq = dv[0]*dv[0] + dv[1]*dv[1] + dv[2]*dv[2] + EPSF;
  float f = dot / dsq;
#pragma unroll
  for (int d = 0; d < 3; ++d) {
    float neg = p[d] - f * dv[d];
    out[d] = NSLOPE * p[d] + (1.f - NSLOPE) * ((dot >= 0.f) ? p[d] : neg);
  }
}

// ---------------- fused weight prep + LN1 (independent work; overlapped in one launch) ----------------
__global__ __launch_bounds__(256) void prep_ln1(
    const float* __restrict__ Wq, const float* __restrict__ Wk,
    const float* __restrict__ Wv, const float* __restrict__ Wo,
    const float* __restrict__ W1, const float* __restrict__ U1,
    const float* __restrict__ W2, const float* __restrict__ W3,
    const float* __restrict__ U3, const float* __restrict__ W4,
    const float* __restrict__ U4,
    ushort_t* __restrict__ Wall, _Float16* __restrict__ Af16,
    _Float16* __restrict__ W3h, _Float16* __restrict__ U3h,
    _Float16* __restrict__ W4h, _Float16* __restrict__ U4h,
    const float* __restrict__ xin, ushort_t* __restrict__ xbp,
    float* __restrict__ xdi, const float* __restrict__ g1,
    const float* __restrict__ b1) {
  __shared__ float red[8];
  int bi = blockIdx.x;
  if (bi >= 1600) {
    // ---- LN1: 2 points per block ----
    int t = threadIdx.x;
    int half = t >> 7, c = t & 127;
    int bn = (bi - 1600) * 2 + half;
    const float* row = xin + (size_t)bn * 384;
    float x0 = row[c*3+0], x1 = row[c*3+1], x2 = row[c*3+2];
    float nv = sqrtf(x0*x0 + x1*x1 + x2*x2 + EPSF);
    float s1 = nv, s2 = nv*nv;
#pragma unroll
    for (int off = 32; off >= 1; off >>= 1) {
      s1 += __shfl_down(s1, off);
      s2 += __shfl_down(s2, off);
    }
    int lane = t & 63, w = t >> 6;
    if (lane == 0) { red[w*2] = s1; red[w*2+1] = s2; }
    __syncthreads();
    int rb4 = (w >> 1) * 4;
    float tot1 = red[rb4] + red[rb4+2], tot2 = red[rb4+1] + red[rb4+3];
    float mu  = tot1 * (1.f/128.f);
    float var = tot2 * (1.f/128.f) - mu*mu;
    float rsig = rsqrtf(var + LNEPSF);
    float nnew = g1[c] * ((nv - mu) * rsig) + b1[c];
    float sc = nnew / nv;
    size_t rb = (size_t)bn * 384;
    xbp[rb + c]       = f2bf(x0*sc);
    xbp[rb + 128 + c] = f2bf(x1*sc);
    xbp[rb + 256 + c] = f2bf(x2*sc);
    xdi[rb + c]       = x0;
    xdi[rb + 128 + c] = x1;
    xdi[rb + 256 + c] = x2;
    return;
  }
  int idx = bi * 256 + threadIdx.x;
  if (idx < 212992) {
    int m = idx >> 7, c = idx & 127;
    float val;
    if (m < 384)       val = Wq[m*128 + c] * QSCALE;
    else if (m < 768)  val = Wk[(m-384)*128 + c];
    else if (m < 1152) val = Wv[(m-768)*128 + c];
    else {
      int j = m - 1152;
      if (j < 128)      val = W1[j*256 + c];
      else if (j < 256) val = U1[(j-128)*256 + c];
      else if (j < 384) { int o = j-256; val = W1[o*256 + 128 + c] - W1[o*256 + c]; }
      else              { int o = j-384; val = U1[o*256 + 128 + c] - U1[o*256 + c]; }
    }
    Wall[idx] = f2bf(val); return;
  }
  idx -= 212992;
  if (idx < 49152) {
    int c = idx / 384, j = idx % 384;   // coalesced: j fast -> Wo stride-4B, W2 wave-uniform
    float s = 0.f;
    for (int cp = 0; cp < 128; ++cp) s += W2[c*256 + cp] * Wo[cp*384 + j];
    Af16[(size_t)c*512 + j] = (_Float16)s; return;
  }
  idx -= 49152;
  if (idx < 16384) {
    int c2 = idx / 128, c = idx % 128;
    Af16[(size_t)c*512 + 384 + c2] = (_Float16)W2[c*256 + 128 + c2]; return;
  }
  idx -= 16384;
  if (idx < 32768) { W3h[idx] = (_Float16)W3[idx]; return; }
  idx -= 32768;
  if (idx < 32768) { U3h[idx] = (_Float16)U3[idx]; return; }
  idx -= 32768;
  if (idx < 32768) { W4h[idx] = (_Float16)W4[idx]; return; }
  idx -= 32768;
  if (idx < 32768) { U4h[idx] = (_Float16)U4[idx]; return; }
}

// ---------------- fused QKV + conv1 MFMA GEMM: weight-tile DOUBLE BUFFER ----------------
// One barrier per m-tile (was 2): next 8KB Wall tile prefetched into regs during
// MFMA+epilogue, ds-written to the alternate buffer after, single sync. Math identical.
#define XT_PITCH 132
#define WT_PITCH 132
#define TR_PITCH 36
__global__ __launch_bounds__(256, 2) void qkv_conv1_mfma(
    const ushort_t* __restrict__ xb, const ushort_t* __restrict__ Wall,
    ushort_t* __restrict__ q, ushort_t* __restrict__ k, ushort_t* __restrict__ v,
    _Float16* __restrict__ YZh, _Float16* __restrict__ NBh) {
  __shared__ ushort_t xs[128*XT_PITCH];
  __shared__ ushort_t wt[2][32*WT_PITCH];
  __shared__ float tr[4][32*TR_PITCH];
  int nb = blockIdx.x % 192;
  int mq = blockIdx.x / 192;
  int n0 = nb * 128;
  int t = threadIdx.x;
  int w = t >> 6, lane = t & 63, ql = lane & 31, hl = lane >> 5;
  for (int idx = t; idx < 2048; idx += 256) {
    int n = idx >> 4, c16 = idx & 15;
    bf16x8 gv = *(const bf16x8*)&xb[(size_t)(n0 + n)*128 + c16*8];
    ushort_t* dst = &xs[n*XT_PITCH + c16*8];
    *(bf16x4*)dst = __builtin_shufflevector(gv, gv, 0, 1, 2, 3);
    *(bf16x4*)(dst+4) = __builtin_shufflevector(gv, gv, 4, 5, 6, 7);
  }
  // stage wt[0] (first m-tile)
#pragma unroll
  for (int i = 0; i < 2; ++i) {
    int idx = i*256 + t;
    int mm = idx >> 4, c16 = idx & 15;
    bf16x8 gv = *(const bf16x8*)&Wall[(size_t)(mq*416 + mm)*128 + c16*8];
    ushort_t* dst = &wt[0][mm*WT_PITCH + c16*8];
    *(bf16x4*)dst = __builtin_shufflevector(gv, gv, 0, 1, 2, 3);
    *(bf16x4*)(dst+4) = __builtin_shufflevector(gv, gv, 4, 5, 6, 7);
  }
  __syncthreads();
  bf16x8 xf[8];
  {
    const ushort_t* xr = &xs[(w*32 + ql)*XT_PITCH + hl*8];
#pragma unroll
    for (int cs = 0; cs < 8; ++cs) {
      bf16x4 lo = *(const bf16x4*)(xr + cs*16);
      bf16x4 hi = *(const bf16x4*)(xr + cs*16 + 4);
      xf[cs] = __builtin_shufflevector(lo, hi, 0, 1, 2, 3, 4, 5, 6, 7);
    }
  }
  int ng = n0 + w*32 + ql;
  int pt = ng / 3;
  int d  = ng - 3*pt;
  float* trw = tr[w];
  int mm0 = t >> 4, c160 = t & 15;            // prefetch chunk 0 decode
  int mm1 = (t + 256) >> 4, c161 = t & 15;    // prefetch chunk 1 decode
  for (int mt = 0; mt < 13; ++mt) {
    int m0 = mq*416 + mt*32;
    int cur = mt & 1;
    // prefetch next weight tile into registers (hides under MFMA+epilogue)
    bf16x8 wpre0, wpre1;
    if (mt < 12) {
      int m0n = m0 + 32;
      wpre0 = *(const bf16x8*)&Wall[(size_t)(m0n + mm0)*128 + c160*8];
      wpre1 = *(const bf16x8*)&Wall[(size_t)(m0n + mm1)*128 + c161*8];
    }
    f32x16 acc;
#pragma unroll
    for (int r = 0; r < 16; ++r) acc[r] = 0.f;
    const ushort_t* wr = &wt[cur][ql*WT_PITCH + hl*8];
#pragma unroll
    for (int cs = 0; cs < 8; ++cs) {
      bf16x4 lo = *(const bf16x4*)(wr + cs*16);
      bf16x4 hi = *(const bf16x4*)(wr + cs*16 + 4);
      bf16x8 af = __builtin_shufflevector(lo, hi, 0, 1, 2, 3, 4, 5, 6, 7);
      acc = __builtin_amdgcn_mfma_f32_32x32x16_bf16(af, xf[cs], acc, 0, 0, 0);
    }
#pragma unroll
    for (int r = 0; r < 16; ++r) {
      int mrow = (r&3) + 8*(r>>2) + 4*hl;
      trw[ql*TR_PITCH + mrow] = acc[r];
    }
    asm volatile("s_waitcnt lgkmcnt(0)" ::: "memory");
    float4 c0 = *(float4*)&trw[ql*TR_PITCH + hl*16 + 0];
    float4 c1 = *(float4*)&trw[ql*TR_PITCH + hl*16 + 4];
    float4 c2 = *(float4*)&trw[ql*TR_PITCH + hl*16 + 8];
    float4 c3 = *(float4*)&trw[ql*TR_PITCH + hl*16 + 12];
    asm volatile("s_waitcnt lgkmcnt(0)" ::: "memory");
    int mg = m0 + hl*16;
    if (m0 < 1152) {
      uint4 s0, s1;
      s0.x = pack2(c0.x, c0.y); s0.y = pack2(c0.z, c0.w);
      s0.z = pack2(c1.x, c1.y); s0.w = pack2(c1.z, c1.w);
      s1.x = pack2(c2.x, c2.y); s1.y = pack2(c2.z, c2.w);
      s1.z = pack2(c3.x, c3.y); s1.w = pack2(c3.z, c3.w);
      ushort_t* dst;
      if (m0 < 384)       dst = q + (size_t)pt*1152 + d*384 + mg;
      else if (m0 < 768)  dst = k + (size_t)pt*1152 + d*384 + (mg - 384);
      else                dst = v + (size_t)pt*1152 + d*384 + (mg - 768);
      *(uint4*)dst = s0;
      *(uint4*)(dst + 8) = s1;
    } else {
      int mat = mg - 1152;
      int sub = mat >> 7, o = mat & 127;
      _Float16* basep = (sub < 2) ? YZh : NBh;
      _Float16* dst = basep + (size_t)pt*768 + d*256 + (sub & 1)*128 + o;
      uint4 s0, s1;
      s0.x = packh2(c0.x, c0.y); s0.y = packh2(c0.z, c0.w);
      s0.z = packh2(c1.x, c1.y); s0.w = packh2(c1.z, c1.w);
      s1.x = packh2(c2.x, c2.y); s1.y = packh2(c2.z, c2.w);
      s1.z = packh2(c3.x, c3.y); s1.w = packh2(c3.z, c3.w);
      *(uint4*)dst = s0;
      *(uint4*)(dst + 8) = s1;
    }
    if (mt < 12) {
      int nxt = cur ^ 1;
      ushort_t* d0 = &wt[nxt][mm0*WT_PITCH + c160*8];
      *(bf16x4*)d0 = __builtin_shufflevector(wpre0, wpre0, 0, 1, 2, 3);
      *(bf16x4*)(d0+4) = __builtin_shufflevector(wpre0, wpre0, 4, 5, 6, 7);
      ushort_t* d1 = &wt[nxt][mm1*WT_PITCH + c161*8];
      *(bf16x4*)d1 = __builtin_shufflevector(wpre1, wpre1, 0, 1, 2, 3);
      *(bf16x4*)(d1+4) = __builtin_shufflevector(wpre1, wpre1, 4, 5, 6, 7);
    }
    __syncthreads();
  }
}

// ---------------- fused V-transpose + conv1-post (independent; overlapped in one launch) ----------------
#define VT_LP 196
__global__ __launch_bounds__(256) void post_vtrans(const ushort_t* __restrict__ v,
    ushort_t* __restrict__ vT, const _Float16* __restrict__ YZh,
    const _Float16* __restrict__ NBh, const int* __restrict__ knn_index,
    _Float16* __restrict__ kmf16) {
  __shared__ ushort_t tl[64*VT_LP];   // 25088 B
  __shared__ int sidx[8][KNN];
  int blk = blockIdx.x;
  int t = threadIdx.x;
  if (blk < 768) {
    int bh = blk / 32, ptile = blk % 32;
    int b = bh / HH, h = bh % HH;
    int pt0 = ptile * 64;
#pragma unroll
    for (int i = 0; i < 6; ++i) {
      int u = i*256 + t;
      int p = u / 24, seg = u % 24;
      int d = seg >> 3, c8 = seg & 7;
      bf16x8 gv = *(const bf16x8*)&v[(size_t)(b*NFIX + pt0 + p)*1152 + d*384 + h*64 + c8*8];
      ushort_t* dst = &tl[p*VT_LP + d*64 + c8*8];
      *(bf16x4*)dst = __builtin_shufflevector(gv, gv, 0, 1, 2, 3);
      *(bf16x4*)(dst+4) = __builtin_shufflevector(gv, gv, 4, 5, 6, 7);
    }
    __syncthreads();
#pragma unroll
    for (int i = 0; i < 6; ++i) {
      int u = i*256 + t;
      int ch = u >> 3, pc = u & 7;
      int ol = ch / 3, dd = ch - 3*ol;
      int cloc = dd*64 + ol;
      ushort_t hv[8];
#pragma unroll
      for (int e = 0; e < 8; ++e)
        hv[e] = tl[(pc*8 + e)*VT_LP + cloc];
      uint4 o4;
      o4.x = (uint_t)hv[0] | ((uint_t)hv[1] << 16);
      o4.y = (uint_t)hv[2] | ((uint_t)hv[3] << 16);
      o4.z = (uint_t)hv[4] | ((uint_t)hv[5] << 16);
      o4.w = (uint_t)hv[6] | ((uint_t)hv[7] << 16);
      *(uint4*)&vT[((size_t)bh*192 + ch)*2048 + pt0 + pc*8] = o4;
    }
    return;
  }
  // conv1_post: 8 points per block; threads 0-127 -> pts 0-3, 128-255 -> pts 4-7
  int bnb = (blk - 768) * 8;
  int half = t >> 7, c = t & 127;
  if (t < 64) {
    int pi = t >> 3, kk = t & 7;
    int bn = bnb + pi;
    int b = bn / NFIX, n = bn % NFIX;
    sidx[pi][kk] = knn_index[(b*KNN + kk)*NFIX + n];
  }
  __syncthreads();
#pragma unroll
  for (int pi2 = 0; pi2 < 4; ++pi2) {
    int pi = half*4 + pi2;
    int bn = bnb + pi;
    float yb[3], zb[3];
#pragma unroll
    for (int d = 0; d < 3; ++d) {
      yb[d] = (float)NBh[(size_t)bn*768 + d*256 + c];
      zb[d] = (float)NBh[(size_t)bn*768 + d*256 + 128 + c];
    }
    float om[3] = {0.f, 0.f, 0.f};
#pragma unroll
    for (int kk = 0; kk < KNN; ++kk) {
      const _Float16* r = YZh + (size_t)sidx[pi][kk]*768;
      float p[3], dd[3];
#pragma unroll
      for (int d = 0; d < 3; ++d) {
        p[d]  = (float)r[d*256 + c] + yb[d];
        dd[d] = (float)r[d*256 + 128 + c] + zb[d];
      }
      float res[3];
      vnleaky3(p, dd, res);
      om[0] += res[0]; om[1] += res[1]; om[2] += res[2];
    }
#pragma unroll
    for (int d = 0; d < 3; ++d)
      kmf16[((size_t)bn*3 + d)*128 + c] = (_Float16)(om[d] * (1.f/KNN));
  }
}

// ---------------- attention (round-5 proven version): split-K=2, XCD-grouped decode,
// dual S-MFMA chains, pack2 RNE softmax, V LDS-staged dbuf, f16 O_s epilogue. ----------------
#define KT_P 196
#define VT_P 36
#define TW_P 195
__global__ __launch_bounds__(256, 2) void attn_kernel(const ushort_t* __restrict__ q,
    const ushort_t* __restrict__ k, const ushort_t* __restrict__ vT,
    ushort_t* __restrict__ opart, float* __restrict__ lpart) {
  __shared__ ushort_t kt[2][32*KT_P];
  __shared__ ushort_t vt[2][192*VT_P];
  __shared__ float alds[4][32];
  int blk = blockIdx.x;
  int xcd = blk & 7, j = blk >> 3;          // j in 0..95
  int g = xcd*6 + (j >> 4);                 // 48 groups
  int qt = j & 15;
  int bh = g % 24;
  int split = g / 24;                       // 0..1
  int b = bh / HH, h = bh % HH;
  int t = threadIdx.x;
  int w = t >> 6, lane = t & 63, ql = lane & 31, hl = lane >> 5;
  int qrow0 = qt*128 + w*32;
  const ushort_t* qpb = q + (size_t)(b*NFIX + qrow0 + ql)*1152 + h*64;
  bf16x8 qf[12];
#pragma unroll
  for (int cs = 0; cs < 12; ++cs) {
    int red0 = cs*16 + hl*8;
    int dq = red0 >> 6, ml = red0 & 63;
    qf[cs] = *(const bf16x8*)(qpb + dq*384 + ml);
  }
  const ushort_t* ksrc[3]; int kdsto[3];
  const ushort_t* vsrc[3]; int vdsto[3];
#pragma unroll
  for (int j2 = 0; j2 < 3; ++j2) {
    int idx = t + j2*256;
    int kp = idx / 24, c16 = idx % 24;
    int red0 = c16*8;
    int dk = red0 >> 6, ml = red0 & 63;
    ksrc[j2] = k + (size_t)(b*NFIX + kp)*1152 + dk*384 + h*64 + ml;
    kdsto[j2] = kp*KT_P + c16*8;
    int ch = idx >> 2, c4 = idx & 3;
    vsrc[j2] = vT + ((size_t)bh*192 + ch)*2048 + c4*8;
    vdsto[j2] = ch*VT_P + c4*8;
  }
  f32x16 acc[6];
#pragma unroll
  for (int nt = 0; nt < 6; ++nt)
#pragma unroll
    for (int r = 0; r < 16; ++r) acc[nt][r] = 0.f;
  float lsum = 0.f;
  int koff0 = split * 1024;                 // 1024 keys per split, 32 K-tiles
  bf16x8 kpre[3], vpre[3];
#pragma unroll
  for (int j2 = 0; j2 < 3; ++j2) {
    kpre[j2] = *(const bf16x8*)(ksrc[j2] + (size_t)koff0*1152);
    vpre[j2] = *(const bf16x8*)(vsrc[j2] + koff0);
  }
#pragma unroll
  for (int j2 = 0; j2 < 3; ++j2) {
    ushort_t* kd = &kt[0][kdsto[j2]];
    *(bf16x4*)kd = __builtin_shufflevector(kpre[j2], kpre[j2], 0, 1, 2, 3);
    *(bf16x4*)(kd+4) = __builtin_shufflevector(kpre[j2], kpre[j2], 4, 5, 6, 7);
    ushort_t* vd = &vt[0][vdsto[j2]];
    *(bf16x4*)vd = __builtin_shufflevector(vpre[j2], vpre[j2], 0, 1, 2, 3);
    *(bf16x4*)(vd+4) = __builtin_shufflevector(vpre[j2], vpre[j2], 4, 5, 6, 7);
  }
  __syncthreads();
  for (int kb = 0; kb < 32; ++kb) {
    int cur = kb & 1;
    if (kb < 31) {
      int koff = koff0 + (kb+1)*32;
#pragma unroll
      for (int j2 = 0; j2 < 3; ++j2) {
        kpre[j2] = *(const bf16x8*)(ksrc[j2] + (size_t)koff*1152);
        vpre[j2] = *(const bf16x8*)(vsrc[j2] + koff);
      }
    }
    // dual independent S accumulation chains (6-deep each instead of 12)
    f32x16 sca, scb;
#pragma unroll
    for (int r = 0; r < 16; ++r) { sca[r] = 0.f; scb[r] = 0.f; }
    const ushort_t* ktc = kt[cur];
#pragma unroll
    for (int cs = 0; cs < 12; ++cs) {
      const ushort_t* kr = &ktc[ql*KT_P + cs*16 + hl*8];
      bf16x4 alo = *(const bf16x4*)kr;
      bf16x4 ahi = *(const bf16x4*)(kr + 4);
      bf16x8 af = __builtin_shufflevector(alo, ahi, 0, 1, 2, 3, 4, 5, 6, 7);
      if (cs & 1) scb = __builtin_amdgcn_mfma_f32_32x32x16_bf16(af, qf[cs], scb, 0, 0, 0);
      else        sca = __builtin_amdgcn_mfma_f32_32x32x16_bf16(af, qf[cs], sca, 0, 0, 0);
    }
    uint_t u[8], pex[8];
#pragma unroll
    for (int g2 = 0; g2 < 4; ++g2) {
      float p0 = __builtin_amdgcn_exp2f(sca[g2*4 + 0] + scb[g2*4 + 0]);
      float p1 = __builtin_amdgcn_exp2f(sca[g2*4 + 1] + scb[g2*4 + 1]);
      float p2 = __builtin_amdgcn_exp2f(sca[g2*4 + 2] + scb[g2*4 + 2]);
      float p3 = __builtin_amdgcn_exp2f(sca[g2*4 + 3] + scb[g2*4 + 3]);
      lsum += (p0 + p1) + (p2 + p3);
      u[2*g2]   = pack2(p0, p1);
      u[2*g2+1] = pack2(p2, p3);
    }
#pragma unroll
    for (int j2 = 0; j2 < 8; ++j2) pex[j2] = (uint_t)__shfl_xor((int)u[j2], 32);
    const ushort_t* vtc = vt[cur];
#pragma unroll
    for (int s = 0; s < 2; ++s) {
      uint4 au;
      au.x = hl ? pex[4*s+2] : u[4*s+0];
      au.y = hl ? pex[4*s+3] : u[4*s+1];
      au.z = hl ? u[4*s+2]   : pex[4*s+0];
      au.w = hl ? u[4*s+3]   : pex[4*s+1];
      union { uint4 ui; bf16x8 bv; } cvt; cvt.ui = au;
      bf16x8 pa = cvt.bv;
#pragma unroll
      for (int nt = 0; nt < 6; ++nt) {
        const ushort_t* vr = &vtc[(nt*32 + ql)*VT_P + s*16 + hl*8];
        bf16x4 vlo = *(const bf16x4*)vr;
        bf16x4 vhi = *(const bf16x4*)(vr + 4);
        bf16x8 vf = __builtin_shufflevector(vlo, vhi, 0, 1, 2, 3, 4, 5, 6, 7);
        acc[nt] = __builtin_amdgcn_mfma_f32_32x32x16_bf16(pa, vf, acc[nt], 0, 0, 0);
      }
    }
    if (kb < 31) {
      int nxt = cur ^ 1;
#pragma unroll
      for (int j2 = 0; j2 < 3; ++j2) {
        ushort_t* kd = &kt[nxt][kdsto[j2]];
        *(bf16x4*)kd = __builtin_shufflevector(kpre[j2], kpre[j2], 0, 1, 2, 3);
        *(bf16x4*)(kd+4) = __builtin_shufflevector(kpre[j2], kpre[j2], 4, 5, 6, 7);
        ushort_t* vd = &vt[nxt][vdsto[j2]];
        *(bf16x4*)vd = __builtin_shufflevector(vpre[j2], vpre[j2], 0, 1, 2, 3);
        *(bf16x4*)(vd+4) = __builtin_shufflevector(vpre[j2], vpre[j2], 4, 5, 6, 7);
      }
    }
    __syncthreads();
  }
  lsum += __shfl_xor(lsum, 32);
  if (lane < 32) {
    alds[w][ql] = 1.0f / lsum;
    lpart[(size_t)split*24*NFIX + (size_t)bh*NFIX + qrow0 + ql] = lsum;
  }
  asm volatile("s_waitcnt lgkmcnt(0)" ::: "memory");
  float lv[4][4];
#pragma unroll
  for (int g2 = 0; g2 < 4; ++g2) {
    f32x4 tv = *(const f32x4*)&alds[w][8*g2 + 4*hl];
#pragma unroll
    for (int rr = 0; rr < 4; ++rr) lv[g2][rr] = tv[rr];
  }
  // ---- epilogue: O_s stored as f16 bits (split-combine precision) ----
  ushort_t* tw = (w == 0) ? kt[0] : (w == 1) ? kt[1] : (w == 2) ? vt[0] : vt[1];
#pragma unroll
  for (int nt = 0; nt < 6; ++nt) {
    int ch = nt*32 + ql;
#pragma unroll
    for (int r = 0; r < 16; ++r) {
      int qrow = (r&3) + 8*(r>>2) + 4*hl;
      tw[qrow*TW_P + ch] = f2h_bits(acc[nt][r] * lv[r>>2][r&3]);
    }
  }
  asm volatile("s_waitcnt lgkmcnt(0)" ::: "memory");
  const size_t SS = (size_t)8192*1152;
  ushort_t* opb = opart + (size_t)split*SS;
  size_t nbase = (size_t)(b*NFIX + qrow0) * 3;
#pragma unroll
  for (int i = 0; i < 12; ++i) {
    int chunk = i*64 + lane;
    int nl = chunk >> 3, jc = chunk & 7;
    int qq = nl / 3, dd = nl - 3*qq;
    ushort_t hv[8];
#pragma unroll
    for (int e = 0; e < 8; ++e)
      hv[e] = tw[qq*TW_P + (jc*8 + e)*3 + dd];
    uint4 sv;
    sv.x = (uint_t)hv[0] | ((uint_t)hv[1] << 16);
    sv.y = (uint_t)hv[2] | ((uint_t)hv[3] << 16);
    sv.z = (uint_t)hv[4] | ((uint_t)hv[5] << 16);
    sv.w = (uint_t)hv[6] | ((uint_t)hv[7] << 16);
    *(uint4*)&opb[(nbase + nl)*384 + h*64 + jc*8] = sv;
  }
}

// ---------------- x1mid fp16 MFMA + fused LN2, 768 threads (12 waves) ----------------
#define AP 68
#define XLP 132
__global__ __launch_bounds__(768) void x1mid_mfma(
    const float* __restrict__ xdi, const ushort_t* __restrict__ opart,
    const float* __restrict__ lpart, const _Float16* __restrict__ kmf16,
    const _Float16* __restrict__ Af16, float* __restrict__ xmid,
    _Float16* __restrict__ nxh, const float* __restrict__ g2,
    const float* __restrict__ b2) {
  __shared__ __align__(16) char smem[50944];
  _Float16* As = (_Float16*)smem;                 // 128 x AP = 17408 B
  _Float16* Bt = (_Float16*)(smem + 17408);       //  96 x AP = 13056 B
  float* wlsL  = (float*)(smem + 30464);          //  32 x 6 x 2 = 1536 B
  float* X     = (float*)smem;                    // epilogue overlay: 96 x XLP f32 = 50688 B
  float* stats = (float*)(smem + 50688);          // 32 x 2 f32 = 256 B
  int blk = blockIdx.x;
  int n0 = blk * 96;
  int pt0 = blk * 32;
  int t = threadIdx.x;
  int w = t >> 6, lane = t & 63, ql = lane & 31, hl = lane >> 5;
  int nsub = w >> 2, mt2 = w & 3;                 // 12 waves: 3 n-subtiles x 4 m-tiles
  if (t < 192) {
    int ptl = t / 6, h = t % 6;
    int ptg = pt0 + ptl;
    int b = ptg >> 11, n = ptg & 2047;
    size_t lidx = (size_t)(b*HH + h)*NFIX + n;
    float l[NSPLIT]; float tot = 0.f;
#pragma unroll
    for (int s = 0; s < NSPLIT; ++s) {
      l[s] = lpart[(size_t)s*24*NFIX + lidx];
      tot += l[s];
    }
    float rd = 1.f / tot;
    float* wp = &wlsL[(ptl*6 + h)*NSPLIT];
#pragma unroll
    for (int s = 0; s < NSPLIT; ++s) wp[s] = l[s]*rd;
  }
  f32x16 acc;
#pragma unroll
  for (int r = 0; r < 16; ++r) acc[r] = 0.f;
  const size_t SS = (size_t)8192*1152;
  __syncthreads();
  for (int p = 0; p < 8; ++p) {
    for (int u = t; u < 1024; u += 768) {
      int m = u >> 3, kc = u & 7;
      f16x4 a0 = *(const f16x4*)&Af16[(size_t)m*512 + p*64 + kc*8];
      f16x4 a1 = *(const f16x4*)&Af16[(size_t)m*512 + p*64 + kc*8 + 4];
      _Float16* dst = &As[m*AP + kc*8];
      *(f16x4*)dst = a0;
      *(f16x4*)(dst+4) = a1;
    }
    {
      // Bt staging: 768 threads = 96 rows x 8 col-chunks of 8 f16
      int n_l = t >> 3, jc = t & 7;
      int n_g = n0 + n_l;
      _Float16* dst = &Bt[n_l*AP + jc*8];
      if (p < 6) {
        int pt_l = n_l / 3;
        const float* wp = &wlsL[(pt_l*6 + p)*NSPLIT];
        float facc[8];
#pragma unroll
        for (int e = 0; e < 8; ++e) facc[e] = 0.f;
#pragma unroll
        for (int s = 0; s < NSPLIT; ++s) {
          const ushort_t* src = opart + s*SS + (size_t)n_g*384 + p*64 + jc*8;
          uint4 ra = *(const uint4*)src;
          const _Float16* ua = (const _Float16*)&ra;
          float wsc = wp[s];
#pragma unroll
          for (int e = 0; e < 8; ++e)
            facc[e] += wsc * (float)ua[e];
        }
        _Float16 hv[8];
#pragma unroll
        for (int e = 0; e < 8; ++e) hv[e] = (_Float16)facc[e];
        *(f16x4*)dst = *(f16x4*)&hv[0];
        *(f16x4*)(dst+4) = *(f16x4*)&hv[4];
      } else {
        const _Float16* src = kmf16 + (size_t)n_g*128 + (p-6)*64 + jc*8;
        f16x4 v0 = *(const f16x4*)src;
        f16x4 v1 = *(const f16x4*)(src + 4);
        *(f16x4*)dst = v0; *(f16x4*)(dst+4) = v1;
      }
    }
    __syncthreads();
#pragma unroll
    for (int cs = 0; cs < 4; ++cs) {
      int kloc = cs*16 + hl*8;
      f16x4 b0 = *(const f16x4*)&Bt[(nsub*32 + ql)*AP + kloc];
      f16x4 b1 = *(const f16x4*)&Bt[(nsub*32 + ql)*AP + kloc + 4];
      f16x8 bf = __builtin_shufflevector(b0, b1, 0, 1, 2, 3, 4, 5, 6, 7);
      int mrow = mt2*32 + ql;
      f16x4 a0 = *(const f16x4*)&As[mrow*AP + kloc];
      f16x4 a1 = *(const f16x4*)&As[mrow*AP + kloc + 4];
      f16x8 af = __builtin_shufflevector(a0, a1, 0, 1, 2, 3, 4, 5, 6, 7);
      acc = __builtin_amdgcn_mfma_f32_32x32x16_f16(af, bf, acc, 0, 0, 0);
    }
    __syncthreads();
  }
  {
    int cbase = mt2*32 + 4*hl;
    float* xrow = &X[(nsub*32 + ql)*XLP];
#pragma unroll
    for (int r = 0; r < 16; ++r) {
      int col = cbase + (r&3) + 8*(r>>2);
      xrow[col] = acc[r];
    }
  }
  __syncthreads();
  // ---- Phase A: add residual (post-residual stays in X), emit xmid global ----
#pragma unroll
  for (int i = 0; i < 2; ++i) {
    int u = i*768 + t;                  // 96 rows x 16 chunks of 8 = 1536
    int row = u >> 4, c0 = (u & 15) * 8;
    float* xp = &X[row*XLP + c0];
    const float* xd = xdi + (size_t)(n0 + row)*128 + c0;
    float4 a0 = *(float4*)xp, a1 = *(float4*)(xp + 4);
    float4 d0 = *(const float4*)xd, d1 = *(const float4*)(xd + 4);
    a0.x += d0.x; a0.y += d0.y; a0.z += d0.z; a0.w += d0.w;
    a1.x += d1.x; a1.y += d1.y; a1.z += d1.z; a1.w += d1.w;
    *(float4*)xp = a0; *(float4*)(xp + 4) = a1;
    float* dst = xmid + (size_t)(n0 + row)*128 + c0;
    *(float4*)dst = a0; *(float4*)(dst + 4) = a1;
  }
  __syncthreads();
  // ---- Phase B: per-point LN stats (12 waves cover 32 points) ----
  for (int pi = w; pi < 32; pi += 12) {
    int c = lane;
    float a0 = X[(pi*3+0)*XLP + c], a1 = X[(pi*3+1)*XLP + c], a2 = X[(pi*3+2)*XLP + c];
    float e0 = X[(pi*3+0)*XLP + c + 64], e1 = X[(pi*3+1)*XLP + c + 64], e2 = X[(pi*3+2)*XLP + c + 64];
    float nva = sqrtf(a0*a0 + a1*a1 + a2*a2 + EPSF);
    float nvb = sqrtf(e0*e0 + e1*e1 + e2*e2 + EPSF);
    float s1 = nva + nvb;
    float s2 = nva*nva + nvb*nvb;
#pragma unroll
    for (int off = 32; off >= 1; off >>= 1) {
      s1 += __shfl_down(s1, off);
      s2 += __shfl_down(s2, off);
    }
    if (lane == 0) {
      float mu = s1 * (1.f/128.f);
      float var = s2 * (1.f/128.f) - mu*mu;
      stats[pi*2]   = mu;
      stats[pi*2+1] = rsqrtf(var + LNEPSF);
    }
  }
  __syncthreads();
  // ---- Phase C: emit nxh f16 (LN2-normalized) ----
#pragma unroll
  for (int i = 0; i < 2; ++i) {
    int u = i*768 + t;
    int row = u >> 4, c0 = (u & 15) * 8;
    int pt_l = row / 3;
    float mu = stats[pt_l*2], rsig = stats[pt_l*2+1];
    const float* r0 = &X[(pt_l*3 + 0)*XLP + c0];
    const float* r1 = &X[(pt_l*3 + 1)*XLP + c0];
    const float* r2 = &X[(pt_l*3 + 2)*XLP + c0];
    const float* rd = &X[row*XLP + c0];
    float xv[8];
#pragma unroll
    for (int e = 0; e < 8; ++e) {
      float x0 = r0[e], x1 = r1[e], x2 = r2[e];
      float nv = sqrtf(x0*x0 + x1*x1 + x2*x2 + EPSF);
      float nnew = g2[c0 + e] * ((nv - mu) * rsig) + b2[c0 + e];
      xv[e] = rd[e] * (nnew / nv);
    }
    uint4 sv;
    sv.x = packh2(xv[0], xv[1]); sv.y = packh2(xv[2], xv[3]);
    sv.z = packh2(xv[4], xv[5]); sv.w = packh2(xv[6], xv[7]);
    *(uint4*)&nxh[(size_t)(n0 + row)*128 + c0] = sv;
  }
}

// ---------------- conv3+conv4 FUSED: 32-pt tile, 512 thr / 8 waves, h3 lives in LDS ----------------
#define X3P 132
#define HP4 260
#define TF4P 388
__global__ __launch_bounds__(512) void conv34_fused(const _Float16* __restrict__ nxh,
    const _Float16* __restrict__ W3h, const _Float16* __restrict__ U3h,
    const _Float16* __restrict__ W4h, const _Float16* __restrict__ U4h,
    const float* __restrict__ xmid, float* __restrict__ out) {
  __shared__ __align__(16) char smem[49920];
  _Float16* Xs3 = (_Float16*)smem;   // 3*32*X3P f16 = 25344 B (phase 1)
  _Float16* H   = (_Float16*)smem;   // 96 * HP4 f16 = 49920 B (phase 2, overlays Xs3)
  float* trF    = (float*)smem;      // 32 * TF4P f32 = 49664 B (phase 3, overlays H)
  int pt0 = blockIdx.x * 32;
  int t = threadIdx.x;
  int w = t >> 6, lane = t & 63, ql = lane & 31, hl = lane >> 5;
  // ---- Phase 1: stage X (96 rows x 128 cols, d-plane de-interleave) ----
#pragma unroll
  for (int i = 0; i < 3; ++i) {
    int u = i*512 + t;
    int r = u >> 4, c8 = u & 15;
    f16x8 gv = *(const f16x8*)&nxh[(size_t)(pt0*3 + r)*128 + c8*8];
    int d = r % 3, p = r / 3;
    _Float16* dst = &Xs3[(d*32 + p)*X3P + c8*8];
    *(f16x4*)dst = __builtin_shufflevector(gv, gv, 0, 1, 2, 3);
    *(f16x4*)(dst+4) = __builtin_shufflevector(gv, gv, 4, 5, 6, 7);
  }
  __syncthreads();
  int ot3 = w*32;
  const _Float16* Wp = W3h + (size_t)(ot3 + ql)*128 + hl*8;
  const _Float16* Up = U3h + (size_t)(ot3 + ql)*128 + hl*8;
  f32x16 accP[3], accD[3];
#pragma unroll
  for (int d = 0; d < 3; ++d)
#pragma unroll
    for (int r = 0; r < 16; ++r) { accP[d][r] = 0.f; accD[d][r] = 0.f; }
#pragma unroll
  for (int cs = 0; cs < 8; ++cs) {
    f16x8 wf = *(const f16x8*)(Wp + cs*16);
    f16x8 uf = *(const f16x8*)(Up + cs*16);
#pragma unroll
    for (int d = 0; d < 3; ++d) {
      const _Float16* xr = &Xs3[(d*32 + ql)*X3P + cs*16 + hl*8];
      f16x4 lo = *(const f16x4*)xr;
      f16x4 hi = *(const f16x4*)(xr + 4);
      f16x8 xf = __builtin_shufflevector(lo, hi, 0, 1, 2, 3, 4, 5, 6, 7);
      accP[d] = __builtin_amdgcn_mfma_f32_32x32x16_f16(wf, xf, accP[d], 0, 0, 0);
      accD[d] = __builtin_amdgcn_mfma_f32_32x32x16_f16(uf, xf, accD[d], 0, 0, 0);
    }
  }
  __syncthreads();   // all Xs3 reads done; safe to overlay with H
  // ---- Phase 2a: vnleaky -> H (rows d*32+p, cols o; disjoint col ranges per wave) ----
#pragma unroll
  for (int r = 0; r < 16; ++r) {
    int olr = (r&3) + 8*(r>>2) + 4*hl;
    float p3[3], d3[3], res[3];
#pragma unroll
    for (int d = 0; d < 3; ++d) { p3[d] = accP[d][r]; d3[d] = accD[d][r]; }
    vnleaky3(p3, d3, res);
#pragma unroll
    for (int d = 0; d < 3; ++d)
      H[(d*32 + ql)*HP4 + ot3 + olr] = (_Float16)res[d];
  }
  __syncthreads();
  // ---- Phase 2b: conv4 MFMAs from H ----
  int ph = w >> 2;           // point-half: 0 -> pts 0-15, 1 -> pts 16-31
  int ot4 = (w & 3) * 32;
  int nl = lane & 15, kq = lane >> 4;
  f32x4 acc4P[2][3], acc4D[2][3];
#pragma unroll
  for (int mt = 0; mt < 2; ++mt)
#pragma unroll
    for (int d = 0; d < 3; ++d)
#pragma unroll
      for (int r = 0; r < 4; ++r) { acc4P[mt][d][r] = 0.f; acc4D[mt][d][r] = 0.f; }
  const _Float16* Wb = W4h + (size_t)ot4*256;
  const _Float16* Ub = U4h + (size_t)ot4*256;
#pragma unroll
  for (int cs = 0; cs < 8; ++cs) {
    int kof = cs*32 + kq*8;
    f16x8 xf[3];
#pragma unroll
    for (int d = 0; d < 3; ++d) {
      const _Float16* xr = &H[(d*32 + ph*16 + nl)*HP4 + kof];
      f16x4 lo = *(const f16x4*)xr;
      f16x4 hi = *(const f16x4*)(xr + 4);
      xf[d] = __builtin_shufflevector(lo, hi, 0, 1, 2, 3, 4, 5, 6, 7);
    }
#pragma unroll
    for (int mt = 0; mt < 2; ++mt) {
      f16x8 wf = *(const f16x8*)(Wb + (size_t)(mt*16 + nl)*256 + kof);
      f16x8 uf = *(const f16x8*)(Ub + (size_t)(mt*16 + nl)*256 + kof);
#pragma unroll
      for (int d = 0; d < 3; ++d) {
        acc4P[mt][d] = __builtin_amdgcn_mfma_f32_16x16x32_f16(wf, xf[d], acc4P[mt][d], 0, 0, 0);
        acc4D[mt][d] = __builtin_amdgcn_mfma_f32_16x16x32_f16(uf, xf[d], acc4D[mt][d], 0, 0, 0);
      }
    }
  }
  __syncthreads();   // all H reads done; safe to overlay with trF
  // ---- Phase 3: vnleaky -> trF[p][o*3+d] (interleaved layout) ----
#pragma unroll
  for (int mt = 0; mt < 2; ++mt)
#pragma unroll
    for (int r = 0; r < 4; ++r) {
      int o = ot4 + mt*16 + kq*4 + r;
      int p_l = ph*16 + nl;
      float p3[3], d3[3], res[3];
#pragma unroll
      for (int d = 0; d < 3; ++d) { p3[d] = acc4P[mt][d][r]; d3[d] = acc4D[mt][d][r]; }
      vnleaky3(p3, d3, res);
#pragma unroll
      for (int d = 0; d < 3; ++d) trF[p_l*TF4P + o*3 + d] = res[d];
    }
  __syncthreads();
  // ---- write out: 32 rows x 384 f32, + xmid residual (de-interleaved [3bn+d][o]) ----
#pragma unroll
  for (int i = 0; i < 6; ++i) {
    int u = i*512 + t;
    int row = u / 96, c4 = u % 96;
    float4 vv = *(float4*)&trF[row*TF4P + c4*4];
    int bn = pt0 + row;
    float rs[4];
    const float* fv = (const float*)&vv;
#pragma unroll
    for (int e = 0; e < 4; ++e) {
      int col = c4*4 + e;
      int o = col / 3, d = col - 3*o;
      rs[e] = fv[e] + xmid[(size_t)(3*bn + d)*128 + o];
    }
    float4 ov; ov.x = rs[0]; ov.y = rs[1]; ov.z = rs[2]; ov.w = rs[3];
    *(float4*)&out[(size_t)bn*384 + c4*4] = ov;
  }
}

extern "C" void kernel_launch(void* const* d_in, const int* in_sizes, int n_in,
                              void* d_out, int out_size, void* d_ws, size_t ws_size,
                              hipStream_t stream) {
  const float* x   = (const float*)d_in[0];
  const int* knn   = (const int*)d_in[1];
  const float* g1  = (const float*)d_in[2];
  const float* b1  = (const float*)d_in[3];
  const float* g2  = (const float*)d_in[4];
  const float* b2  = (const float*)d_in[5];
  const float* Wq  = (const float*)d_in[6];
  const float* Wk  = (const float*)d_in[7];
  const float* Wv  = (const float*)d_in[8];
  const float* Wo  = (const float*)d_in[9];
  const float* W1  = (const float*)d_in[10];
  const float* U1  = (const float*)d_in[11];
  const float* W2  = (const float*)d_in[12];
  const float* W3  = (const float*)d_in[13];
  const float* U3  = (const float*)d_in[14];
  const float* W4  = (const float*)d_in[15];
  const float* U4  = (const float*)d_in[16];
  float* out = (float*)d_out;
  (void)n_in; (void)out_size; (void)ws_size;

  const size_t BN = (size_t)in_sizes[0] / 384;   // 8192

  float* ws    = (float*)d_ws;
  float* xdi   = ws;                          // BN*384 f32 (raw x, de-interleaved [n][c])
  float* xmid  = xdi + BN*384;                // BN*384 f32 (x_mid, de-interleaved)
  _Float16* kmf16 = (_Float16*)(xmid + BN*384);  // BN*384 fp16 [n][128]
  ushort_t* xbp = (ushort_t*)(kmf16 + BN*384);   // BN*384 bf16 (LN1 normalized, de-interleaved)
  ushort_t* qb = xbp + BN*384;                // BN*1152 bf16
  ushort_t* kb = qb + BN*1152;
  ushort_t* vb = kb + BN*1152;
  ushort_t* vT = vb + BN*1152;
  ushort_t* Wall = vT + BN*1152;              // 212992 bf16
  _Float16* Af16 = (_Float16*)(Wall + 212992);   // 65536 fp16
  _Float16* W3h = Af16 + 65536;               // 32768 fp16
  _Float16* U3h = W3h + 32768;
  _Float16* W4h = U3h + 32768;
  _Float16* U4h = W4h + 32768;
  ushort_t* opart = (ushort_t*)(U4h + 32768); // region 4*BN*1152 (2 splits used)
  float* lpart = (float*)(opart + 4*BN*1152); // 2*24*2048 f32
  // YZh/NBh (BN*768 f16 each = 12.6 MB) alias the opart region: conv1_post runs before attn.
  _Float16* YZh = (_Float16*)opart;
  _Float16* NBh = YZh + BN*768;
  _Float16* nxh = (_Float16*)qb;   // q dead after x1mid; LN2 out f16 [ng][128]

  prep_ln1<<<1600 + 4096, 256, 0, stream>>>(Wq, Wk, Wv, Wo, W1, U1, W2, W3, U3, W4, U4,
                                            Wall, Af16, W3h, U3h, W4h, U4h,
                                            x, xbp, xdi, g1, b1);
  qkv_conv1_mfma<<<192*4, 256, 0, stream>>>(xbp, Wall, qb, kb, vb, YZh, NBh);
  post_vtrans<<<768 + 1024, 256, 0, stream>>>(vb, vT, YZh, NBh, knn, kmf16);
  attn_kernel<<<16*24*NSPLIT, 256, 0, stream>>>(qb, kb, vT, opart, lpart);
  x1mid_mfma<<<256, 768, 0, stream>>>(xdi, opart, lpart, kmf16, Af16, xmid, nxh, g2, b2);
  conv34_fused<<<256, 512, 0, stream>>>(nxh, W3h, U3h, W4h, U4h, xmid, out);
}

// Round 13
// 294.612 us; speedup vs baseline: 1.3431x; 1.0132x over previous
//
#include <hip/hip_runtime.h>
#include <math.h>

// Problem constants (fixed by setup_inputs): B=4, N=2048, C=128, H=6, K=8
#define NFIX 2048
#define HH 6
#define KNN 8
#define NSLOPE 0.2f
#define EPSF 1e-6f
#define LNEPSF 1e-5f
// 0.125 (softmax scale) * log2(e), folded into Wq rows so S-MFMA output is exp2-ready
#define QSCALE 0.18033688011112042f
#define NSPLIT 2

typedef unsigned short ushort_t;
typedef unsigned int uint_t;
typedef __attribute__((ext_vector_type(8))) short bf16x8;
typedef __attribute__((ext_vector_type(4))) short bf16x4;
typedef __attribute__((ext_vector_type(8))) _Float16 f16x8;
typedef __attribute__((ext_vector_type(4))) _Float16 f16x4;
typedef __attribute__((ext_vector_type(16))) float f32x16;
typedef __attribute__((ext_vector_type(4))) float f32x4;

__device__ __forceinline__ ushort_t f2bf(float f) {
  union { float f; unsigned u; } v; v.f = f;
  unsigned r = v.u + 0x7fff + ((v.u >> 16) & 1);   // RNE
  return (ushort_t)(r >> 16);
}
__device__ __forceinline__ float bf2f(ushort_t u) {
  union { uint_t u; float f; } v; v.u = ((uint_t)u) << 16; return v.f;
}
__device__ __forceinline__ uint_t pack2(float a, float b) {
  return (uint_t)f2bf(a) | ((uint_t)f2bf(b) << 16);
}
// f32 -> f16 bit pattern (register-only)
__device__ __forceinline__ ushort_t f2h_bits(float a) {
  union { _Float16 h; ushort_t s; } cv; cv.h = (_Float16)a; return cv.s;
}
// pack two fp32 -> two f16 in one dword (register-only; no local-array aliasing)
__device__ __forceinline__ uint_t packh2(float a, float b) {
  union { _Float16 h; ushort_t s; } ha, hb;
  ha.h = (_Float16)a; hb.h = (_Float16)b;
  return (uint_t)ha.s | ((uint_t)hb.s << 16);
}

__device__ __forceinline__ void vnleaky3(const float* p, const float* dv, float* out) {
  float dot = p[0]*dv[0] + p[1]*dv[1] + p[2]*dv[2];
  float dsq = dv[0]*dv[0] + dv[1]*dv[1] + dv[2]*dv[2] + EPSF;
  float f = dot / dsq;
#pragma unroll
  for (int d = 0; d < 3; ++d) {
    float neg = p[d] - f * dv[d];
    out[d] = NSLOPE * p[d] + (1.f - NSLOPE) * ((dot >= 0.f) ? p[d] : neg);
  }
}

// ---------------- fused weight prep + LN1 (independent work; overlapped in one launch) ----------------
__global__ __launch_bounds__(256) void prep_ln1(
    const float* __restrict__ Wq, const float* __restrict__ Wk,
    const float* __restrict__ Wv, const float* __restrict__ Wo,
    const float* __restrict__ W1, const float* __restrict__ U1,
    const float* __restrict__ W2, const float* __restrict__ W3,
    const float* __restrict__ U3, const float* __restrict__ W4,
    const float* __restrict__ U4,
    ushort_t* __restrict__ Wall, _Float16* __restrict__ Af16,
    _Float16* __restrict__ W3h, _Float16* __restrict__ U3h,
    _Float16* __restrict__ W4h, _Float16* __restrict__ U4h,
    const float* __restrict__ xin, ushort_t* __restrict__ xbp,
    float* __restrict__ xdi, const float* __restrict__ g1,
    const float* __restrict__ b1) {
  __shared__ float red[8];
  int bi = blockIdx.x;
  if (bi >= 1600) {
    // ---- LN1: 2 points per block ----
    int t = threadIdx.x;
    int half = t >> 7, c = t & 127;
    int bn = (bi - 1600) * 2 + half;
    const float* row = xin + (size_t)bn * 384;
    float x0 = row[c*3+0], x1 = row[c*3+1], x2 = row[c*3+2];
    float nv = sqrtf(x0*x0 + x1*x1 + x2*x2 + EPSF);
    float s1 = nv, s2 = nv*nv;
#pragma unroll
    for (int off = 32; off >= 1; off >>= 1) {
      s1 += __shfl_down(s1, off);
      s2 += __shfl_down(s2, off);
    }
    int lane = t & 63, w = t >> 6;
    if (lane == 0) { red[w*2] = s1; red[w*2+1] = s2; }
    __syncthreads();
    int rb4 = (w >> 1) * 4;
    float tot1 = red[rb4] + red[rb4+2], tot2 = red[rb4+1] + red[rb4+3];
    float mu  = tot1 * (1.f/128.f);
    float var = tot2 * (1.f/128.f) - mu*mu;
    float rsig = rsqrtf(var + LNEPSF);
    float nnew = g1[c] * ((nv - mu) * rsig) + b1[c];
    float sc = nnew / nv;
    size_t rb = (size_t)bn * 384;
    xbp[rb + c]       = f2bf(x0*sc);
    xbp[rb + 128 + c] = f2bf(x1*sc);
    xbp[rb + 256 + c] = f2bf(x2*sc);
    xdi[rb + c]       = x0;
    xdi[rb + 128 + c] = x1;
    xdi[rb + 256 + c] = x2;
    return;
  }
  int idx = bi * 256 + threadIdx.x;
  if (idx < 212992) {
    int m = idx >> 7, c = idx & 127;
    float val;
    if (m < 384)       val = Wq[m*128 + c] * QSCALE;
    else if (m < 768)  val = Wk[(m-384)*128 + c];
    else if (m < 1152) val = Wv[(m-768)*128 + c];
    else {
      int j = m - 1152;
      if (j < 128)      val = W1[j*256 + c];
      else if (j < 256) val = U1[(j-128)*256 + c];
      else if (j < 384) { int o = j-256; val = W1[o*256 + 128 + c] - W1[o*256 + c]; }
      else              { int o = j-384; val = U1[o*256 + 128 + c] - U1[o*256 + c]; }
    }
    Wall[idx] = f2bf(val); return;
  }
  idx -= 212992;
  if (idx < 49152) {
    int c = idx / 384, j = idx % 384;   // coalesced: j fast -> Wo stride-4B, W2 wave-uniform
    float s = 0.f;
    for (int cp = 0; cp < 128; ++cp) s += W2[c*256 + cp] * Wo[cp*384 + j];
    Af16[(size_t)c*512 + j] = (_Float16)s; return;
  }
  idx -= 49152;
  if (idx < 16384) {
    int c2 = idx / 128, c = idx % 128;
    Af16[(size_t)c*512 + 384 + c2] = (_Float16)W2[c*256 + 128 + c2]; return;
  }
  idx -= 16384;
  if (idx < 32768) { W3h[idx] = (_Float16)W3[idx]; return; }
  idx -= 32768;
  if (idx < 32768) { U3h[idx] = (_Float16)U3[idx]; return; }
  idx -= 32768;
  if (idx < 32768) { W4h[idx] = (_Float16)W4[idx]; return; }
  idx -= 32768;
  if (idx < 32768) { U4h[idx] = (_Float16)U4[idx]; return; }
}

// ---------------- fused QKV + conv1 MFMA GEMM: weight-tile DOUBLE BUFFER ----------------
#define XT_PITCH 132
#define WT_PITCH 132
#define TR_PITCH 36
__global__ __launch_bounds__(256, 2) void qkv_conv1_mfma(
    const ushort_t* __restrict__ xb, const ushort_t* __restrict__ Wall,
    ushort_t* __restrict__ q, ushort_t* __restrict__ k, ushort_t* __restrict__ v,
    _Float16* __restrict__ YZh, _Float16* __restrict__ NBh) {
  __shared__ ushort_t xs[128*XT_PITCH];
  __shared__ ushort_t wt[2][32*WT_PITCH];
  __shared__ float tr[4][32*TR_PITCH];
  int nb = blockIdx.x % 192;
  int mq = blockIdx.x / 192;
  int n0 = nb * 128;
  int t = threadIdx.x;
  int w = t >> 6, lane = t & 63, ql = lane & 31, hl = lane >> 5;
  for (int idx = t; idx < 2048; idx += 256) {
    int n = idx >> 4, c16 = idx & 15;
    bf16x8 gv = *(const bf16x8*)&xb[(size_t)(n0 + n)*128 + c16*8];
    ushort_t* dst = &xs[n*XT_PITCH + c16*8];
    *(bf16x4*)dst = __builtin_shufflevector(gv, gv, 0, 1, 2, 3);
    *(bf16x4*)(dst+4) = __builtin_shufflevector(gv, gv, 4, 5, 6, 7);
  }
  // stage wt[0] (first m-tile)
#pragma unroll
  for (int i = 0; i < 2; ++i) {
    int idx = i*256 + t;
    int mm = idx >> 4, c16 = idx & 15;
    bf16x8 gv = *(const bf16x8*)&Wall[(size_t)(mq*416 + mm)*128 + c16*8];
    ushort_t* dst = &wt[0][mm*WT_PITCH + c16*8];
    *(bf16x4*)dst = __builtin_shufflevector(gv, gv, 0, 1, 2, 3);
    *(bf16x4*)(dst+4) = __builtin_shufflevector(gv, gv, 4, 5, 6, 7);
  }
  __syncthreads();
  bf16x8 xf[8];
  {
    const ushort_t* xr = &xs[(w*32 + ql)*XT_PITCH + hl*8];
#pragma unroll
    for (int cs = 0; cs < 8; ++cs) {
      bf16x4 lo = *(const bf16x4*)(xr + cs*16);
      bf16x4 hi = *(const bf16x4*)(xr + cs*16 + 4);
      xf[cs] = __builtin_shufflevector(lo, hi, 0, 1, 2, 3, 4, 5, 6, 7);
    }
  }
  int ng = n0 + w*32 + ql;
  int pt = ng / 3;
  int d  = ng - 3*pt;
  float* trw = tr[w];
  int mm0 = t >> 4, c160 = t & 15;            // prefetch chunk 0 decode
  int mm1 = (t + 256) >> 4, c161 = t & 15;    // prefetch chunk 1 decode
  for (int mt = 0; mt < 13; ++mt) {
    int m0 = mq*416 + mt*32;
    int cur = mt & 1;
    // prefetch next weight tile into registers (hides under MFMA+epilogue)
    bf16x8 wpre0, wpre1;
    if (mt < 12) {
      int m0n = m0 + 32;
      wpre0 = *(const bf16x8*)&Wall[(size_t)(m0n + mm0)*128 + c160*8];
      wpre1 = *(const bf16x8*)&Wall[(size_t)(m0n + mm1)*128 + c161*8];
    }
    f32x16 acc;
#pragma unroll
    for (int r = 0; r < 16; ++r) acc[r] = 0.f;
    const ushort_t* wr = &wt[cur][ql*WT_PITCH + hl*8];
#pragma unroll
    for (int cs = 0; cs < 8; ++cs) {
      bf16x4 lo = *(const bf16x4*)(wr + cs*16);
      bf16x4 hi = *(const bf16x4*)(wr + cs*16 + 4);
      bf16x8 af = __builtin_shufflevector(lo, hi, 0, 1, 2, 3, 4, 5, 6, 7);
      acc = __builtin_amdgcn_mfma_f32_32x32x16_bf16(af, xf[cs], acc, 0, 0, 0);
    }
#pragma unroll
    for (int r = 0; r < 16; ++r) {
      int mrow = (r&3) + 8*(r>>2) + 4*hl;
      trw[ql*TR_PITCH + mrow] = acc[r];
    }
    asm volatile("s_waitcnt lgkmcnt(0)" ::: "memory");
    float4 c0 = *(float4*)&trw[ql*TR_PITCH + hl*16 + 0];
    float4 c1 = *(float4*)&trw[ql*TR_PITCH + hl*16 + 4];
    float4 c2 = *(float4*)&trw[ql*TR_PITCH + hl*16 + 8];
    float4 c3 = *(float4*)&trw[ql*TR_PITCH + hl*16 + 12];
    asm volatile("s_waitcnt lgkmcnt(0)" ::: "memory");
    int mg = m0 + hl*16;
    if (m0 < 1152) {
      uint4 s0, s1;
      s0.x = pack2(c0.x, c0.y); s0.y = pack2(c0.z, c0.w);
      s0.z = pack2(c1.x, c1.y); s0.w = pack2(c1.z, c1.w);
      s1.x = pack2(c2.x, c2.y); s1.y = pack2(c2.z, c2.w);
      s1.z = pack2(c3.x, c3.y); s1.w = pack2(c3.z, c3.w);
      ushort_t* dst;
      if (m0 < 384)       dst = q + (size_t)pt*1152 + d*384 + mg;
      else if (m0 < 768)  dst = k + (size_t)pt*1152 + d*384 + (mg - 384);
      else                dst = v + (size_t)pt*1152 + d*384 + (mg - 768);
      *(uint4*)dst = s0;
      *(uint4*)(dst + 8) = s1;
    } else {
      int mat = mg - 1152;
      int sub = mat >> 7, o = mat & 127;
      _Float16* basep = (sub < 2) ? YZh : NBh;
      _Float16* dst = basep + (size_t)pt*768 + d*256 + (sub & 1)*128 + o;
      uint4 s0, s1;
      s0.x = packh2(c0.x, c0.y); s0.y = packh2(c0.z, c0.w);
      s0.z = packh2(c1.x, c1.y); s0.w = packh2(c1.z, c1.w);
      s1.x = packh2(c2.x, c2.y); s1.y = packh2(c2.z, c2.w);
      s1.z = packh2(c3.x, c3.y); s1.w = packh2(c3.z, c3.w);
      *(uint4*)dst = s0;
      *(uint4*)(dst + 8) = s1;
    }
    if (mt < 12) {
      int nxt = cur ^ 1;
      ushort_t* d0 = &wt[nxt][mm0*WT_PITCH + c160*8];
      *(bf16x4*)d0 = __builtin_shufflevector(wpre0, wpre0, 0, 1, 2, 3);
      *(bf16x4*)(d0+4) = __builtin_shufflevector(wpre0, wpre0, 4, 5, 6, 7);
      ushort_t* d1 = &wt[nxt][mm1*WT_PITCH + c161*8];
      *(bf16x4*)d1 = __builtin_shufflevector(wpre1, wpre1, 0, 1, 2, 3);
      *(bf16x4*)(d1+4) = __builtin_shufflevector(wpre1, wpre1, 4, 5, 6, 7);
    }
    __syncthreads();
  }
}

// ---------------- fused V-transpose + conv1-post (independent; overlapped in one launch) ----------------
#define VT_LP 196
__global__ __launch_bounds__(256) void post_vtrans(const ushort_t* __restrict__ v,
    ushort_t* __restrict__ vT, const _Float16* __restrict__ YZh,
    const _Float16* __restrict__ NBh, const int* __restrict__ knn_index,
    _Float16* __restrict__ kmf16) {
  __shared__ ushort_t tl[64*VT_LP];   // 25088 B
  __shared__ int sidx[8][KNN];
  int blk = blockIdx.x;
  int t = threadIdx.x;
  if (blk < 768) {
    int bh = blk / 32, ptile = blk % 32;
    int b = bh / HH, h = bh % HH;
    int pt0 = ptile * 64;
#pragma unroll
    for (int i = 0; i < 6; ++i) {
      int u = i*256 + t;
      int p = u / 24, seg = u % 24;
      int d = seg >> 3, c8 = seg & 7;
      bf16x8 gv = *(const bf16x8*)&v[(size_t)(b*NFIX + pt0 + p)*1152 + d*384 + h*64 + c8*8];
      ushort_t* dst = &tl[p*VT_LP + d*64 + c8*8];
      *(bf16x4*)dst = __builtin_shufflevector(gv, gv, 0, 1, 2, 3);
      *(bf16x4*)(dst+4) = __builtin_shufflevector(gv, gv, 4, 5, 6, 7);
    }
    __syncthreads();
#pragma unroll
    for (int i = 0; i < 6; ++i) {
      int u = i*256 + t;
      int ch = u >> 3, pc = u & 7;
      int ol = ch / 3, dd = ch - 3*ol;
      int cloc = dd*64 + ol;
      ushort_t hv[8];
#pragma unroll
      for (int e = 0; e < 8; ++e)
        hv[e] = tl[(pc*8 + e)*VT_LP + cloc];
      uint4 o4;
      o4.x = (uint_t)hv[0] | ((uint_t)hv[1] << 16);
      o4.y = (uint_t)hv[2] | ((uint_t)hv[3] << 16);
      o4.z = (uint_t)hv[4] | ((uint_t)hv[5] << 16);
      o4.w = (uint_t)hv[6] | ((uint_t)hv[7] << 16);
      *(uint4*)&vT[((size_t)bh*192 + ch)*2048 + pt0 + pc*8] = o4;
    }
    return;
  }
  // conv1_post: 8 points per block; threads 0-127 -> pts 0-3, 128-255 -> pts 4-7
  int bnb = (blk - 768) * 8;
  int half = t >> 7, c = t & 127;
  if (t < 64) {
    int pi = t >> 3, kk = t & 7;
    int bn = bnb + pi;
    int b = bn / NFIX, n = bn % NFIX;
    sidx[pi][kk] = knn_index[(b*KNN + kk)*NFIX + n];
  }
  __syncthreads();
#pragma unroll
  for (int pi2 = 0; pi2 < 4; ++pi2) {
    int pi = half*4 + pi2;
    int bn = bnb + pi;
    float yb[3], zb[3];
#pragma unroll
    for (int d = 0; d < 3; ++d) {
      yb[d] = (float)NBh[(size_t)bn*768 + d*256 + c];
      zb[d] = (float)NBh[(size_t)bn*768 + d*256 + 128 + c];
    }
    float om[3] = {0.f, 0.f, 0.f};
#pragma unroll
    for (int kk = 0; kk < KNN; ++kk) {
      const _Float16* r = YZh + (size_t)sidx[pi][kk]*768;
      float p[3], dd[3];
#pragma unroll
      for (int d = 0; d < 3; ++d) {
        p[d]  = (float)r[d*256 + c] + yb[d];
        dd[d] = (float)r[d*256 + 128 + c] + zb[d];
      }
      float res[3];
      vnleaky3(p, dd, res);
      om[0] += res[0]; om[1] += res[1]; om[2] += res[2];
    }
#pragma unroll
    for (int d = 0; d < 3; ++d)
      kmf16[((size_t)bn*3 + d)*128 + c] = (_Float16)(om[d] * (1.f/KNN));
  }
}

// ---------------- attention (round-5 proven version): split-K=2, XCD-grouped decode,
// dual S-MFMA chains, pack2 RNE softmax, V LDS-staged dbuf, f16 O_s epilogue. ----------------
#define KT_P 196
#define VT_P 36
#define TW_P 195
__global__ __launch_bounds__(256, 2) void attn_kernel(const ushort_t* __restrict__ q,
    const ushort_t* __restrict__ k, const ushort_t* __restrict__ vT,
    ushort_t* __restrict__ opart, float* __restrict__ lpart) {
  __shared__ ushort_t kt[2][32*KT_P];
  __shared__ ushort_t vt[2][192*VT_P];
  __shared__ float alds[4][32];
  int blk = blockIdx.x;
  int xcd = blk & 7, j = blk >> 3;          // j in 0..95
  int g = xcd*6 + (j >> 4);                 // 48 groups
  int qt = j & 15;
  int bh = g % 24;
  int split = g / 24;                       // 0..1
  int b = bh / HH, h = bh % HH;
  int t = threadIdx.x;
  int w = t >> 6, lane = t & 63, ql = lane & 31, hl = lane >> 5;
  int qrow0 = qt*128 + w*32;
  const ushort_t* qpb = q + (size_t)(b*NFIX + qrow0 + ql)*1152 + h*64;
  bf16x8 qf[12];
#pragma unroll
  for (int cs = 0; cs < 12; ++cs) {
    int red0 = cs*16 + hl*8;
    int dq = red0 >> 6, ml = red0 & 63;
    qf[cs] = *(const bf16x8*)(qpb + dq*384 + ml);
  }
  const ushort_t* ksrc[3]; int kdsto[3];
  const ushort_t* vsrc[3]; int vdsto[3];
#pragma unroll
  for (int j2 = 0; j2 < 3; ++j2) {
    int idx = t + j2*256;
    int kp = idx / 24, c16 = idx % 24;
    int red0 = c16*8;
    int dk = red0 >> 6, ml = red0 & 63;
    ksrc[j2] = k + (size_t)(b*NFIX + kp)*1152 + dk*384 + h*64 + ml;
    kdsto[j2] = kp*KT_P + c16*8;
    int ch = idx >> 2, c4 = idx & 3;
    vsrc[j2] = vT + ((size_t)bh*192 + ch)*2048 + c4*8;
    vdsto[j2] = ch*VT_P + c4*8;
  }
  f32x16 acc[6];
#pragma unroll
  for (int nt = 0; nt < 6; ++nt)
#pragma unroll
    for (int r = 0; r < 16; ++r) acc[nt][r] = 0.f;
  float lsum = 0.f;
  int koff0 = split * 1024;                 // 1024 keys per split, 32 K-tiles
  bf16x8 kpre[3], vpre[3];
#pragma unroll
  for (int j2 = 0; j2 < 3; ++j2) {
    kpre[j2] = *(const bf16x8*)(ksrc[j2] + (size_t)koff0*1152);
    vpre[j2] = *(const bf16x8*)(vsrc[j2] + koff0);
  }
#pragma unroll
  for (int j2 = 0; j2 < 3; ++j2) {
    ushort_t* kd = &kt[0][kdsto[j2]];
    *(bf16x4*)kd = __builtin_shufflevector(kpre[j2], kpre[j2], 0, 1, 2, 3);
    *(bf16x4*)(kd+4) = __builtin_shufflevector(kpre[j2], kpre[j2], 4, 5, 6, 7);
    ushort_t* vd = &vt[0][vdsto[j2]];
    *(bf16x4*)vd = __builtin_shufflevector(vpre[j2], vpre[j2], 0, 1, 2, 3);
    *(bf16x4*)(vd+4) = __builtin_shufflevector(vpre[j2], vpre[j2], 4, 5, 6, 7);
  }
  __syncthreads();
  for (int kb = 0; kb < 32; ++kb) {
    int cur = kb & 1;
    if (kb < 31) {
      int koff = koff0 + (kb+1)*32;
#pragma unroll
      for (int j2 = 0; j2 < 3; ++j2) {
        kpre[j2] = *(const bf16x8*)(ksrc[j2] + (size_t)koff*1152);
        vpre[j2] = *(const bf16x8*)(vsrc[j2] + koff);
      }
    }
    // dual independent S accumulation chains (6-deep each instead of 12)
    f32x16 sca, scb;
#pragma unroll
    for (int r = 0; r < 16; ++r) { sca[r] = 0.f; scb[r] = 0.f; }
    const ushort_t* ktc = kt[cur];
#pragma unroll
    for (int cs = 0; cs < 12; ++cs) {
      const ushort_t* kr = &ktc[ql*KT_P + cs*16 + hl*8];
      bf16x4 alo = *(const bf16x4*)kr;
      bf16x4 ahi = *(const bf16x4*)(kr + 4);
      bf16x8 af = __builtin_shufflevector(alo, ahi, 0, 1, 2, 3, 4, 5, 6, 7);
      if (cs & 1) scb = __builtin_amdgcn_mfma_f32_32x32x16_bf16(af, qf[cs], scb, 0, 0, 0);
      else        sca = __builtin_amdgcn_mfma_f32_32x32x16_bf16(af, qf[cs], sca, 0, 0, 0);
    }
    uint_t u[8], pex[8];
#pragma unroll
    for (int g2 = 0; g2 < 4; ++g2) {
      float p0 = __builtin_amdgcn_exp2f(sca[g2*4 + 0] + scb[g2*4 + 0]);
      float p1 = __builtin_amdgcn_exp2f(sca[g2*4 + 1] + scb[g2*4 + 1]);
      float p2 = __builtin_amdgcn_exp2f(sca[g2*4 + 2] + scb[g2*4 + 2]);
      float p3 = __builtin_amdgcn_exp2f(sca[g2*4 + 3] + scb[g2*4 + 3]);
      lsum += (p0 + p1) + (p2 + p3);
      u[2*g2]   = pack2(p0, p1);
      u[2*g2+1] = pack2(p2, p3);
    }
#pragma unroll
    for (int j2 = 0; j2 < 8; ++j2) pex[j2] = (uint_t)__shfl_xor((int)u[j2], 32);
    const ushort_t* vtc = vt[cur];
#pragma unroll
    for (int s = 0; s < 2; ++s) {
      uint4 au;
      au.x = hl ? pex[4*s+2] : u[4*s+0];
      au.y = hl ? pex[4*s+3] : u[4*s+1];
      au.z = hl ? u[4*s+2]   : pex[4*s+0];
      au.w = hl ? u[4*s+3]   : pex[4*s+1];
      union { uint4 ui; bf16x8 bv; } cvt; cvt.ui = au;
      bf16x8 pa = cvt.bv;
#pragma unroll
      for (int nt = 0; nt < 6; ++nt) {
        const ushort_t* vr = &vtc[(nt*32 + ql)*VT_P + s*16 + hl*8];
        bf16x4 vlo = *(const bf16x4*)vr;
        bf16x4 vhi = *(const bf16x4*)(vr + 4);
        bf16x8 vf = __builtin_shufflevector(vlo, vhi, 0, 1, 2, 3, 4, 5, 6, 7);
        acc[nt] = __builtin_amdgcn_mfma_f32_32x32x16_bf16(pa, vf, acc[nt], 0, 0, 0);
      }
    }
    if (kb < 31) {
      int nxt = cur ^ 1;
#pragma unroll
      for (int j2 = 0; j2 < 3; ++j2) {
        ushort_t* kd = &kt[nxt][kdsto[j2]];
        *(bf16x4*)kd = __builtin_shufflevector(kpre[j2], kpre[j2], 0, 1, 2, 3);
        *(bf16x4*)(kd+4) = __builtin_shufflevector(kpre[j2], kpre[j2], 4, 5, 6, 7);
        ushort_t* vd = &vt[nxt][vdsto[j2]];
        *(bf16x4*)vd = __builtin_shufflevector(vpre[j2], vpre[j2], 0, 1, 2, 3);
        *(bf16x4*)(vd+4) = __builtin_shufflevector(vpre[j2], vpre[j2], 4, 5, 6, 7);
      }
    }
    __syncthreads();
  }
  lsum += __shfl_xor(lsum, 32);
  if (lane < 32) {
    alds[w][ql] = 1.0f / lsum;
    lpart[(size_t)split*24*NFIX + (size_t)bh*NFIX + qrow0 + ql] = lsum;
  }
  asm volatile("s_waitcnt lgkmcnt(0)" ::: "memory");
  float lv[4][4];
#pragma unroll
  for (int g2 = 0; g2 < 4; ++g2) {
    f32x4 tv = *(const f32x4*)&alds[w][8*g2 + 4*hl];
#pragma unroll
    for (int rr = 0; rr < 4; ++rr) lv[g2][rr] = tv[rr];
  }
  // ---- epilogue: O_s stored as f16 bits (split-combine precision) ----
  ushort_t* tw = (w == 0) ? kt[0] : (w == 1) ? kt[1] : (w == 2) ? vt[0] : vt[1];
#pragma unroll
  for (int nt = 0; nt < 6; ++nt) {
    int ch = nt*32 + ql;
#pragma unroll
    for (int r = 0; r < 16; ++r) {
      int qrow = (r&3) + 8*(r>>2) + 4*hl;
      tw[qrow*TW_P + ch] = f2h_bits(acc[nt][r] * lv[r>>2][r&3]);
    }
  }
  asm volatile("s_waitcnt lgkmcnt(0)" ::: "memory");
  const size_t SS = (size_t)8192*1152;
  ushort_t* opb = opart + (size_t)split*SS;
  size_t nbase = (size_t)(b*NFIX + qrow0) * 3;
#pragma unroll
  for (int i = 0; i < 12; ++i) {
    int chunk = i*64 + lane;
    int nl = chunk >> 3, jc = chunk & 7;
    int qq = nl / 3, dd = nl - 3*qq;
    ushort_t hv[8];
#pragma unroll
    for (int e = 0; e < 8; ++e)
      hv[e] = tw[qq*TW_P + (jc*8 + e)*3 + dd];
    uint4 sv;
    sv.x = (uint_t)hv[0] | ((uint_t)hv[1] << 16);
    sv.y = (uint_t)hv[2] | ((uint_t)hv[3] << 16);
    sv.z = (uint_t)hv[4] | ((uint_t)hv[5] << 16);
    sv.w = (uint_t)hv[6] | ((uint_t)hv[7] << 16);
    *(uint4*)&opb[(nbase + nl)*384 + h*64 + jc*8] = sv;
  }
}

// ---------------- x1mid + LN2 + conv3 + conv4 FULLY FUSED (block-local dependency):
// x1mid block blk covers points [32blk,32blk+32) == conv34 tile blk. nxh hand-off via
// LDS (Phase C -> regs -> Xs3 overlay); conv4 residual (xmid) stashed in 16 regs/thread
// from X before overlay. Eliminates nxh (12.6MB w+r), xmid (25.2MB w+r), one launch.
// 768 thr / 12 waves; conv phases run on waves 0-7 (same 8 active waves as standalone).
#define AP 68
#define XLP 132
#define X3P 132
#define HP4 260
#define TF4P 388
__global__ __launch_bounds__(768) void x1mid_c34(
    const float* __restrict__ xdi, const ushort_t* __restrict__ opart,
    const float* __restrict__ lpart, const _Float16* __restrict__ kmf16,
    const _Float16* __restrict__ Af16, const float* __restrict__ g2,
    const float* __restrict__ b2,
    const _Float16* __restrict__ W3h, const _Float16* __restrict__ U3h,
    const _Float16* __restrict__ W4h, const _Float16* __restrict__ U4h,
    float* __restrict__ out) {
  __shared__ __align__(16) char smem[50944];
  _Float16* As = (_Float16*)smem;                 // 128 x AP = 17408 B
  _Float16* Bt = (_Float16*)(smem + 17408);       //  96 x AP = 13056 B
  float* wlsL  = (float*)(smem + 30464);          //  32 x 6 x 2 = 1536 B
  float* X     = (float*)smem;                    // overlay: 96 x XLP f32 = 50688 B
  float* stats = (float*)(smem + 50688);          // 32 x 2 f32 = 256 B
  _Float16* Xs3 = (_Float16*)smem;                // overlay: 3*32*X3P f16 = 25344 B
  _Float16* H   = (_Float16*)smem;                // overlay: 96 x HP4 f16 = 49920 B
  float* trF    = (float*)smem;                   // overlay: 32 x TF4P f32 = 49664 B
  int blk = blockIdx.x;
  int n0 = blk * 96;
  int pt0 = blk * 32;
  int t = threadIdx.x;
  int w = t >> 6, lane = t & 63, ql = lane & 31, hl = lane >> 5;
  int nsub = w >> 2, mt2 = w & 3;                 // 12 waves: 3 n-subtiles x 4 m-tiles
  if (t < 192) {
    int ptl = t / 6, h = t % 6;
    int ptg = pt0 + ptl;
    int b = ptg >> 11, n = ptg & 2047;
    size_t lidx = (size_t)(b*HH + h)*NFIX + n;
    float l[NSPLIT]; float tot = 0.f;
#pragma unroll
    for (int s = 0; s < NSPLIT; ++s) {
      l[s] = lpart[(size_t)s*24*NFIX + lidx];
      tot += l[s];
    }
    float rd = 1.f / tot;
    float* wp = &wlsL[(ptl*6 + h)*NSPLIT];
#pragma unroll
    for (int s = 0; s < NSPLIT; ++s) wp[s] = l[s]*rd;
  }
  f32x16 acc;
#pragma unroll
  for (int r = 0; r < 16; ++r) acc[r] = 0.f;
  const size_t SS = (size_t)8192*1152;
  __syncthreads();
  for (int p = 0; p < 8; ++p) {
    for (int u = t; u < 1024; u += 768) {
      int m = u >> 3, kc = u & 7;
      f16x4 a0 = *(const f16x4*)&Af16[(size_t)m*512 + p*64 + kc*8];
      f16x4 a1 = *(const f16x4*)&Af16[(size_t)m*512 + p*64 + kc*8 + 4];
      _Float16* dst = &As[m*AP + kc*8];
      *(f16x4*)dst = a0;
      *(f16x4*)(dst+4) = a1;
    }
    {
      // Bt staging: 768 threads = 96 rows x 8 col-chunks of 8 f16
      int n_l = t >> 3, jc = t & 7;
      int n_g = n0 + n_l;
      _Float16* dst = &Bt[n_l*AP + jc*8];
      if (p < 6) {
        int pt_l = n_l / 3;
        const float* wp = &wlsL[(pt_l*6 + p)*NSPLIT];
        float facc[8];
#pragma unroll
        for (int e = 0; e < 8; ++e) facc[e] = 0.f;
#pragma unroll
        for (int s = 0; s < NSPLIT; ++s) {
          const ushort_t* src = opart + s*SS + (size_t)n_g*384 + p*64 + jc*8;
          uint4 ra = *(const uint4*)src;
          const _Float16* ua = (const _Float16*)&ra;
          float wsc = wp[s];
#pragma unroll
          for (int e = 0; e < 8; ++e)
            facc[e] += wsc * (float)ua[e];
        }
        _Float16 hv[8];
#pragma unroll
        for (int e = 0; e < 8; ++e) hv[e] = (_Float16)facc[e];
        *(f16x4*)dst = *(f16x4*)&hv[0];
        *(f16x4*)(dst+4) = *(f16x4*)&hv[4];
      } else {
        const _Float16* src = kmf16 + (size_t)n_g*128 + (p-6)*64 + jc*8;
        f16x4 v0 = *(const f16x4*)src;
        f16x4 v1 = *(const f16x4*)(src + 4);
        *(f16x4*)dst = v0; *(f16x4*)(dst+4) = v1;
      }
    }
    __syncthreads();
#pragma unroll
    for (int cs = 0; cs < 4; ++cs) {
      int kloc = cs*16 + hl*8;
      f16x4 b0 = *(const f16x4*)&Bt[(nsub*32 + ql)*AP + kloc];
      f16x4 b1 = *(const f16x4*)&Bt[(nsub*32 + ql)*AP + kloc + 4];
      f16x8 bf = __builtin_shufflevector(b0, b1, 0, 1, 2, 3, 4, 5, 6, 7);
      int mrow = mt2*32 + ql;
      f16x4 a0 = *(const f16x4*)&As[mrow*AP + kloc];
      f16x4 a1 = *(const f16x4*)&As[mrow*AP + kloc + 4];
      f16x8 af = __builtin_shufflevector(a0, a1, 0, 1, 2, 3, 4, 5, 6, 7);
      acc = __builtin_amdgcn_mfma_f32_32x32x16_f16(af, bf, acc, 0, 0, 0);
    }
    __syncthreads();
  }
  {
    int cbase = mt2*32 + 4*hl;
    float* xrow = &X[(nsub*32 + ql)*XLP];
#pragma unroll
    for (int r = 0; r < 16; ++r) {
      int col = cbase + (r&3) + 8*(r>>2);
      xrow[col] = acc[r];
    }
  }
  __syncthreads();
  // ---- Phase A: add residual (post-residual stays in X; no global xmid) ----
#pragma unroll
  for (int i = 0; i < 2; ++i) {
    int u = i*768 + t;                  // 96 rows x 16 chunks of 8 = 1536
    int row = u >> 4, c0 = (u & 15) * 8;
    float* xp = &X[row*XLP + c0];
    const float* xd = xdi + (size_t)(n0 + row)*128 + c0;
    float4 a0 = *(float4*)xp, a1 = *(float4*)(xp + 4);
    float4 d0 = *(const float4*)xd, d1 = *(const float4*)(xd + 4);
    a0.x += d0.x; a0.y += d0.y; a0.z += d0.z; a0.w += d0.w;
    a1.x += d1.x; a1.y += d1.y; a1.z += d1.z; a1.w += d1.w;
    *(float4*)xp = a0; *(float4*)(xp + 4) = a1;
  }
  __syncthreads();
  // ---- stash conv4 residuals in regs (out-write mapping; X alive until Phase C sync) ----
  float rs[16];
#pragma unroll
  for (int i = 0; i < 4; ++i) {
    int u = i*768 + t;
    int row = u / 96, c4 = u % 96;
#pragma unroll
    for (int e = 0; e < 4; ++e) {
      int col = c4*4 + e;
      int o = col / 3, dd = col - 3*o;
      rs[i*4 + e] = X[(3*row + dd)*XLP + o];
    }
  }
  // ---- Phase B: per-point LN stats (12 waves cover 32 points) ----
  for (int pi = w; pi < 32; pi += 12) {
    int c = lane;
    float a0 = X[(pi*3+0)*XLP + c], a1 = X[(pi*3+1)*XLP + c], a2 = X[(pi*3+2)*XLP + c];
    float e0 = X[(pi*3+0)*XLP + c + 64], e1 = X[(pi*3+1)*XLP + c + 64], e2 = X[(pi*3+2)*XLP + c + 64];
    float nva = sqrtf(a0*a0 + a1*a1 + a2*a2 + EPSF);
    float nvb = sqrtf(e0*e0 + e1*e1 + e2*e2 + EPSF);
    float s1 = nva + nvb;
    float s2 = nva*nva + nvb*nvb;
#pragma unroll
    for (int off = 32; off >= 1; off >>= 1) {
      s1 += __shfl_down(s1, off);
      s2 += __shfl_down(s2, off);
    }
    if (lane == 0) {
      float mu = s1 * (1.f/128.f);
      float var = s2 * (1.f/128.f) - mu*mu;
      stats[pi*2]   = mu;
      stats[pi*2+1] = rsqrtf(var + LNEPSF);
    }
  }
  __syncthreads();
  // ---- Phase C: LN2-normalize into regs (f16 bits; identical rounding to old nxh path) ----
  uint4 svr[2]; int rowr[2], c0r[2];
#pragma unroll
  for (int i = 0; i < 2; ++i) {
    int u = i*768 + t;
    int row = u >> 4, c0 = (u & 15) * 8;
    int pt_l = row / 3;
    float mu = stats[pt_l*2], rsig = stats[pt_l*2+1];
    const float* r0 = &X[(pt_l*3 + 0)*XLP + c0];
    const float* r1 = &X[(pt_l*3 + 1)*XLP + c0];
    const float* r2 = &X[(pt_l*3 + 2)*XLP + c0];
    const float* rd = &X[row*XLP + c0];
    float xv[8];
#pragma unroll
    for (int e = 0; e < 8; ++e) {
      float x0 = r0[e], x1 = r1[e], x2 = r2[e];
      float nv = sqrtf(x0*x0 + x1*x1 + x2*x2 + EPSF);
      float nnew = g2[c0 + e] * ((nv - mu) * rsig) + b2[c0 + e];
      xv[e] = rd[e] * (nnew / nv);
    }
    uint4 sv;
    sv.x = packh2(xv[0], xv[1]); sv.y = packh2(xv[2], xv[3]);
    sv.z = packh2(xv[4], xv[5]); sv.w = packh2(xv[6], xv[7]);
    svr[i] = sv; rowr[i] = row; c0r[i] = c0;
  }
  __syncthreads();   // all X/stats reads done; safe to overlay with Xs3
  // ---- write nxh values into conv3 staging layout (d-plane de-interleave) ----
#pragma unroll
  for (int i = 0; i < 2; ++i) {
    int row = rowr[i];
    int d = row % 3, p = row / 3;
    _Float16* dst = &Xs3[(d*32 + p)*X3P + c0r[i]];
    uint2 lo; lo.x = svr[i].x; lo.y = svr[i].y;
    uint2 hi; hi.x = svr[i].z; hi.y = svr[i].w;
    *(uint2*)dst = lo;
    *(uint2*)(dst + 4) = hi;
  }
  __syncthreads();
  // ---- conv3 phase (waves 0-7): o-tile ot3 = w*32, all 3 d-planes in-register ----
  f32x16 accP[3], accD[3];
  int ot3 = w*32;
  if (w < 8) {
#pragma unroll
    for (int d = 0; d < 3; ++d)
#pragma unroll
      for (int r = 0; r < 16; ++r) { accP[d][r] = 0.f; accD[d][r] = 0.f; }
    const _Float16* Wp = W3h + (size_t)(ot3 + ql)*128 + hl*8;
    const _Float16* Up = U3h + (size_t)(ot3 + ql)*128 + hl*8;
#pragma unroll
    for (int cs = 0; cs < 8; ++cs) {
      f16x8 wf = *(const f16x8*)(Wp + cs*16);
      f16x8 uf = *(const f16x8*)(Up + cs*16);
#pragma unroll
      for (int d = 0; d < 3; ++d) {
        const _Float16* xr = &Xs3[(d*32 + ql)*X3P + cs*16 + hl*8];
        f16x4 lo = *(const f16x4*)xr;
        f16x4 hi = *(const f16x4*)(xr + 4);
        f16x8 xf = __builtin_shufflevector(lo, hi, 0, 1, 2, 3, 4, 5, 6, 7);
        accP[d] = __builtin_amdgcn_mfma_f32_32x32x16_f16(wf, xf, accP[d], 0, 0, 0);
        accD[d] = __builtin_amdgcn_mfma_f32_32x32x16_f16(uf, xf, accD[d], 0, 0, 0);
      }
    }
  }
  __syncthreads();   // all Xs3 reads done; safe to overlay with H
  if (w < 8) {
#pragma unroll
    for (int r = 0; r < 16; ++r) {
      int olr = (r&3) + 8*(r>>2) + 4*hl;
      float p3[3], d3[3], res[3];
#pragma unroll
      for (int d = 0; d < 3; ++d) { p3[d] = accP[d][r]; d3[d] = accD[d][r]; }
      vnleaky3(p3, d3, res);
#pragma unroll
      for (int d = 0; d < 3; ++d)
        H[(d*32 + ql)*HP4 + ot3 + olr] = (_Float16)res[d];
    }
  }
  __syncthreads();
  // ---- conv4 phase (waves 0-7): ph=w>>2 point-half, ot4=(w&3)*32 ----
  int ph = w >> 2;
  int ot4 = (w & 3) * 32;
  int nl = lane & 15, kq = lane >> 4;
  f32x4 acc4P[2][3], acc4D[2][3];
  if (w < 8) {
#pragma unroll
    for (int mt = 0; mt < 2; ++mt)
#pragma unroll
      for (int d = 0; d < 3; ++d)
#pragma unroll
        for (int r = 0; r < 4; ++r) { acc4P[mt][d][r] = 0.f; acc4D[mt][d][r] = 0.f; }
    const _Float16* Wb = W4h + (size_t)ot4*256;
    const _Float16* Ub = U4h + (size_t)ot4*256;
#pragma unroll
    for (int cs = 0; cs < 8; ++cs) {
      int kof = cs*32 + kq*8;
      f16x8 xf[3];
#pragma unroll
      for (int d = 0; d < 3; ++d) {
        const _Float16* xr = &H[(d*32 + ph*16 + nl)*HP4 + kof];
        f16x4 lo = *(const f16x4*)xr;
        f16x4 hi = *(const f16x4*)(xr + 4);
        xf[d] = __builtin_shufflevector(lo, hi, 0, 1, 2, 3, 4, 5, 6, 7);
      }
#pragma unroll
      for (int mt = 0; mt < 2; ++mt) {
        f16x8 wf = *(const f16x8*)(Wb + (size_t)(mt*16 + nl)*256 + kof);
        f16x8 uf = *(const f16x8*)(Ub + (size_t)(mt*16 + nl)*256 + kof);
#pragma unroll
        for (int d = 0; d < 3; ++d) {
          acc4P[mt][d] = __builtin_amdgcn_mfma_f32_16x16x32_f16(wf, xf[d], acc4P[mt][d], 0, 0, 0);
          acc4D[mt][d] = __builtin_amdgcn_mfma_f32_16x16x32_f16(uf, xf[d], acc4D[mt][d], 0, 0, 0);
        }
      }
    }
  }
  __syncthreads();   // all H reads done; safe to overlay with trF
  if (w < 8) {
#pragma unroll
    for (int mt = 0; mt < 2; ++mt)
#pragma unroll
      for (int r = 0; r < 4; ++r) {
        int o = ot4 + mt*16 + kq*4 + r;
        int p_l = ph*16 + nl;
        float p3[3], d3[3], res[3];
#pragma unroll
        for (int d = 0; d < 3; ++d) { p3[d] = acc4P[mt][d][r]; d3[d] = acc4D[mt][d][r]; }
        vnleaky3(p3, d3, res);
#pragma unroll
        for (int d = 0; d < 3; ++d) trF[p_l*TF4P + o*3 + d] = res[d];
      }
  }
  __syncthreads();
  // ---- out-write: 32 rows x 384 f32, + stashed residuals (all 768 threads) ----
#pragma unroll
  for (int i = 0; i < 4; ++i) {
    int u = i*768 + t;
    int row = u / 96, c4 = u % 96;
    float4 vv = *(float4*)&trF[row*TF4P + c4*4];
    int bn = pt0 + row;
    float4 ov;
    ov.x = vv.x + rs[i*4 + 0];
    ov.y = vv.y + rs[i*4 + 1];
    ov.z = vv.z + rs[i*4 + 2];
    ov.w = vv.w + rs[i*4 + 3];
    *(float4*)&out[(size_t)bn*384 + c4*4] = ov;
  }
}

extern "C" void kernel_launch(void* const* d_in, const int* in_sizes, int n_in,
                              void* d_out, int out_size, void* d_ws, size_t ws_size,
                              hipStream_t stream) {
  const float* x   = (const float*)d_in[0];
  const int* knn   = (const int*)d_in[1];
  const float* g1  = (const float*)d_in[2];
  const float* b1  = (const float*)d_in[3];
  const float* g2  = (const float*)d_in[4];
  const float* b2  = (const float*)d_in[5];
  const float* Wq  = (const float*)d_in[6];
  const float* Wk  = (const float*)d_in[7];
  const float* Wv  = (const float*)d_in[8];
  const float* Wo  = (const float*)d_in[9];
  const float* W1  = (const float*)d_in[10];
  const float* U1  = (const float*)d_in[11];
  const float* W2  = (const float*)d_in[12];
  const float* W3  = (const float*)d_in[13];
  const float* U3  = (const float*)d_in[14];
  const float* W4  = (const float*)d_in[15];
  const float* U4  = (const float*)d_in[16];
  float* out = (float*)d_out;
  (void)n_in; (void)out_size; (void)ws_size;

  const size_t BN = (size_t)in_sizes[0] / 384;   // 8192

  float* ws    = (float*)d_ws;
  float* xdi   = ws;                          // BN*384 f32 (raw x, de-interleaved [n][c])
  float* xmid  = xdi + BN*384;                // (region unused after fusion)
  _Float16* kmf16 = (_Float16*)(xmid + BN*384);  // BN*384 fp16 [n][128]
  ushort_t* xbp = (ushort_t*)(kmf16 + BN*384);   // BN*384 bf16 (LN1 normalized, de-interleaved)
  ushort_t* qb = xbp + BN*384;                // BN*1152 bf16
  ushort_t* kb = qb + BN*1152;
  ushort_t* vb = kb + BN*1152;
  ushort_t* vT = vb + BN*1152;
  ushort_t* Wall = vT + BN*1152;              // 212992 bf16
  _Float16* Af16 = (_Float16*)(Wall + 212992);   // 65536 fp16
  _Float16* W3h = Af16 + 65536;               // 32768 fp16
  _Float16* U3h = W3h + 32768;
  _Float16* W4h = U3h + 32768;
  _Float16* U4h = W4h + 32768;
  ushort_t* opart = (ushort_t*)(U4h + 32768); // region 4*BN*1152 (2 splits used)
  float* lpart = (float*)(opart + 4*BN*1152); // 2*24*2048 f32
  // YZh/NBh (BN*768 f16 each = 12.6 MB) alias the opart region: conv1_post runs before attn.
  _Float16* YZh = (_Float16*)opart;
  _Float16* NBh = YZh + BN*768;

  prep_ln1<<<1600 + 4096, 256, 0, stream>>>(Wq, Wk, Wv, Wo, W1, U1, W2, W3, U3, W4, U4,
                                            Wall, Af16, W3h, U3h, W4h, U4h,
                                            x, xbp, xdi, g1, b1);
  qkv_conv1_mfma<<<192*4, 256, 0, stream>>>(xbp, Wall, qb, kb, vb, YZh, NBh);
  post_vtrans<<<768 + 1024, 256, 0, stream>>>(vb, vT, YZh, NBh, knn, kmf16);
  attn_kernel<<<16*24*NSPLIT, 256, 0, stream>>>(qb, kb, vT, opart, lpart);
  x1mid_c34<<<256, 768, 0, stream>>>(xdi, opart, lpart, kmf16, Af16, g2, b2,
                                     W3h, U3h, W4h, U4h, out);
}

// Round 14
// 282.416 us; speedup vs baseline: 1.4011x; 1.0432x over previous
//
#include <hip/hip_runtime.h>
#include <math.h>

// Problem constants (fixed by setup_inputs): B=4, N=2048, C=128, H=6, K=8
#define NFIX 2048
#define HH 6
#define KNN 8
#define NSLOPE 0.2f
#define EPSF 1e-6f
#define LNEPSF 1e-5f
// 0.125 (softmax scale) * log2(e), folded into Wq rows so S-MFMA output is exp2-ready
#define QSCALE 0.18033688011112042f
#define NSPLIT 2

typedef unsigned short ushort_t;
typedef unsigned int uint_t;
typedef __attribute__((ext_vector_type(8))) short bf16x8;
typedef __attribute__((ext_vector_type(4))) short bf16x4;
typedef __attribute__((ext_vector_type(8))) _Float16 f16x8;
typedef __attribute__((ext_vector_type(4))) _Float16 f16x4;
typedef __attribute__((ext_vector_type(16))) float f32x16;
typedef __attribute__((ext_vector_type(4))) float f32x4;

__device__ __forceinline__ ushort_t f2bf(float f) {
  union { float f; unsigned u; } v; v.f = f;
  unsigned r = v.u + 0x7fff + ((v.u >> 16) & 1);   // RNE
  return (ushort_t)(r >> 16);
}
__device__ __forceinline__ float bf2f(ushort_t u) {
  union { uint_t u; float f; } v; v.u = ((uint_t)u) << 16; return v.f;
}
__device__ __forceinline__ uint_t pack2(float a, float b) {
  return (uint_t)f2bf(a) | ((uint_t)f2bf(b) << 16);
}
// f32 -> f16 bit pattern (register-only)
__device__ __forceinline__ ushort_t f2h_bits(float a) {
  union { _Float16 h; ushort_t s; } cv; cv.h = (_Float16)a; return cv.s;
}
// pack two fp32 -> two f16 in one dword (register-only; no local-array aliasing)
__device__ __forceinline__ uint_t packh2(float a, float b) {
  union { _Float16 h; ushort_t s; } ha, hb;
  ha.h = (_Float16)a; hb.h = (_Float16)b;
  return (uint_t)ha.s | ((uint_t)hb.s << 16);
}

__device__ __forceinline__ void vnleaky3(const float* p, const float* dv, float* out) {
  float dot = p[0]*dv[0] + p[1]*dv[1] + p[2]*dv[2];
  float dsq = dv[0]*dv[0] + dv[1]*dv[1] + dv[2]*dv[2] + EPSF;
  float f = dot / dsq;
#pragma unroll
  for (int d = 0; d < 3; ++d) {
    float neg = p[d] - f * dv[d];
    out[d] = NSLOPE * p[d] + (1.f - NSLOPE) * ((dot >= 0.f) ? p[d] : neg);
  }
}

// ---------------- fused weight prep + LN1 (independent work; overlapped in one launch) ----------------
__global__ __launch_bounds__(256) void prep_ln1(
    const float* __restrict__ Wq, const float* __restrict__ Wk,
    const float* __restrict__ Wv, const float* __restrict__ Wo,
    const float* __restrict__ W1, const float* __restrict__ U1,
    const float* __restrict__ W2, const float* __restrict__ W3,
    const float* __restrict__ U3, const float* __restrict__ W4,
    const float* __restrict__ U4,
    ushort_t* __restrict__ Wall, _Float16* __restrict__ Af16,
    _Float16* __restrict__ W3h, _Float16* __restrict__ U3h,
    _Float16* __restrict__ W4h, _Float16* __restrict__ U4h,
    const float* __restrict__ xin, ushort_t* __restrict__ xbp,
    float* __restrict__ xdi, const float* __restrict__ g1,
    const float* __restrict__ b1) {
  __shared__ float red[8];
  int bi = blockIdx.x;
  if (bi >= 1600) {
    // ---- LN1: 2 points per block ----
    int t = threadIdx.x;
    int half = t >> 7, c = t & 127;
    int bn = (bi - 1600) * 2 + half;
    const float* row = xin + (size_t)bn * 384;
    float x0 = row[c*3+0], x1 = row[c*3+1], x2 = row[c*3+2];
    float nv = sqrtf(x0*x0 + x1*x1 + x2*x2 + EPSF);
    float s1 = nv, s2 = nv*nv;
#pragma unroll
    for (int off = 32; off >= 1; off >>= 1) {
      s1 += __shfl_down(s1, off);
      s2 += __shfl_down(s2, off);
    }
    int lane = t & 63, w = t >> 6;
    if (lane == 0) { red[w*2] = s1; red[w*2+1] = s2; }
    __syncthreads();
    int rb4 = (w >> 1) * 4;
    float tot1 = red[rb4] + red[rb4+2], tot2 = red[rb4+1] + red[rb4+3];
    float mu  = tot1 * (1.f/128.f);
    float var = tot2 * (1.f/128.f) - mu*mu;
    float rsig = rsqrtf(var + LNEPSF);
    float nnew = g1[c] * ((nv - mu) * rsig) + b1[c];
    float sc = nnew / nv;
    size_t rb = (size_t)bn * 384;
    xbp[rb + c]       = f2bf(x0*sc);
    xbp[rb + 128 + c] = f2bf(x1*sc);
    xbp[rb + 256 + c] = f2bf(x2*sc);
    xdi[rb + c]       = x0;
    xdi[rb + 128 + c] = x1;
    xdi[rb + 256 + c] = x2;
    return;
  }
  int idx = bi * 256 + threadIdx.x;
  if (idx < 212992) {
    int m = idx >> 7, c = idx & 127;
    float val;
    if (m < 384)       val = Wq[m*128 + c] * QSCALE;
    else if (m < 768)  val = Wk[(m-384)*128 + c];
    else if (m < 1152) val = Wv[(m-768)*128 + c];
    else {
      int j = m - 1152;
      if (j < 128)      val = W1[j*256 + c];
      else if (j < 256) val = U1[(j-128)*256 + c];
      else if (j < 384) { int o = j-256; val = W1[o*256 + 128 + c] - W1[o*256 + c]; }
      else              { int o = j-384; val = U1[o*256 + 128 + c] - U1[o*256 + c]; }
    }
    Wall[idx] = f2bf(val); return;
  }
  idx -= 212992;
  if (idx < 49152) {
    int c = idx / 384, j = idx % 384;   // coalesced: j fast -> Wo stride-4B, W2 wave-uniform
    float s = 0.f;
    for (int cp = 0; cp < 128; ++cp) s += W2[c*256 + cp] * Wo[cp*384 + j];
    Af16[(size_t)c*512 + j] = (_Float16)s; return;
  }
  idx -= 49152;
  if (idx < 16384) {
    int c2 = idx / 128, c = idx % 128;
    Af16[(size_t)c*512 + 384 + c2] = (_Float16)W2[c*256 + 128 + c2]; return;
  }
  idx -= 16384;
  if (idx < 32768) { W3h[idx] = (_Float16)W3[idx]; return; }
  idx -= 32768;
  if (idx < 32768) { U3h[idx] = (_Float16)U3[idx]; return; }
  idx -= 32768;
  if (idx < 32768) { W4h[idx] = (_Float16)W4[idx]; return; }
  idx -= 32768;
  if (idx < 32768) { U4h[idx] = (_Float16)U4[idx]; return; }
}

// ---------------- fused QKV + conv1 MFMA GEMM: weight-tile DOUBLE BUFFER ----------------
#define XT_PITCH 132
#define WT_PITCH 132
#define TR_PITCH 36
__global__ __launch_bounds__(256, 2) void qkv_conv1_mfma(
    const ushort_t* __restrict__ xb, const ushort_t* __restrict__ Wall,
    ushort_t* __restrict__ q, ushort_t* __restrict__ k, ushort_t* __restrict__ v,
    _Float16* __restrict__ YZh, _Float16* __restrict__ NBh) {
  __shared__ ushort_t xs[128*XT_PITCH];
  __shared__ ushort_t wt[2][32*WT_PITCH];
  __shared__ float tr[4][32*TR_PITCH];
  int nb = blockIdx.x % 192;
  int mq = blockIdx.x / 192;
  int n0 = nb * 128;
  int t = threadIdx.x;
  int w = t >> 6, lane = t & 63, ql = lane & 31, hl = lane >> 5;
  for (int idx = t; idx < 2048; idx += 256) {
    int n = idx >> 4, c16 = idx & 15;
    bf16x8 gv = *(const bf16x8*)&xb[(size_t)(n0 + n)*128 + c16*8];
    ushort_t* dst = &xs[n*XT_PITCH + c16*8];
    *(bf16x4*)dst = __builtin_shufflevector(gv, gv, 0, 1, 2, 3);
    *(bf16x4*)(dst+4) = __builtin_shufflevector(gv, gv, 4, 5, 6, 7);
  }
  // stage wt[0] (first m-tile)
#pragma unroll
  for (int i = 0; i < 2; ++i) {
    int idx = i*256 + t;
    int mm = idx >> 4, c16 = idx & 15;
    bf16x8 gv = *(const bf16x8*)&Wall[(size_t)(mq*416 + mm)*128 + c16*8];
    ushort_t* dst = &wt[0][mm*WT_PITCH + c16*8];
    *(bf16x4*)dst = __builtin_shufflevector(gv, gv, 0, 1, 2, 3);
    *(bf16x4*)(dst+4) = __builtin_shufflevector(gv, gv, 4, 5, 6, 7);
  }
  __syncthreads();
  bf16x8 xf[8];
  {
    const ushort_t* xr = &xs[(w*32 + ql)*XT_PITCH + hl*8];
#pragma unroll
    for (int cs = 0; cs < 8; ++cs) {
      bf16x4 lo = *(const bf16x4*)(xr + cs*16);
      bf16x4 hi = *(const bf16x4*)(xr + cs*16 + 4);
      xf[cs] = __builtin_shufflevector(lo, hi, 0, 1, 2, 3, 4, 5, 6, 7);
    }
  }
  int ng = n0 + w*32 + ql;
  int pt = ng / 3;
  int d  = ng - 3*pt;
  float* trw = tr[w];
  int mm0 = t >> 4, c160 = t & 15;            // prefetch chunk 0 decode
  int mm1 = (t + 256) >> 4, c161 = t & 15;    // prefetch chunk 1 decode
  for (int mt = 0; mt < 13; ++mt) {
    int m0 = mq*416 + mt*32;
    int cur = mt & 1;
    // prefetch next weight tile into registers (hides under MFMA+epilogue)
    bf16x8 wpre0, wpre1;
    if (mt < 12) {
      int m0n = m0 + 32;
      wpre0 = *(const bf16x8*)&Wall[(size_t)(m0n + mm0)*128 + c160*8];
      wpre1 = *(const bf16x8*)&Wall[(size_t)(m0n + mm1)*128 + c161*8];
    }
    f32x16 acc;
#pragma unroll
    for (int r = 0; r < 16; ++r) acc[r] = 0.f;
    const ushort_t* wr = &wt[cur][ql*WT_PITCH + hl*8];
#pragma unroll
    for (int cs = 0; cs < 8; ++cs) {
      bf16x4 lo = *(const bf16x4*)(wr + cs*16);
      bf16x4 hi = *(const bf16x4*)(wr + cs*16 + 4);
      bf16x8 af = __builtin_shufflevector(lo, hi, 0, 1, 2, 3, 4, 5, 6, 7);
      acc = __builtin_amdgcn_mfma_f32_32x32x16_bf16(af, xf[cs], acc, 0, 0, 0);
    }
#pragma unroll
    for (int r = 0; r < 16; ++r) {
      int mrow = (r&3) + 8*(r>>2) + 4*hl;
      trw[ql*TR_PITCH + mrow] = acc[r];
    }
    asm volatile("s_waitcnt lgkmcnt(0)" ::: "memory");
    float4 c0 = *(float4*)&trw[ql*TR_PITCH + hl*16 + 0];
    float4 c1 = *(float4*)&trw[ql*TR_PITCH + hl*16 + 4];
    float4 c2 = *(float4*)&trw[ql*TR_PITCH + hl*16 + 8];
    float4 c3 = *(float4*)&trw[ql*TR_PITCH + hl*16 + 12];
    asm volatile("s_waitcnt lgkmcnt(0)" ::: "memory");
    int mg = m0 + hl*16;
    if (m0 < 1152) {
      uint4 s0, s1;
      s0.x = pack2(c0.x, c0.y); s0.y = pack2(c0.z, c0.w);
      s0.z = pack2(c1.x, c1.y); s0.w = pack2(c1.z, c1.w);
      s1.x = pack2(c2.x, c2.y); s1.y = pack2(c2.z, c2.w);
      s1.z = pack2(c3.x, c3.y); s1.w = pack2(c3.z, c3.w);
      ushort_t* dst;
      if (m0 < 384)       dst = q + (size_t)pt*1152 + d*384 + mg;
      else if (m0 < 768)  dst = k + (size_t)pt*1152 + d*384 + (mg - 384);
      else                dst = v + (size_t)pt*1152 + d*384 + (mg - 768);
      *(uint4*)dst = s0;
      *(uint4*)(dst + 8) = s1;
    } else {
      int mat = mg - 1152;
      int sub = mat >> 7, o = mat & 127;
      _Float16* basep = (sub < 2) ? YZh : NBh;
      _Float16* dst = basep + (size_t)pt*768 + d*256 + (sub & 1)*128 + o;
      uint4 s0, s1;
      s0.x = packh2(c0.x, c0.y); s0.y = packh2(c0.z, c0.w);
      s0.z = packh2(c1.x, c1.y); s0.w = packh2(c1.z, c1.w);
      s1.x = packh2(c2.x, c2.y); s1.y = packh2(c2.z, c2.w);
      s1.z = packh2(c3.x, c3.y); s1.w = packh2(c3.z, c3.w);
      *(uint4*)dst = s0;
      *(uint4*)(dst + 8) = s1;
    }
    if (mt < 12) {
      int nxt = cur ^ 1;
      ushort_t* d0 = &wt[nxt][mm0*WT_PITCH + c160*8];
      *(bf16x4*)d0 = __builtin_shufflevector(wpre0, wpre0, 0, 1, 2, 3);
      *(bf16x4*)(d0+4) = __builtin_shufflevector(wpre0, wpre0, 4, 5, 6, 7);
      ushort_t* d1 = &wt[nxt][mm1*WT_PITCH + c161*8];
      *(bf16x4*)d1 = __builtin_shufflevector(wpre1, wpre1, 0, 1, 2, 3);
      *(bf16x4*)(d1+4) = __builtin_shufflevector(wpre1, wpre1, 4, 5, 6, 7);
    }
    __syncthreads();
  }
}

// ---------------- V transpose (768 blocks; conv1_post moved into attn launch as tail filler) ----------------
#define VT_LP 196
__global__ __launch_bounds__(256) void vtrans_kernel(const ushort_t* __restrict__ v,
    ushort_t* __restrict__ vT) {
  __shared__ ushort_t tl[64*VT_LP];   // 25088 B
  int blk = blockIdx.x;
  int t = threadIdx.x;
  int bh = blk / 32, ptile = blk % 32;
  int b = bh / HH, h = bh % HH;
  int pt0 = ptile * 64;
#pragma unroll
  for (int i = 0; i < 6; ++i) {
    int u = i*256 + t;
    int p = u / 24, seg = u % 24;
    int d = seg >> 3, c8 = seg & 7;
    bf16x8 gv = *(const bf16x8*)&v[(size_t)(b*NFIX + pt0 + p)*1152 + d*384 + h*64 + c8*8];
    ushort_t* dst = &tl[p*VT_LP + d*64 + c8*8];
    *(bf16x4*)dst = __builtin_shufflevector(gv, gv, 0, 1, 2, 3);
    *(bf16x4*)(dst+4) = __builtin_shufflevector(gv, gv, 4, 5, 6, 7);
  }
  __syncthreads();
#pragma unroll
  for (int i = 0; i < 6; ++i) {
    int u = i*256 + t;
    int ch = u >> 3, pc = u & 7;
    int ol = ch / 3, dd = ch - 3*ol;
    int cloc = dd*64 + ol;
    ushort_t hv[8];
#pragma unroll
    for (int e = 0; e < 8; ++e)
      hv[e] = tl[(pc*8 + e)*VT_LP + cloc];
    uint4 o4;
    o4.x = (uint_t)hv[0] | ((uint_t)hv[1] << 16);
    o4.y = (uint_t)hv[2] | ((uint_t)hv[3] << 16);
    o4.z = (uint_t)hv[4] | ((uint_t)hv[5] << 16);
    o4.w = (uint_t)hv[6] | ((uint_t)hv[7] << 16);
    *(uint4*)&vT[((size_t)bh*192 + ch)*2048 + pt0 + pc*8] = o4;
  }
}

// ---------------- attention + conv1_post tail-filler:
// blocks [0,768): round-5-proven attn (split-K=2, XCD-grouped decode, dual S-chains,
// pack2 RNE softmax, V LDS-staged dbuf, f16 O_s epilogue).
// blocks [768, 768+1024): conv1_post (ready before attn: reads YZh/NBh from qkv, knn;
// writes kmf16 consumed only after this launch). These blocks dispatch as attn's 1.5
// occupancy-rounds drain, filling the tail. YZh/NBh moved to opart splits-2/3 region
// (unused) so attn's opart writes (splits 0/1) CANNOT race conv reads. ----------------
#define KT_P 196
#define VT_P 36
#define TW_P 195
__global__ __launch_bounds__(256, 2) void attn_kernel(const ushort_t* __restrict__ q,
    const ushort_t* __restrict__ k, const ushort_t* __restrict__ vT,
    ushort_t* __restrict__ opart, float* __restrict__ lpart,
    const _Float16* __restrict__ YZh, const _Float16* __restrict__ NBh,
    const int* __restrict__ knn_index, _Float16* __restrict__ kmf16) {
  __shared__ ushort_t kt[2][32*KT_P];
  __shared__ ushort_t vt[2][192*VT_P];
  __shared__ float alds[4][32];
  __shared__ int sidx[8][KNN];
  int blk = blockIdx.x;
  int t = threadIdx.x;
  if (blk >= 768) {
    // ---- conv1_post: 8 points per block; threads 0-127 -> pts 0-3, 128-255 -> pts 4-7 ----
    int bnb = (blk - 768) * 8;
    int half = t >> 7, c = t & 127;
    if (t < 64) {
      int pi = t >> 3, kk = t & 7;
      int bn = bnb + pi;
      int b = bn / NFIX, n = bn % NFIX;
      sidx[pi][kk] = knn_index[(b*KNN + kk)*NFIX + n];
    }
    __syncthreads();
#pragma unroll
    for (int pi2 = 0; pi2 < 4; ++pi2) {
      int pi = half*4 + pi2;
      int bn = bnb + pi;
      float yb[3], zb[3];
#pragma unroll
      for (int d = 0; d < 3; ++d) {
        yb[d] = (float)NBh[(size_t)bn*768 + d*256 + c];
        zb[d] = (float)NBh[(size_t)bn*768 + d*256 + 128 + c];
      }
      float om[3] = {0.f, 0.f, 0.f};
#pragma unroll
      for (int kk = 0; kk < KNN; ++kk) {
        const _Float16* r = YZh + (size_t)sidx[pi][kk]*768;
        float p[3], dd[3];
#pragma unroll
        for (int d = 0; d < 3; ++d) {
          p[d]  = (float)r[d*256 + c] + yb[d];
          dd[d] = (float)r[d*256 + 128 + c] + zb[d];
        }
        float res[3];
        vnleaky3(p, dd, res);
        om[0] += res[0]; om[1] += res[1]; om[2] += res[2];
      }
#pragma unroll
      for (int d = 0; d < 3; ++d)
        kmf16[((size_t)bn*3 + d)*128 + c] = (_Float16)(om[d] * (1.f/KNN));
    }
    return;
  }
  // ---- attention path (blk < 768) ----
  int xcd = blk & 7, j = blk >> 3;          // j in 0..95
  int g = xcd*6 + (j >> 4);                 // 48 groups
  int qt = j & 15;
  int bh = g % 24;
  int split = g / 24;                       // 0..1
  int b = bh / HH, h = bh % HH;
  int w = t >> 6, lane = t & 63, ql = lane & 31, hl = lane >> 5;
  int qrow0 = qt*128 + w*32;
  const ushort_t* qpb = q + (size_t)(b*NFIX + qrow0 + ql)*1152 + h*64;
  bf16x8 qf[12];
#pragma unroll
  for (int cs = 0; cs < 12; ++cs) {
    int red0 = cs*16 + hl*8;
    int dq = red0 >> 6, ml = red0 & 63;
    qf[cs] = *(const bf16x8*)(qpb + dq*384 + ml);
  }
  const ushort_t* ksrc[3]; int kdsto[3];
  const ushort_t* vsrc[3]; int vdsto[3];
#pragma unroll
  for (int j2 = 0; j2 < 3; ++j2) {
    int idx = t + j2*256;
    int kp = idx / 24, c16 = idx % 24;
    int red0 = c16*8;
    int dk = red0 >> 6, ml = red0 & 63;
    ksrc[j2] = k + (size_t)(b*NFIX + kp)*1152 + dk*384 + h*64 + ml;
    kdsto[j2] = kp*KT_P + c16*8;
    int ch = idx >> 2, c4 = idx & 3;
    vsrc[j2] = vT + ((size_t)bh*192 + ch)*2048 + c4*8;
    vdsto[j2] = ch*VT_P + c4*8;
  }
  f32x16 acc[6];
#pragma unroll
  for (int nt = 0; nt < 6; ++nt)
#pragma unroll
    for (int r = 0; r < 16; ++r) acc[nt][r] = 0.f;
  float lsum = 0.f;
  int koff0 = split * 1024;                 // 1024 keys per split, 32 K-tiles
  bf16x8 kpre[3], vpre[3];
#pragma unroll
  for (int j2 = 0; j2 < 3; ++j2) {
    kpre[j2] = *(const bf16x8*)(ksrc[j2] + (size_t)koff0*1152);
    vpre[j2] = *(const bf16x8*)(vsrc[j2] + koff0);
  }
#pragma unroll
  for (int j2 = 0; j2 < 3; ++j2) {
    ushort_t* kd = &kt[0][kdsto[j2]];
    *(bf16x4*)kd = __builtin_shufflevector(kpre[j2], kpre[j2], 0, 1, 2, 3);
    *(bf16x4*)(kd+4) = __builtin_shufflevector(kpre[j2], kpre[j2], 4, 5, 6, 7);
    ushort_t* vd = &vt[0][vdsto[j2]];
    *(bf16x4*)vd = __builtin_shufflevector(vpre[j2], vpre[j2], 0, 1, 2, 3);
    *(bf16x4*)(vd+4) = __builtin_shufflevector(vpre[j2], vpre[j2], 4, 5, 6, 7);
  }
  __syncthreads();
  for (int kb = 0; kb < 32; ++kb) {
    int cur = kb & 1;
    if (kb < 31) {
      int koff = koff0 + (kb+1)*32;
#pragma unroll
      for (int j2 = 0; j2 < 3; ++j2) {
        kpre[j2] = *(const bf16x8*)(ksrc[j2] + (size_t)koff*1152);
        vpre[j2] = *(const bf16x8*)(vsrc[j2] + koff);
      }
    }
    // dual independent S accumulation chains (6-deep each instead of 12)
    f32x16 sca, scb;
#pragma unroll
    for (int r = 0; r < 16; ++r) { sca[r] = 0.f; scb[r] = 0.f; }
    const ushort_t* ktc = kt[cur];
#pragma unroll
    for (int cs = 0; cs < 12; ++cs) {
      const ushort_t* kr = &ktc[ql*KT_P + cs*16 + hl*8];
      bf16x4 alo = *(const bf16x4*)kr;
      bf16x4 ahi = *(const bf16x4*)(kr + 4);
      bf16x8 af = __builtin_shufflevector(alo, ahi, 0, 1, 2, 3, 4, 5, 6, 7);
      if (cs & 1) scb = __builtin_amdgcn_mfma_f32_32x32x16_bf16(af, qf[cs], scb, 0, 0, 0);
      else        sca = __builtin_amdgcn_mfma_f32_32x32x16_bf16(af, qf[cs], sca, 0, 0, 0);
    }
    uint_t u[8], pex[8];
#pragma unroll
    for (int g2 = 0; g2 < 4; ++g2) {
      float p0 = __builtin_amdgcn_exp2f(sca[g2*4 + 0] + scb[g2*4 + 0]);
      float p1 = __builtin_amdgcn_exp2f(sca[g2*4 + 1] + scb[g2*4 + 1]);
      float p2 = __builtin_amdgcn_exp2f(sca[g2*4 + 2] + scb[g2*4 + 2]);
      float p3 = __builtin_amdgcn_exp2f(sca[g2*4 + 3] + scb[g2*4 + 3]);
      lsum += (p0 + p1) + (p2 + p3);
      u[2*g2]   = pack2(p0, p1);
      u[2*g2+1] = pack2(p2, p3);
    }
#pragma unroll
    for (int j2 = 0; j2 < 8; ++j2) pex[j2] = (uint_t)__shfl_xor((int)u[j2], 32);
    const ushort_t* vtc = vt[cur];
#pragma unroll
    for (int s = 0; s < 2; ++s) {
      uint4 au;
      au.x = hl ? pex[4*s+2] : u[4*s+0];
      au.y = hl ? pex[4*s+3] : u[4*s+1];
      au.z = hl ? u[4*s+2]   : pex[4*s+0];
      au.w = hl ? u[4*s+3]   : pex[4*s+1];
      union { uint4 ui; bf16x8 bv; } cvt; cvt.ui = au;
      bf16x8 pa = cvt.bv;
#pragma unroll
      for (int nt = 0; nt < 6; ++nt) {
        const ushort_t* vr = &vtc[(nt*32 + ql)*VT_P + s*16 + hl*8];
        bf16x4 vlo = *(const bf16x4*)vr;
        bf16x4 vhi = *(const bf16x4*)(vr + 4);
        bf16x8 vf = __builtin_shufflevector(vlo, vhi, 0, 1, 2, 3, 4, 5, 6, 7);
        acc[nt] = __builtin_amdgcn_mfma_f32_32x32x16_bf16(pa, vf, acc[nt], 0, 0, 0);
      }
    }
    if (kb < 31) {
      int nxt = cur ^ 1;
#pragma unroll
      for (int j2 = 0; j2 < 3; ++j2) {
        ushort_t* kd = &kt[nxt][kdsto[j2]];
        *(bf16x4*)kd = __builtin_shufflevector(kpre[j2], kpre[j2], 0, 1, 2, 3);
        *(bf16x4*)(kd+4) = __builtin_shufflevector(kpre[j2], kpre[j2], 4, 5, 6, 7);
        ushort_t* vd = &vt[nxt][vdsto[j2]];
        *(bf16x4*)vd = __builtin_shufflevector(vpre[j2], vpre[j2], 0, 1, 2, 3);
        *(bf16x4*)(vd+4) = __builtin_shufflevector(vpre[j2], vpre[j2], 4, 5, 6, 7);
      }
    }
    __syncthreads();
  }
  lsum += __shfl_xor(lsum, 32);
  if (lane < 32) {
    alds[w][ql] = 1.0f / lsum;
    lpart[(size_t)split*24*NFIX + (size_t)bh*NFIX + qrow0 + ql] = lsum;
  }
  asm volatile("s_waitcnt lgkmcnt(0)" ::: "memory");
  float lv[4][4];
#pragma unroll
  for (int g2 = 0; g2 < 4; ++g2) {
    f32x4 tv = *(const f32x4*)&alds[w][8*g2 + 4*hl];
#pragma unroll
    for (int rr = 0; rr < 4; ++rr) lv[g2][rr] = tv[rr];
  }
  // ---- epilogue: O_s stored as f16 bits (split-combine precision) ----
  ushort_t* tw = (w == 0) ? kt[0] : (w == 1) ? kt[1] : (w == 2) ? vt[0] : vt[1];
#pragma unroll
  for (int nt = 0; nt < 6; ++nt) {
    int ch = nt*32 + ql;
#pragma unroll
    for (int r = 0; r < 16; ++r) {
      int qrow = (r&3) + 8*(r>>2) + 4*hl;
      tw[qrow*TW_P + ch] = f2h_bits(acc[nt][r] * lv[r>>2][r&3]);
    }
  }
  asm volatile("s_waitcnt lgkmcnt(0)" ::: "memory");
  const size_t SS = (size_t)8192*1152;
  ushort_t* opb = opart + (size_t)split*SS;
  size_t nbase = (size_t)(b*NFIX + qrow0) * 3;
#pragma unroll
  for (int i = 0; i < 12; ++i) {
    int chunk = i*64 + lane;
    int nl = chunk >> 3, jc = chunk & 7;
    int qq = nl / 3, dd = nl - 3*qq;
    ushort_t hv[8];
#pragma unroll
    for (int e = 0; e < 8; ++e)
      hv[e] = tw[qq*TW_P + (jc*8 + e)*3 + dd];
    uint4 sv;
    sv.x = (uint_t)hv[0] | ((uint_t)hv[1] << 16);
    sv.y = (uint_t)hv[2] | ((uint_t)hv[3] << 16);
    sv.z = (uint_t)hv[4] | ((uint_t)hv[5] << 16);
    sv.w = (uint_t)hv[6] | ((uint_t)hv[7] << 16);
    *(uint4*)&opb[(nbase + nl)*384 + h*64 + jc*8] = sv;
  }
}

// ---------------- x1mid + LN2 + conv3 + conv4 FULLY FUSED (block-local dependency) ----------------
#define AP 68
#define XLP 132
#define X3P 132
#define HP4 260
#define TF4P 388
__global__ __launch_bounds__(768) void x1mid_c34(
    const float* __restrict__ xdi, const ushort_t* __restrict__ opart,
    const float* __restrict__ lpart, const _Float16* __restrict__ kmf16,
    const _Float16* __restrict__ Af16, const float* __restrict__ g2,
    const float* __restrict__ b2,
    const _Float16* __restrict__ W3h, const _Float16* __restrict__ U3h,
    const _Float16* __restrict__ W4h, const _Float16* __restrict__ U4h,
    float* __restrict__ out) {
  __shared__ __align__(16) char smem[50944];
  _Float16* As = (_Float16*)smem;                 // 128 x AP = 17408 B
  _Float16* Bt = (_Float16*)(smem + 17408);       //  96 x AP = 13056 B
  float* wlsL  = (float*)(smem + 30464);          //  32 x 6 x 2 = 1536 B
  float* X     = (float*)smem;                    // overlay: 96 x XLP f32 = 50688 B
  float* stats = (float*)(smem + 50688);          // 32 x 2 f32 = 256 B
  _Float16* Xs3 = (_Float16*)smem;                // overlay: 3*32*X3P f16 = 25344 B
  _Float16* H   = (_Float16*)smem;                // overlay: 96 x HP4 f16 = 49920 B
  float* trF    = (float*)smem;                   // overlay: 32 x TF4P f32 = 49664 B
  int blk = blockIdx.x;
  int n0 = blk * 96;
  int pt0 = blk * 32;
  int t = threadIdx.x;
  int w = t >> 6, lane = t & 63, ql = lane & 31, hl = lane >> 5;
  int nsub = w >> 2, mt2 = w & 3;                 // 12 waves: 3 n-subtiles x 4 m-tiles
  if (t < 192) {
    int ptl = t / 6, h = t % 6;
    int ptg = pt0 + ptl;
    int b = ptg >> 11, n = ptg & 2047;
    size_t lidx = (size_t)(b*HH + h)*NFIX + n;
    float l[NSPLIT]; float tot = 0.f;
#pragma unroll
    for (int s = 0; s < NSPLIT; ++s) {
      l[s] = lpart[(size_t)s*24*NFIX + lidx];
      tot += l[s];
    }
    float rd = 1.f / tot;
    float* wp = &wlsL[(ptl*6 + h)*NSPLIT];
#pragma unroll
    for (int s = 0; s < NSPLIT; ++s) wp[s] = l[s]*rd;
  }
  f32x16 acc;
#pragma unroll
  for (int r = 0; r < 16; ++r) acc[r] = 0.f;
  const size_t SS = (size_t)8192*1152;
  __syncthreads();
  for (int p = 0; p < 8; ++p) {
    for (int u = t; u < 1024; u += 768) {
      int m = u >> 3, kc = u & 7;
      f16x4 a0 = *(const f16x4*)&Af16[(size_t)m*512 + p*64 + kc*8];
      f16x4 a1 = *(const f16x4*)&Af16[(size_t)m*512 + p*64 + kc*8 + 4];
      _Float16* dst = &As[m*AP + kc*8];
      *(f16x4*)dst = a0;
      *(f16x4*)(dst+4) = a1;
    }
    {
      // Bt staging: 768 threads = 96 rows x 8 col-chunks of 8 f16
      int n_l = t >> 3, jc = t & 7;
      int n_g = n0 + n_l;
      _Float16* dst = &Bt[n_l*AP + jc*8];
      if (p < 6) {
        int pt_l = n_l / 3;
        const float* wp = &wlsL[(pt_l*6 + p)*NSPLIT];
        float facc[8];
#pragma unroll
        for (int e = 0; e < 8; ++e) facc[e] = 0.f;
#pragma unroll
        for (int s = 0; s < NSPLIT; ++s) {
          const ushort_t* src = opart + s*SS + (size_t)n_g*384 + p*64 + jc*8;
          uint4 ra = *(const uint4*)src;
          const _Float16* ua = (const _Float16*)&ra;
          float wsc = wp[s];
#pragma unroll
          for (int e = 0; e < 8; ++e)
            facc[e] += wsc * (float)ua[e];
        }
        _Float16 hv[8];
#pragma unroll
        for (int e = 0; e < 8; ++e) hv[e] = (_Float16)facc[e];
        *(f16x4*)dst = *(f16x4*)&hv[0];
        *(f16x4*)(dst+4) = *(f16x4*)&hv[4];
      } else {
        const _Float16* src = kmf16 + (size_t)n_g*128 + (p-6)*64 + jc*8;
        f16x4 v0 = *(const f16x4*)src;
        f16x4 v1 = *(const f16x4*)(src + 4);
        *(f16x4*)dst = v0; *(f16x4*)(dst+4) = v1;
      }
    }
    __syncthreads();
#pragma unroll
    for (int cs = 0; cs < 4; ++cs) {
      int kloc = cs*16 + hl*8;
      f16x4 b0 = *(const f16x4*)&Bt[(nsub*32 + ql)*AP + kloc];
      f16x4 b1 = *(const f16x4*)&Bt[(nsub*32 + ql)*AP + kloc + 4];
      f16x8 bf = __builtin_shufflevector(b0, b1, 0, 1, 2, 3, 4, 5, 6, 7);
      int mrow = mt2*32 + ql;
      f16x4 a0 = *(const f16x4*)&As[mrow*AP + kloc];
      f16x4 a1 = *(const f16x4*)&As[mrow*AP + kloc + 4];
      f16x8 af = __builtin_shufflevector(a0, a1, 0, 1, 2, 3, 4, 5, 6, 7);
      acc = __builtin_amdgcn_mfma_f32_32x32x16_f16(af, bf, acc, 0, 0, 0);
    }
    __syncthreads();
  }
  {
    int cbase = mt2*32 + 4*hl;
    float* xrow = &X[(nsub*32 + ql)*XLP];
#pragma unroll
    for (int r = 0; r < 16; ++r) {
      int col = cbase + (r&3) + 8*(r>>2);
      xrow[col] = acc[r];
    }
  }
  __syncthreads();
  // ---- Phase A: add residual (post-residual stays in X; no global xmid) ----
#pragma unroll
  for (int i = 0; i < 2; ++i) {
    int u = i*768 + t;                  // 96 rows x 16 chunks of 8 = 1536
    int row = u >> 4, c0 = (u & 15) * 8;
    float* xp = &X[row*XLP + c0];
    const float* xd = xdi + (size_t)(n0 + row)*128 + c0;
    float4 a0 = *(float4*)xp, a1 = *(float4*)(xp + 4);
    float4 d0 = *(const float4*)xd, d1 = *(const float4*)(xd + 4);
    a0.x += d0.x; a0.y += d0.y; a0.z += d0.z; a0.w += d0.w;
    a1.x += d1.x; a1.y += d1.y; a1.z += d1.z; a1.w += d1.w;
    *(float4*)xp = a0; *(float4*)(xp + 4) = a1;
  }
  __syncthreads();
  // ---- stash conv4 residuals in regs (out-write mapping; X alive until Phase C sync) ----
  float rs[16];
#pragma unroll
  for (int i = 0; i < 4; ++i) {
    int u = i*768 + t;
    int row = u / 96, c4 = u % 96;
#pragma unroll
    for (int e = 0; e < 4; ++e) {
      int col = c4*4 + e;
      int o = col / 3, dd = col - 3*o;
      rs[i*4 + e] = X[(3*row + dd)*XLP + o];
    }
  }
  // ---- Phase B: per-point LN stats (12 waves cover 32 points) ----
  for (int pi = w; pi < 32; pi += 12) {
    int c = lane;
    float a0 = X[(pi*3+0)*XLP + c], a1 = X[(pi*3+1)*XLP + c], a2 = X[(pi*3+2)*XLP + c];
    float e0 = X[(pi*3+0)*XLP + c + 64], e1 = X[(pi*3+1)*XLP + c + 64], e2 = X[(pi*3+2)*XLP + c + 64];
    float nva = sqrtf(a0*a0 + a1*a1 + a2*a2 + EPSF);
    float nvb = sqrtf(e0*e0 + e1*e1 + e2*e2 + EPSF);
    float s1 = nva + nvb;
    float s2 = nva*nva + nvb*nvb;
#pragma unroll
    for (int off = 32; off >= 1; off >>= 1) {
      s1 += __shfl_down(s1, off);
      s2 += __shfl_down(s2, off);
    }
    if (lane == 0) {
      float mu = s1 * (1.f/128.f);
      float var = s2 * (1.f/128.f) - mu*mu;
      stats[pi*2]   = mu;
      stats[pi*2+1] = rsqrtf(var + LNEPSF);
    }
  }
  __syncthreads();
  // ---- Phase C: LN2-normalize into regs (f16 bits; identical rounding to old nxh path) ----
  uint4 svr[2]; int rowr[2], c0r[2];
#pragma unroll
  for (int i = 0; i < 2; ++i) {
    int u = i*768 + t;
    int row = u >> 4, c0 = (u & 15) * 8;
    int pt_l = row / 3;
    float mu = stats[pt_l*2], rsig = stats[pt_l*2+1];
    const float* r0 = &X[(pt_l*3 + 0)*XLP + c0];
    const float* r1 = &X[(pt_l*3 + 1)*XLP + c0];
    const float* r2 = &X[(pt_l*3 + 2)*XLP + c0];
    const float* rd = &X[row*XLP + c0];
    float xv[8];
#pragma unroll
    for (int e = 0; e < 8; ++e) {
      float x0 = r0[e], x1 = r1[e], x2 = r2[e];
      float nv = sqrtf(x0*x0 + x1*x1 + x2*x2 + EPSF);
      float nnew = g2[c0 + e] * ((nv - mu) * rsig) + b2[c0 + e];
      xv[e] = rd[e] * (nnew / nv);
    }
    uint4 sv;
    sv.x = packh2(xv[0], xv[1]); sv.y = packh2(xv[2], xv[3]);
    sv.z = packh2(xv[4], xv[5]); sv.w = packh2(xv[6], xv[7]);
    svr[i] = sv; rowr[i] = row; c0r[i] = c0;
  }
  __syncthreads();   // all X/stats reads done; safe to overlay with Xs3
  // ---- write nxh values into conv3 staging layout (d-plane de-interleave) ----
#pragma unroll
  for (int i = 0; i < 2; ++i) {
    int row = rowr[i];
    int d = row % 3, p = row / 3;
    _Float16* dst = &Xs3[(d*32 + p)*X3P + c0r[i]];
    uint2 lo; lo.x = svr[i].x; lo.y = svr[i].y;
    uint2 hi; hi.x = svr[i].z; hi.y = svr[i].w;
    *(uint2*)dst = lo;
    *(uint2*)(dst + 4) = hi;
  }
  __syncthreads();
  // ---- conv3 phase (waves 0-7): o-tile ot3 = w*32, all 3 d-planes in-register ----
  f32x16 accP[3], accD[3];
  int ot3 = w*32;
  if (w < 8) {
#pragma unroll
    for (int d = 0; d < 3; ++d)
#pragma unroll
      for (int r = 0; r < 16; ++r) { accP[d][r] = 0.f; accD[d][r] = 0.f; }
    const _Float16* Wp = W3h + (size_t)(ot3 + ql)*128 + hl*8;
    const _Float16* Up = U3h + (size_t)(ot3 + ql)*128 + hl*8;
#pragma unroll
    for (int cs = 0; cs < 8; ++cs) {
      f16x8 wf = *(const f16x8*)(Wp + cs*16);
      f16x8 uf = *(const f16x8*)(Up + cs*16);
#pragma unroll
      for (int d = 0; d < 3; ++d) {
        const _Float16* xr = &Xs3[(d*32 + ql)*X3P + cs*16 + hl*8];
        f16x4 lo = *(const f16x4*)xr;
        f16x4 hi = *(const f16x4*)(xr + 4);
        f16x8 xf = __builtin_shufflevector(lo, hi, 0, 1, 2, 3, 4, 5, 6, 7);
        accP[d] = __builtin_amdgcn_mfma_f32_32x32x16_f16(wf, xf, accP[d], 0, 0, 0);
        accD[d] = __builtin_amdgcn_mfma_f32_32x32x16_f16(uf, xf, accD[d], 0, 0, 0);
      }
    }
  }
  __syncthreads();   // all Xs3 reads done; safe to overlay with H
  if (w < 8) {
#pragma unroll
    for (int r = 0; r < 16; ++r) {
      int olr = (r&3) + 8*(r>>2) + 4*hl;
      float p3[3], d3[3], res[3];
#pragma unroll
      for (int d = 0; d < 3; ++d) { p3[d] = accP[d][r]; d3[d] = accD[d][r]; }
      vnleaky3(p3, d3, res);
#pragma unroll
      for (int d = 0; d < 3; ++d)
        H[(d*32 + ql)*HP4 + ot3 + olr] = (_Float16)res[d];
    }
  }
  __syncthreads();
  // ---- conv4 phase (waves 0-7): ph=w>>2 point-half, ot4=(w&3)*32 ----
  int ph = w >> 2;
  int ot4 = (w & 3) * 32;
  int nl = lane & 15, kq = lane >> 4;
  f32x4 acc4P[2][3], acc4D[2][3];
  if (w < 8) {
#pragma unroll
    for (int mt = 0; mt < 2; ++mt)
#pragma unroll
      for (int d = 0; d < 3; ++d)
#pragma unroll
        for (int r = 0; r < 4; ++r) { acc4P[mt][d][r] = 0.f; acc4D[mt][d][r] = 0.f; }
    const _Float16* Wb = W4h + (size_t)ot4*256;
    const _Float16* Ub = U4h + (size_t)ot4*256;
#pragma unroll
    for (int cs = 0; cs < 8; ++cs) {
      int kof = cs*32 + kq*8;
      f16x8 xf[3];
#pragma unroll
      for (int d = 0; d < 3; ++d) {
        const _Float16* xr = &H[(d*32 + ph*16 + nl)*HP4 + kof];
        f16x4 lo = *(const f16x4*)xr;
        f16x4 hi = *(const f16x4*)(xr + 4);
        xf[d] = __builtin_shufflevector(lo, hi, 0, 1, 2, 3, 4, 5, 6, 7);
      }
#pragma unroll
      for (int mt = 0; mt < 2; ++mt) {
        f16x8 wf = *(const f16x8*)(Wb + (size_t)(mt*16 + nl)*256 + kof);
        f16x8 uf = *(const f16x8*)(Ub + (size_t)(mt*16 + nl)*256 + kof);
#pragma unroll
        for (int d = 0; d < 3; ++d) {
          acc4P[mt][d] = __builtin_amdgcn_mfma_f32_16x16x32_f16(wf, xf[d], acc4P[mt][d], 0, 0, 0);
          acc4D[mt][d] = __builtin_amdgcn_mfma_f32_16x16x32_f16(uf, xf[d], acc4D[mt][d], 0, 0, 0);
        }
      }
    }
  }
  __syncthreads();   // all H reads done; safe to overlay with trF
  if (w < 8) {
#pragma unroll
    for (int mt = 0; mt < 2; ++mt)
#pragma unroll
      for (int r = 0; r < 4; ++r) {
        int o = ot4 + mt*16 + kq*4 + r;
        int p_l = ph*16 + nl;
        float p3[3], d3[3], res[3];
#pragma unroll
        for (int d = 0; d < 3; ++d) { p3[d] = acc4P[mt][d][r]; d3[d] = acc4D[mt][d][r]; }
        vnleaky3(p3, d3, res);
#pragma unroll
        for (int d = 0; d < 3; ++d) trF[p_l*TF4P + o*3 + d] = res[d];
      }
  }
  __syncthreads();
  // ---- out-write: 32 rows x 384 f32, + stashed residuals (all 768 threads) ----
#pragma unroll
  for (int i = 0; i < 4; ++i) {
    int u = i*768 + t;
    int row = u / 96, c4 = u % 96;
    float4 vv = *(float4*)&trF[row*TF4P + c4*4];
    int bn = pt0 + row;
    float4 ov;
    ov.x = vv.x + rs[i*4 + 0];
    ov.y = vv.y + rs[i*4 + 1];
    ov.z = vv.z + rs[i*4 + 2];
    ov.w = vv.w + rs[i*4 + 3];
    *(float4*)&out[(size_t)bn*384 + c4*4] = ov;
  }
}

extern "C" void kernel_launch(void* const* d_in, const int* in_sizes, int n_in,
                              void* d_out, int out_size, void* d_ws, size_t ws_size,
                              hipStream_t stream) {
  const float* x   = (const float*)d_in[0];
  const int* knn   = (const int*)d_in[1];
  const float* g1  = (const float*)d_in[2];
  const float* b1  = (const float*)d_in[3];
  const float* g2  = (const float*)d_in[4];
  const float* b2  = (const float*)d_in[5];
  const float* Wq  = (const float*)d_in[6];
  const float* Wk  = (const float*)d_in[7];
  const float* Wv  = (const float*)d_in[8];
  const float* Wo  = (const float*)d_in[9];
  const float* W1  = (const float*)d_in[10];
  const float* U1  = (const float*)d_in[11];
  const float* W2  = (const float*)d_in[12];
  const float* W3  = (const float*)d_in[13];
  const float* U3  = (const float*)d_in[14];
  const float* W4  = (const float*)d_in[15];
  const float* U4  = (const float*)d_in[16];
  float* out = (float*)d_out;
  (void)n_in; (void)out_size; (void)ws_size;

  const size_t BN = (size_t)in_sizes[0] / 384;   // 8192

  float* ws    = (float*)d_ws;
  float* xdi   = ws;                          // BN*384 f32 (raw x, de-interleaved [n][c])
  float* xmid  = xdi + BN*384;                // (region unused after fusion)
  _Float16* kmf16 = (_Float16*)(xmid + BN*384);  // BN*384 fp16 [n][128]
  ushort_t* xbp = (ushort_t*)(kmf16 + BN*384);   // BN*384 bf16 (LN1 normalized, de-interleaved)
  ushort_t* qb = xbp + BN*384;                // BN*1152 bf16
  ushort_t* kb = qb + BN*1152;
  ushort_t* vb = kb + BN*1152;
  ushort_t* vT = vb + BN*1152;
  ushort_t* Wall = vT + BN*1152;              // 212992 bf16
  _Float16* Af16 = (_Float16*)(Wall + 212992);   // 65536 fp16
  _Float16* W3h = Af16 + 65536;               // 32768 fp16
  _Float16* U3h = W3h + 32768;
  _Float16* W4h = U3h + 32768;
  _Float16* U4h = W4h + 32768;
  ushort_t* opart = (ushort_t*)(U4h + 32768); // region 4*BN*1152; attn uses splits 0/1
  float* lpart = (float*)(opart + 4*BN*1152); // 2*24*2048 f32
  // YZh/NBh moved to opart splits-2/3 (unused by attn) so attn's opart writes
  // can run CONCURRENTLY with conv1_post reads (tail-filler blocks in attn launch).
  _Float16* YZh = (_Float16*)(opart + 2*BN*1152);
  _Float16* NBh = YZh + BN*768;

  prep_ln1<<<1600 + 4096, 256, 0, stream>>>(Wq, Wk, Wv, Wo, W1, U1, W2, W3, U3, W4, U4,
                                            Wall, Af16, W3h, U3h, W4h, U4h,
                                            x, xbp, xdi, g1, b1);
  qkv_conv1_mfma<<<192*4, 256, 0, stream>>>(xbp, Wall, qb, kb, vb, YZh, NBh);
  vtrans_kernel<<<768, 256, 0, stream>>>(vb, vT);
  attn_kernel<<<16*24*NSPLIT + 1024, 256, 0, stream>>>(qb, kb, vT, opart, lpart,
                                                       YZh, NBh, knn, kmf16);
  x1mid_c34<<<256, 768, 0, stream>>>(xdi, opart, lpart, kmf16, Af16, g2, b2,
                                     W3h, U3h, W4h, U4h, out);
}